// Round 3
// baseline (1250.026 us; speedup 1.0000x reference)
//
#include <hip/hip_runtime.h>
#include <hip/hip_bf16.h>

typedef __hip_bfloat16 bf16;

// Runtime-dtype load: flag==1 -> float32, flag==0 -> bf16
__device__ __forceinline__ float ldx(const void* p, size_t i, bool f32) {
    return f32 ? ((const float*)p)[i]
               : __bfloat162float(((const bf16*)p)[i]);
}

// ---------------------------------------------------------------------------
// dtype detector: f32 N(0,1) words have IEEE exponent in [100,150];
// bf16-pair words essentially never do. flag[0]=1 -> f32, 0 -> bf16.
// ---------------------------------------------------------------------------
__global__ void detect_kernel(const unsigned* __restrict__ x, int nwords,
                              int* __restrict__ flag)
{
    __shared__ int cnt;
    if (threadIdx.x == 0) cnt = 0;
    __syncthreads();
    int c = 0;
    for (int i = threadIdx.x; i < nwords; i += blockDim.x) {
        unsigned e = (x[i] >> 23) & 0xFFu;
        if (e >= 100u && e <= 150u) c++;
    }
    atomicAdd(&cnt, c);
    __syncthreads();
    if (threadIdx.x == 0) flag[0] = (2 * cnt > nwords) ? 1 : 0;
}

// ---------------------------------------------------------------------------
// Projection: H[N,64] = X[N,K] @ W[K,64] (bf16 out), fused alpha_i = H[r,:]@a_i
// One block = 256 threads = 4 waves; wave handles one row (lane = channel).
// ---------------------------------------------------------------------------
template <int K>
__global__ __launch_bounds__(256) void proj_alpha_kernel(
    const void* __restrict__ X, const void* __restrict__ W,
    const void* __restrict__ a1, const void* __restrict__ a2,
    bf16* __restrict__ H, float* __restrict__ al1, float* __restrict__ al2,
    int N, const int* __restrict__ flag)
{
    __shared__ float Wl[K * 64];
    __shared__ float Xl[4 * K];
    __shared__ float a1l[64];
    __shared__ float a2l[64];

    const bool f32 = (flag[0] != 0);
    const int tid = threadIdx.x;
    for (int i = tid; i < K * 64; i += 256) Wl[i] = ldx(W, i, f32);
    if (tid < 64) {
        a1l[tid] = a1 ? ldx(a1, tid, f32) : 0.f;
        a2l[tid] = a2 ? ldx(a2, tid, f32) : 0.f;
    }

    const int c  = tid & 63;   // channel
    const int rl = tid >> 6;   // local row (0..3), wave-uniform

    for (int rg = blockIdx.x; rg * 4 < N; rg += gridDim.x) {
        __syncthreads();  // covers W/a staging on first iter; Xl reuse after
        for (int i = tid; i < 4 * K; i += 256) {
            int rr = rg * 4 + i / K;
            Xl[i] = (rr < N) ? ldx(X, (size_t)rr * K + (i % K), f32) : 0.f;
        }
        __syncthreads();

        const int r = rg * 4 + rl;
        float acc = 0.f;
        #pragma unroll 8
        for (int k = 0; k < K; ++k) acc += Xl[rl * K + k] * Wl[k * 64 + c];

        if (r < N) {
            if (H) H[(size_t)r * 64 + c] = __float2bfloat16(acc);
            if (al1) {
                float v = acc * a1l[c];
                #pragma unroll
                for (int o = 32; o > 0; o >>= 1) v += __shfl_xor(v, o);
                if (c == 0) al1[r] = v;
            }
            if (al2) {
                float v = acc * a2l[c];
                #pragma unroll
                for (int o = 32; o > 0; o >>= 1) v += __shfl_xor(v, o);
                if (c == 0) al2[r] = v;
            }
        }
    }
}

// ---------------------------------------------------------------------------
// CSR construction
// ---------------------------------------------------------------------------
__global__ void count_kernel(const int* __restrict__ dst, int E, int* __restrict__ deg)
{
    int e = blockIdx.x * blockDim.x + threadIdx.x;
    if (e < E) atomicAdd(&deg[dst[e]], 1);
}

__global__ __launch_bounds__(1024) void scan_a_kernel(const int* __restrict__ deg, int n,
                                                      int* __restrict__ rowptr,
                                                      int* __restrict__ partials)
{
    __shared__ int sh[1024];
    const int t = threadIdx.x;
    const int i = blockIdx.x * 1024 + t;
    int v = (i < n) ? deg[i] : 0;
    sh[t] = v;
    __syncthreads();
    for (int o = 1; o < 1024; o <<= 1) {
        int u = (t >= o) ? sh[t - o] : 0;
        __syncthreads();
        sh[t] += u;
        __syncthreads();
    }
    if (i < n) rowptr[i + 1] = sh[t];
    if (t == 1023) partials[blockIdx.x] = sh[t];
}

__global__ void scan_b_kernel(int* __restrict__ partials, int nb)
{
    int t = threadIdx.x;
    int v = (t < nb) ? partials[t] : 0;
    int orig = v;
    #pragma unroll
    for (int o = 1; o < 64; o <<= 1) {
        int u = __shfl_up(v, o);
        if (t >= o) v += u;
    }
    v -= orig;  // exclusive
    if (t < nb) partials[t] = v;
}

__global__ void scan_c_kernel(int* __restrict__ rowptr, const int* __restrict__ partials, int n)
{
    int i = blockIdx.x * blockDim.x + threadIdx.x;
    if (i == 0) rowptr[0] = 0;
    if (i < n) rowptr[i + 1] += partials[i >> 10];
}

__global__ void fill_kernel(const int* __restrict__ src, const int* __restrict__ dst, int E,
                            const float* __restrict__ as_, const float* __restrict__ ad_,
                            const int* __restrict__ rowptr, int* __restrict__ fillc,
                            int* __restrict__ esrc, float* __restrict__ elog)
{
    int e = blockIdx.x * blockDim.x + threadIdx.x;
    if (e >= E) return;
    int s = src[e], d = dst[e];
    float l = as_[s] + ad_[d];
    l = (l > 0.f) ? l : 0.2f * l;                 // leaky_relu 0.2
    if (!(fabsf(l) < 1e30f)) l = 0.f;             // squash NaN/Inf
    int pos  = atomicAdd(&fillc[d], 1);
    int slot = rowptr[d] + pos;
    if (slot < 0) slot = 0;
    if (slot >= E) slot = E - 1;
    esrc[slot] = s;
    elog[slot] = l;
}

// ---------------------------------------------------------------------------
// Pull-mode segment softmax + weighted aggregation (one wave per dst node).
// ---------------------------------------------------------------------------
__global__ __launch_bounds__(256) void aggregate_kernel(
    const int* __restrict__ rowptr, const int* __restrict__ esrc,
    const float* __restrict__ elog, const bf16* __restrict__ HS,
    float* __restrict__ acc, int n, int n_src, int E)
{
    const int gw   = (blockIdx.x * blockDim.x + threadIdx.x) >> 6;
    const int lane = threadIdx.x & 63;
    if (gw >= n) return;

    int start = rowptr[gw];
    int end   = rowptr[gw + 1];
    if (start < 0) start = 0;
    if (end > E) end = E;
    if (end < start) end = start;

    float m = -INFINITY;
    for (int i = start + lane; i < end; i += 64) m = fmaxf(m, elog[i]);
    #pragma unroll
    for (int o = 32; o > 0; o >>= 1) m = fmaxf(m, __shfl_xor(m, o));

    float den = 0.f;
    for (int i = start + lane; i < end; i += 64) den += expf(elog[i] - m);
    #pragma unroll
    for (int o = 32; o > 0; o >>= 1) den += __shfl_xor(den, o);
    const float inv = 1.0f / (den + 1e-16f);

    float a = 0.f;
    for (int i = start; i < end; ++i) {
        int s = esrc[i];                               // wave-uniform broadcast
        if ((unsigned)s >= (unsigned)n_src) s = 0;     // insurance
        float w = expf(elog[i] - m) * inv;
        a += w * __bfloat162float(HS[(size_t)s * 64 + lane]);
    }
    acc[(size_t)gw * 64 + lane] += a;
}

// out = 0.5*(acc + b1 + b2), dtype per flag
__global__ void combine_kernel(const float* __restrict__ acc,
                               const void* __restrict__ b1, const void* __restrict__ b2,
                               void* __restrict__ out_base, size_t elem_off, int total,
                               const int* __restrict__ flag)
{
    const bool f32 = (flag[0] != 0);
    int i = blockIdx.x * blockDim.x + threadIdx.x;
    if (i >= total) return;
    int c = i & 63;
    float v = 0.5f * (acc[i] + ldx(b1, c, f32) + ldx(b2, c, f32));
    if (f32) ((float*)out_base)[elem_off + i] = v;
    else     ((bf16*)out_base)[elem_off + i] = __float2bfloat16(v);
}

// ---------------------------------------------------------------------------
extern "C" void kernel_launch(void* const* d_in, const int* in_sizes, int n_in,
                              void* d_out, int out_size, void* d_ws, size_t ws_size,
                              hipStream_t stream)
{
    const void* x_t = d_in[0];
    const void* x_d = d_in[1];
    const int* ei_tt = (const int*)d_in[2];
    const int* ei_dt = (const int*)d_in[3];
    const int* ei_dd = (const int*)d_in[4];
    const int* ei_td = (const int*)d_in[5];
    const void* W_tt     = d_in[6];
    const void* att_tt_s = d_in[7];
    const void* att_tt_d = d_in[8];
    const void* b_tt     = d_in[9];
    const void* W_dt_src = d_in[10];
    const void* W_dt_dst = d_in[11];
    const void* att_dt_s = d_in[12];
    const void* att_dt_d = d_in[13];
    const void* b_dt     = d_in[14];
    const void* W_dd     = d_in[15];
    const void* att_dd_s = d_in[16];
    const void* att_dd_d = d_in[17];
    const void* b_dd     = d_in[18];
    const void* W_td_src = d_in[19];
    const void* W_td_dst = d_in[20];
    const void* att_td_s = d_in[21];
    const void* att_td_d = d_in[22];
    const void* b_td     = d_in[23];

    const int NT = in_sizes[0] / 128;
    const int ND = in_sizes[1] / 128;
    const int Ett = in_sizes[2] / 2, Edt = in_sizes[3] / 2,
              Edd = in_sizes[4] / 2, Etd = in_sizes[5] / 2;
    const int NMAX = (NT > ND) ? NT : ND;
    int EMAX = Ett;
    if (Edt > EMAX) EMAX = Edt;
    if (Edd > EMAX) EMAX = Edd;
    if (Etd > EMAX) EMAX = Etd;

    // ---- compact workspace (~27 MB) ----
    char* wptr = (char*)d_ws;
    auto alloc = [&](size_t bytes) -> void* {
        void* p = (void*)wptr;
        wptr += (bytes + 255) & ~(size_t)255;
        return p;
    };
    float* acc     = (float*)alloc((size_t)NMAX * 64 * 4);   // aliased t/d phases
    bf16*  h_s     = (bf16*)alloc((size_t)NMAX * 64 * 2);
    float* al_s    = (float*)alloc((size_t)NMAX * 4);
    float* al_d    = (float*)alloc((size_t)NMAX * 4);
    int*   deg     = (int*)alloc((size_t)NMAX * 4);
    int*   rowptr  = (int*)alloc(((size_t)NMAX + 1) * 4);
    int*   fillc   = (int*)alloc((size_t)NMAX * 4);
    int*   esrc    = (int*)alloc((size_t)EMAX * 4);
    float* elog    = (float*)alloc((size_t)EMAX * 4);
    int*   partials= (int*)alloc(256 * 4);
    int*   flag    = (int*)alloc(256 * 4);

    const size_t out_t_off = 0;
    const size_t out_d_off = (size_t)NT * 64;

    auto relation = [&](const int* ei, int E, int n_dst, int n_src) {
        hipMemsetAsync(deg,   0, (size_t)n_dst * 4, stream);
        hipMemsetAsync(fillc, 0, (size_t)n_dst * 4, stream);
        const int* srcv = ei;
        const int* dstv = ei + E;
        count_kernel<<<(E + 255) / 256, 256, 0, stream>>>(dstv, E, deg);
        int nb = (n_dst + 1023) / 1024;
        scan_a_kernel<<<nb, 1024, 0, stream>>>(deg, n_dst, rowptr, partials);
        scan_b_kernel<<<1, 64, 0, stream>>>(partials, nb);
        scan_c_kernel<<<(n_dst + 255) / 256, 256, 0, stream>>>(rowptr, partials, n_dst);
        fill_kernel<<<(E + 255) / 256, 256, 0, stream>>>(srcv, dstv, E, al_s, al_d,
                                                         rowptr, fillc, esrc, elog);
        aggregate_kernel<<<(n_dst + 3) / 4, 256, 0, stream>>>(rowptr, esrc, elog, h_s,
                                                              acc, n_dst, n_src, E);
    };

    const int PG = 2048;

    // dtype probe (writes flag[0]; stream-ordered before all consumers)
    detect_kernel<<<1, 256, 0, stream>>>((const unsigned*)x_t, 4096, flag);

    // ================= target phase: acc = agg_tt + agg_dt =================
    hipMemsetAsync(acc, 0, (size_t)NT * 64 * 4, stream);

    // tt: hs == hd == x_target @ W_tt
    proj_alpha_kernel<128><<<PG, 256, 0, stream>>>(
        x_t, W_tt, att_tt_s, att_tt_d, h_s, al_s, al_d, NT, flag);
    relation(ei_tt, Ett, NT, NT);

    // dt: hs = x_drug @ W_dt_src ; alpha_d from x_target @ W_dt_dst (alpha only)
    proj_alpha_kernel<128><<<PG, 256, 0, stream>>>(
        x_d, W_dt_src, att_dt_s, nullptr, h_s, al_s, nullptr, ND, flag);
    proj_alpha_kernel<128><<<PG, 256, 0, stream>>>(
        x_t, W_dt_dst, att_dt_d, nullptr, nullptr, al_d, nullptr, NT, flag);
    relation(ei_dt, Edt, NT, ND);

    // x_target_new -> final home (dtype per flag); also the td-projection input
    combine_kernel<<<(NT * 64 + 255) / 256, 256, 0, stream>>>(
        acc, b_tt, b_dt, d_out, out_t_off, NT * 64, flag);

    // ================= drug phase: acc = agg_dd + agg_td =================
    hipMemsetAsync(acc, 0, (size_t)ND * 64 * 4, stream);

    // dd: hs == hd == x_drug @ W_dd
    proj_alpha_kernel<128><<<PG, 256, 0, stream>>>(
        x_d, W_dd, att_dd_s, att_dd_d, h_s, al_s, al_d, ND, flag);
    relation(ei_dd, Edd, ND, ND);

    // td: alpha_d from x_drug @ W_td_dst; hs = x_target_new @ W_td_src (K=64)
    proj_alpha_kernel<128><<<PG, 256, 0, stream>>>(
        x_d, W_td_dst, att_td_d, nullptr, nullptr, al_d, nullptr, ND, flag);
    proj_alpha_kernel<64><<<PG, 256, 0, stream>>>(
        d_out, W_td_src, att_td_s, nullptr, h_s, al_s, nullptr, NT, flag);
    relation(ei_td, Etd, ND, NT);

    combine_kernel<<<(ND * 64 + 255) / 256, 256, 0, stream>>>(
        acc, b_dd, b_td, d_out, out_d_off, ND * 64, flag);
}

// Round 4
// 1143.575 us; speedup vs baseline: 1.0931x; 1.0931x over previous
//
#include <hip/hip_runtime.h>
#include <hip/hip_bf16.h>

typedef __hip_bfloat16 bf16;

__device__ __forceinline__ float bf2f(unsigned short u) {
    return __uint_as_float(((unsigned)u) << 16);
}
__device__ __forceinline__ float ldx(const void* p, size_t i, bool f32) {
    return f32 ? ((const float*)p)[i] : bf2f(((const unsigned short*)p)[i]);
}
// i4 = index in 4-element units
__device__ __forceinline__ float4 ldx4(const void* p, size_t i4, bool f32) {
    if (f32) return ((const float4*)p)[i4];
    ushort4 u = ((const ushort4*)p)[i4];
    return make_float4(bf2f(u.x), bf2f(u.y), bf2f(u.z), bf2f(u.w));
}
// i2 = index in 2-element units
__device__ __forceinline__ float2 ldx2(const void* p, size_t i2, bool f32) {
    if (f32) return ((const float2*)p)[i2];
    ushort2 u = ((const ushort2*)p)[i2];
    return make_float2(bf2f(u.x), bf2f(u.y));
}
__device__ __forceinline__ float wave_sum(float v) {
    #pragma unroll
    for (int o = 32; o > 0; o >>= 1) v += __shfl_xor(v, o);
    return v;
}

// ---------------------------------------------------------------------------
// dtype detector: f32 N(0,1) words have IEEE exponent in [100,150];
// bf16-pair words essentially never do. flag[0]=1 -> f32, 0 -> bf16.
// ---------------------------------------------------------------------------
__global__ void detect_kernel(const unsigned* __restrict__ x, int nwords,
                              int* __restrict__ flag)
{
    __shared__ int cnt;
    if (threadIdx.x == 0) cnt = 0;
    __syncthreads();
    int c = 0;
    for (int i = threadIdx.x; i < nwords; i += blockDim.x) {
        unsigned e = (x[i] >> 23) & 0xFFu;
        if (e >= 100u && e <= 150u) c++;
    }
    atomicAdd(&cnt, c);
    __syncthreads();
    if (threadIdx.x == 0) flag[0] = (2 * cnt > nwords) ? 1 : 0;
}

// ---------------------------------------------------------------------------
// Projection GEMM: H[N,64] = X[N,K] @ W[K,64] (bf16 H), fused alpha = H@a.
// Block = 256 thr = 4 waves; block-iter = 16 rows (4 rows/wave, lane=channel).
// W transposed in LDS [64][K+4] -> per-lane ds_read_b128, bank-uniform.
// ---------------------------------------------------------------------------
template <int K>
__global__ __launch_bounds__(256) void proj_kernel(
    const void* __restrict__ X, const void* __restrict__ W,
    const void* __restrict__ a1, const void* __restrict__ a2,
    bf16* __restrict__ H, float* __restrict__ al1, float* __restrict__ al2,
    int N, const int* __restrict__ flag)
{
    constexpr int KP = K + 4;   // 16B-aligned row stride, bank-spread
    __shared__ float Wt[64 * KP];
    __shared__ float Xl[16 * K];
    __shared__ float a1l[64], a2l[64];

    const bool f32 = (flag[0] != 0);
    const int tid = threadIdx.x;

    // stage W transposed: pairs (2i, 2i+1) are (k, c),(k, c+1)
    for (int i = tid; i < K * 32; i += 256) {
        float2 w2 = ldx2(W, i, f32);
        int k = (2 * i) >> 6;
        int c = (2 * i) & 63;
        Wt[c * KP + k]       = w2.x;
        Wt[(c + 1) * KP + k] = w2.y;
    }
    if (tid < 64) {
        a1l[tid] = a1 ? ldx(a1, tid, f32) : 0.f;
        a2l[tid] = a2 ? ldx(a2, tid, f32) : 0.f;
    }

    const int c   = tid & 63;
    const int w4r = (tid >> 6) * 4;   // wave's first local row

    for (int rg = blockIdx.x; rg * 16 < N; rg += gridDim.x) {
        __syncthreads();   // covers W staging (1st iter) + prev-iter compute
        for (int i = tid; i < 16 * K / 4; i += 256) {
            int r  = (i * 4) / K;
            int kk = (i * 4) % K;
            int rr = rg * 16 + r;
            float4 v = (rr < N) ? ldx4(X, (size_t)rr * (K / 4) + kk / 4, f32)
                                : make_float4(0.f, 0.f, 0.f, 0.f);
            *(float4*)&Xl[i * 4] = v;
        }
        __syncthreads();

        float acc0 = 0.f, acc1 = 0.f, acc2 = 0.f, acc3 = 0.f;
        for (int k = 0; k < K; k += 4) {
            float4 w  = *(const float4*)&Wt[c * KP + k];
            float4 x0 = *(const float4*)&Xl[(w4r + 0) * K + k];
            float4 x1 = *(const float4*)&Xl[(w4r + 1) * K + k];
            float4 x2 = *(const float4*)&Xl[(w4r + 2) * K + k];
            float4 x3 = *(const float4*)&Xl[(w4r + 3) * K + k];
            acc0 = fmaf(x0.x, w.x, fmaf(x0.y, w.y, fmaf(x0.z, w.z, fmaf(x0.w, w.w, acc0))));
            acc1 = fmaf(x1.x, w.x, fmaf(x1.y, w.y, fmaf(x1.z, w.z, fmaf(x1.w, w.w, acc1))));
            acc2 = fmaf(x2.x, w.x, fmaf(x2.y, w.y, fmaf(x2.z, w.z, fmaf(x2.w, w.w, acc2))));
            acc3 = fmaf(x3.x, w.x, fmaf(x3.y, w.y, fmaf(x3.z, w.z, fmaf(x3.w, w.w, acc3))));
        }

        float accs[4] = {acc0, acc1, acc2, acc3};
        #pragma unroll
        for (int i = 0; i < 4; ++i) {
            int r = rg * 16 + w4r + i;
            if (r < N) {
                if (H) H[(size_t)r * 64 + c] = __float2bfloat16(accs[i]);
                if (al1) {
                    float v = wave_sum(accs[i] * a1l[c]);
                    if (c == 0) al1[r] = v;
                }
                if (al2) {
                    float v = wave_sum(accs[i] * a2l[c]);
                    if (c == 0) al2[r] = v;
                }
            }
        }
    }
}

// ---------------------------------------------------------------------------
// Alpha-only path: alpha = x @ (W @ a).  wvec[k] = sum_c W[k][c]*a[c]
// ---------------------------------------------------------------------------
__global__ void wvec_kernel(const void* __restrict__ W, const void* __restrict__ a,
                            float* __restrict__ wvec, int K, const int* __restrict__ flag)
{
    const bool f32 = (flag[0] != 0);
    int k = blockIdx.x * blockDim.x + threadIdx.x;
    if (k >= K) return;
    float s = 0.f;
    for (int c = 0; c < 64; ++c) s += ldx(W, (size_t)k * 64 + c, f32) * ldx(a, c, f32);
    wvec[k] = s;
}

template <int K>
__global__ __launch_bounds__(256) void alpha_mv_kernel(
    const void* __restrict__ X, const float* __restrict__ wvec,
    float* __restrict__ al, int N, const int* __restrict__ flag)
{
    const bool f32 = (flag[0] != 0);
    const int r    = (blockIdx.x * blockDim.x + threadIdx.x) >> 6;
    const int lane = threadIdx.x & 63;
    if (r >= N) return;
    float v = 0.f;
    #pragma unroll
    for (int k = lane; k < K; k += 64) v += ldx(X, (size_t)r * K + k, f32) * wvec[k];
    v = wave_sum(v);
    if (lane == 0) al[r] = v;
}

// ---------------------------------------------------------------------------
// CSR construction
// ---------------------------------------------------------------------------
__global__ void count_kernel(const int* __restrict__ dst, int E, int* __restrict__ deg)
{
    int e = blockIdx.x * blockDim.x + threadIdx.x;
    if (e < E) atomicAdd(&deg[dst[e]], 1);
}

__global__ __launch_bounds__(1024) void scan_a_kernel(const int* __restrict__ deg, int n,
                                                      int* __restrict__ rowptr,
                                                      int* __restrict__ partials)
{
    __shared__ int sh[1024];
    const int t = threadIdx.x;
    const int i = blockIdx.x * 1024 + t;
    int v = (i < n) ? deg[i] : 0;
    sh[t] = v;
    __syncthreads();
    for (int o = 1; o < 1024; o <<= 1) {
        int u = (t >= o) ? sh[t - o] : 0;
        __syncthreads();
        sh[t] += u;
        __syncthreads();
    }
    if (i < n) rowptr[i + 1] = sh[t];
    if (t == 1023) partials[blockIdx.x] = sh[t];
}

__global__ void scan_b_kernel(int* __restrict__ partials, int nb)
{
    int t = threadIdx.x;
    int v = (t < nb) ? partials[t] : 0;
    int orig = v;
    #pragma unroll
    for (int o = 1; o < 64; o <<= 1) {
        int u = __shfl_up(v, o);
        if (t >= o) v += u;
    }
    v -= orig;  // exclusive
    if (t < nb) partials[t] = v;
}

__global__ void scan_c_kernel(int* __restrict__ rowptr, const int* __restrict__ partials, int n)
{
    int i = blockIdx.x * blockDim.x + threadIdx.x;
    if (i == 0) rowptr[0] = 0;
    if (i < n) rowptr[i + 1] += partials[i >> 10];
}

// fill: edata[slot] = {src, exp(leaky_relu(alpha_s+alpha_d))}
__global__ void fill_kernel(const int* __restrict__ src, const int* __restrict__ dst, int E,
                            const float* __restrict__ as_, const float* __restrict__ ad_,
                            const int* __restrict__ rowptr, int* __restrict__ fillc,
                            int2* __restrict__ edata)
{
    int e = blockIdx.x * blockDim.x + threadIdx.x;
    if (e >= E) return;
    int s = src[e], d = dst[e];
    float l = as_[s] + ad_[d];
    l = (l > 0.f) ? l : 0.2f * l;       // leaky_relu 0.2
    float ew = __expf(l);               // logits bounded; max-subtraction unneeded
    int pos  = atomicAdd(&fillc[d], 1);
    int slot = rowptr[d] + pos;
    edata[slot] = make_int2(s, __float_as_int(ew));
}

// ---------------------------------------------------------------------------
// Pull-mode aggregation, single pass. One wave per dst node; lane = channel.
// Lane-parallel preload of 64 edges, shfl broadcast, 4x unrolled gather.
// Optional fused epilogue: out = dtype(0.5*(acc_prev + r + b1 + b2)).
// ---------------------------------------------------------------------------
__global__ __launch_bounds__(256) void aggregate_kernel(
    const int* __restrict__ rowptr, const int2* __restrict__ edata,
    const unsigned short* __restrict__ HS,   // bf16 bits
    float* __restrict__ acc, int n, int first,
    const void* __restrict__ b1, const void* __restrict__ b2,
    void* __restrict__ out, size_t out_off, const int* __restrict__ flag)
{
    const int gw   = (blockIdx.x * blockDim.x + threadIdx.x) >> 6;
    const int lane = threadIdx.x & 63;
    if (gw >= n) return;

    const int start = rowptr[gw];
    const int end   = rowptr[gw + 1];

    float a0 = 0.f, a1 = 0.f, a2 = 0.f, a3 = 0.f, den = 0.f;
    for (int base = start; base < end; base += 64) {
        int nn = end - base;
        if (nn > 64) nn = 64;
        int s_l = 0; float w_l = 0.f;
        if (lane < nn) {
            int2 ed = edata[base + lane];
            s_l = ed.x;
            w_l = __int_as_float(ed.y);
        }
        den += w_l;
        int j = 0;
        for (; j + 3 < nn; j += 4) {
            int   s0 = __shfl(s_l, j + 0), s1 = __shfl(s_l, j + 1);
            int   s2 = __shfl(s_l, j + 2), s3 = __shfl(s_l, j + 3);
            float w0 = __shfl(w_l, j + 0), w1 = __shfl(w_l, j + 1);
            float w2 = __shfl(w_l, j + 2), w3 = __shfl(w_l, j + 3);
            float h0 = bf2f(HS[(size_t)s0 * 64 + lane]);
            float h1 = bf2f(HS[(size_t)s1 * 64 + lane]);
            float h2 = bf2f(HS[(size_t)s2 * 64 + lane]);
            float h3 = bf2f(HS[(size_t)s3 * 64 + lane]);
            a0 = fmaf(w0, h0, a0); a1 = fmaf(w1, h1, a1);
            a2 = fmaf(w2, h2, a2); a3 = fmaf(w3, h3, a3);
        }
        for (; j < nn; ++j) {
            int   s = __shfl(s_l, j);
            float w = __shfl(w_l, j);
            a0 = fmaf(w, bf2f(HS[(size_t)s * 64 + lane]), a0);
        }
    }
    den = wave_sum(den);
    float r = (a0 + a1 + a2 + a3) / (den + 1e-16f);

    const size_t idx = (size_t)gw * 64 + lane;
    if (out) {
        const bool f32 = (flag[0] != 0);
        float prev = first ? 0.f : acc[idx];
        float v = 0.5f * (prev + r + ldx(b1, lane, f32) + ldx(b2, lane, f32));
        if (f32) ((float*)out)[out_off + idx] = v;
        else     ((bf16*)out)[out_off + idx] = __float2bfloat16(v);
    } else {
        if (first) acc[idx] = r;
        else       acc[idx] += r;
    }
}

// ---------------------------------------------------------------------------
extern "C" void kernel_launch(void* const* d_in, const int* in_sizes, int n_in,
                              void* d_out, int out_size, void* d_ws, size_t ws_size,
                              hipStream_t stream)
{
    const void* x_t = d_in[0];
    const void* x_d = d_in[1];
    const int* ei_tt = (const int*)d_in[2];
    const int* ei_dt = (const int*)d_in[3];
    const int* ei_dd = (const int*)d_in[4];
    const int* ei_td = (const int*)d_in[5];
    const void* W_tt     = d_in[6];
    const void* att_tt_s = d_in[7];
    const void* att_tt_d = d_in[8];
    const void* b_tt     = d_in[9];
    const void* W_dt_src = d_in[10];
    const void* W_dt_dst = d_in[11];
    const void* att_dt_s = d_in[12];
    const void* att_dt_d = d_in[13];
    const void* b_dt     = d_in[14];
    const void* W_dd     = d_in[15];
    const void* att_dd_s = d_in[16];
    const void* att_dd_d = d_in[17];
    const void* b_dd     = d_in[18];
    const void* W_td_src = d_in[19];
    const void* W_td_dst = d_in[20];
    const void* att_td_s = d_in[21];
    const void* att_td_d = d_in[22];
    const void* b_td     = d_in[23];

    const int NT = in_sizes[0] / 128;
    const int ND = in_sizes[1] / 128;
    const int Ett = in_sizes[2] / 2, Edt = in_sizes[3] / 2,
              Edd = in_sizes[4] / 2, Etd = in_sizes[5] / 2;
    const int NMAX = (NT > ND) ? NT : ND;
    int EMAX = Ett;
    if (Edt > EMAX) EMAX = Edt;
    if (Edd > EMAX) EMAX = Edd;
    if (Etd > EMAX) EMAX = Etd;

    // ---- workspace (~27 MB) ----
    char* wptr = (char*)d_ws;
    auto alloc = [&](size_t bytes) -> void* {
        void* p = (void*)wptr;
        wptr += (bytes + 255) & ~(size_t)255;
        return p;
    };
    float* acc     = (float*)alloc((size_t)NMAX * 64 * 4);
    bf16*  h_s     = (bf16*)alloc((size_t)NMAX * 64 * 2);
    float* al_s    = (float*)alloc((size_t)NMAX * 4);
    float* al_d    = (float*)alloc((size_t)NMAX * 4);
    int*   deg     = (int*)alloc((size_t)NMAX * 4);
    int*   rowptr  = (int*)alloc(((size_t)NMAX + 1) * 4);
    int*   fillc   = (int*)alloc((size_t)NMAX * 4);
    int2*  edata   = (int2*)alloc((size_t)EMAX * 8);
    int*   partials= (int*)alloc(256 * 4);
    float* wvec    = (float*)alloc(256 * 4);
    int*   flag    = (int*)alloc(256 * 4);

    auto csr = [&](const int* ei, int E, int n_dst) {
        hipMemsetAsync(deg,   0, (size_t)n_dst * 4, stream);
        hipMemsetAsync(fillc, 0, (size_t)n_dst * 4, stream);
        const int* srcv = ei;
        const int* dstv = ei + E;
        count_kernel<<<(E + 255) / 256, 256, 0, stream>>>(dstv, E, deg);
        int nb = (n_dst + 1023) / 1024;
        scan_a_kernel<<<nb, 1024, 0, stream>>>(deg, n_dst, rowptr, partials);
        scan_b_kernel<<<1, 64, 0, stream>>>(partials, nb);
        scan_c_kernel<<<(n_dst + 255) / 256, 256, 0, stream>>>(rowptr, partials, n_dst);
        fill_kernel<<<(E + 255) / 256, 256, 0, stream>>>(srcv, dstv, E, al_s, al_d,
                                                         rowptr, fillc, edata);
    };
    auto agg = [&](int n_dst, int first, const void* b1, const void* b2,
                   void* out, size_t out_off) {
        aggregate_kernel<<<(n_dst + 3) / 4, 256, 0, stream>>>(
            rowptr, edata, (const unsigned short*)h_s, acc, n_dst, first,
            b1, b2, out, out_off, flag);
    };

    const int PG = 1024;

    detect_kernel<<<1, 256, 0, stream>>>((const unsigned*)x_t, 4096, flag);

    // ================= target phase =================
    // tt: hs == hd == x_target @ W_tt (full GEMM + both alphas)
    proj_kernel<128><<<PG, 256, 0, stream>>>(
        x_t, W_tt, att_tt_s, att_tt_d, h_s, al_s, al_d, NT, flag);
    csr(ei_tt, Ett, NT);
    agg(NT, 1, nullptr, nullptr, nullptr, 0);

    // dt: hs = x_drug @ W_dt_src (GEMM + al_s); alpha_d = x_t @ (W_dt_dst @ a)
    proj_kernel<128><<<PG, 256, 0, stream>>>(
        x_d, W_dt_src, att_dt_s, nullptr, h_s, al_s, nullptr, ND, flag);
    wvec_kernel<<<1, 128, 0, stream>>>(W_dt_dst, att_dt_d, wvec, 128, flag);
    alpha_mv_kernel<128><<<(NT + 3) / 4, 256, 0, stream>>>(x_t, wvec, al_d, NT, flag);
    csr(ei_dt, Edt, NT);
    agg(NT, 0, b_tt, b_dt, d_out, 0);   // fused: x_target_new -> d_out

    // ================= drug phase =================
    // dd: hs == hd == x_drug @ W_dd
    proj_kernel<128><<<PG, 256, 0, stream>>>(
        x_d, W_dd, att_dd_s, att_dd_d, h_s, al_s, al_d, ND, flag);
    csr(ei_dd, Edd, ND);
    agg(ND, 1, nullptr, nullptr, nullptr, 0);

    // td: alpha_d = x_d @ (W_td_dst @ a); hs = x_target_new @ W_td_src (K=64)
    wvec_kernel<<<1, 128, 0, stream>>>(W_td_dst, att_td_d, wvec, 128, flag);
    alpha_mv_kernel<128><<<(ND + 3) / 4, 256, 0, stream>>>(x_d, wvec, al_d, ND, flag);
    proj_kernel<64><<<PG, 256, 0, stream>>>(
        d_out, W_td_src, att_td_s, nullptr, h_s, al_s, nullptr, NT, flag);
    csr(ei_td, Etd, ND);
    agg(ND, 0, b_dd, b_td, d_out, (size_t)NT * 64);   // x_drug_new
}

// Round 5
// 738.667 us; speedup vs baseline: 1.6923x; 1.5482x over previous
//
#include <hip/hip_runtime.h>
#include <hip/hip_bf16.h>

typedef __hip_bfloat16 bf16;

typedef __bf16 bf16v8 __attribute__((ext_vector_type(8)));
typedef short  s16v8  __attribute__((ext_vector_type(8)));
typedef float  f32v4  __attribute__((ext_vector_type(4)));

__device__ __forceinline__ float bf2f(unsigned short u) {
    return __uint_as_float(((unsigned)u) << 16);
}
__device__ __forceinline__ float ldx(const void* p, size_t i, bool f32) {
    return f32 ? ((const float*)p)[i] : bf2f(((const unsigned short*)p)[i]);
}
__device__ __forceinline__ unsigned short f2bfbits(float f) {
    union { bf16 h; unsigned short u; } cv;
    cv.h = __float2bfloat16(f);
    return cv.u;
}
__device__ __forceinline__ float wave_sum(float v) {
    #pragma unroll
    for (int o = 32; o > 0; o >>= 1) v += __shfl_xor(v, o);
    return v;
}

// ---------------------------------------------------------------------------
// dtype detector: f32 N(0,1) words have IEEE exponent in [100,150];
// bf16-pair words essentially never do. flag[0]=1 -> f32, 0 -> bf16.
// ---------------------------------------------------------------------------
__global__ void detect_kernel(const unsigned* __restrict__ x, int nwords,
                              int* __restrict__ flag)
{
    __shared__ int cnt;
    if (threadIdx.x == 0) cnt = 0;
    __syncthreads();
    int c = 0;
    for (int i = threadIdx.x; i < nwords; i += blockDim.x) {
        unsigned e = (x[i] >> 23) & 0xFFu;
        if (e >= 100u && e <= 150u) c++;
    }
    atomicAdd(&cnt, c);
    __syncthreads();
    if (threadIdx.x == 0) flag[0] = (2 * cnt > nwords) ? 1 : 0;
}

// ---------------------------------------------------------------------------
// MFMA projection: H[N,64] = X[N,K] @ W[K,64] (bf16 H), fused alpha = H@a.
// mfma_f32_16x16x32_bf16. W packed once into LDS in B-frag order, held in
// registers; wave grid-strides over 16-row tiles (4 A-loads + 16 MFMA each).
//   A layout: m=lane&15, k=quad*8+j   (16B contiguous per lane)
//   B layout: n=lane&15, k=quad*8+j
//   D layout: col=lane&15, row=quad*4+reg
// ---------------------------------------------------------------------------
template <int K>
__global__ __launch_bounds__(256) void proj_mfma_kernel(
    const void* __restrict__ X, const void* __restrict__ W,
    const void* __restrict__ a1, const void* __restrict__ a2,
    bf16* __restrict__ H, float* __restrict__ al1, float* __restrict__ al2,
    int N, const int* __restrict__ flag)
{
    constexpr int NKT = K / 32;                 // k-tiles
    __shared__ short Wf[NKT * 4 * 64 * 8];      // [frag(kt,ct)][lane][j]

    const bool f32 = (flag[0] != 0);
    const int tid = threadIdx.x;

    // pack W into B-fragment order (coalesced global read, one-time scatter)
    for (int idx = tid; idx < K * 64; idx += 256) {
        int k = idx >> 6, c = idx & 63;
        float w = ldx(W, idx, f32);
        int kt = k >> 5, quad = (k >> 3) & 3, j = k & 7;
        int ct = c >> 4, n = c & 15;
        Wf[(((kt * 4 + ct) * 64) + quad * 16 + n) * 8 + j] = (short)f2bfbits(w);
    }
    __syncthreads();

    const int wave = tid >> 6, lane = tid & 63;
    const int quad = lane >> 4, n = lane & 15;

    // B fragments -> registers (16B per frag per lane, conflict-free b128)
    s16v8 Bf[NKT][4];
    #pragma unroll
    for (int kt = 0; kt < NKT; ++kt)
        #pragma unroll
        for (int ct = 0; ct < 4; ++ct)
            Bf[kt][ct] = *(const s16v8*)&Wf[((kt * 4 + ct) * 64 + lane) * 8];

    float a1v[4], a2v[4];
    #pragma unroll
    for (int ct = 0; ct < 4; ++ct) {
        a1v[ct] = a1 ? ldx(a1, ct * 16 + n, f32) : 0.f;
        a2v[ct] = a2 ? ldx(a2, ct * 16 + n, f32) : 0.f;
    }

    const int tiles = (N + 15) / 16;
    for (int tb = blockIdx.x * 4 + wave; tb < tiles; tb += gridDim.x * 4) {
        const int r0 = tb * 16;
        const int arow = r0 + n;                     // A-row this lane loads
        const int ars  = (arow < N) ? arow : 0;      // clamp (garbage rows unused)

        f32v4 acc[4];
        #pragma unroll
        for (int ct = 0; ct < 4; ++ct) acc[ct] = (f32v4){0.f, 0.f, 0.f, 0.f};

        #pragma unroll
        for (int kt = 0; kt < NKT; ++kt) {
            s16v8 As;
            if (f32) {
                const float4* xp = (const float4*)X +
                    ((size_t)ars * K + kt * 32 + quad * 8) / 4;
                float4 x0 = xp[0], x1 = xp[1];
                As[0] = (short)f2bfbits(x0.x); As[1] = (short)f2bfbits(x0.y);
                As[2] = (short)f2bfbits(x0.z); As[3] = (short)f2bfbits(x0.w);
                As[4] = (short)f2bfbits(x1.x); As[5] = (short)f2bfbits(x1.y);
                As[6] = (short)f2bfbits(x1.z); As[7] = (short)f2bfbits(x1.w);
            } else {
                As = *(const s16v8*)((const unsigned short*)X +
                    (size_t)ars * K + kt * 32 + quad * 8);
            }
            bf16v8 Ab = __builtin_bit_cast(bf16v8, As);
            #pragma unroll
            for (int ct = 0; ct < 4; ++ct)
                acc[ct] = __builtin_amdgcn_mfma_f32_16x16x32_bf16(
                    Ab, __builtin_bit_cast(bf16v8, Bf[kt][ct]), acc[ct], 0, 0, 0);
        }

        // epilogue: H stores + per-row alpha reduce (rows = quad*4+i)
        #pragma unroll
        for (int i = 0; i < 4; ++i) {
            const int r = r0 + quad * 4 + i;
            const bool rv = (r < N);
            if (rv && H) {
                #pragma unroll
                for (int ct = 0; ct < 4; ++ct)
                    H[(size_t)r * 64 + ct * 16 + n] = __float2bfloat16(acc[ct][i]);
            }
            if (al1) {
                float t = acc[0][i] * a1v[0] + acc[1][i] * a1v[1] +
                          acc[2][i] * a1v[2] + acc[3][i] * a1v[3];
                #pragma unroll
                for (int o = 1; o < 16; o <<= 1) t += __shfl_xor(t, o);
                if (rv && n == 0) al1[r] = t;
            }
            if (al2) {
                float t = acc[0][i] * a2v[0] + acc[1][i] * a2v[1] +
                          acc[2][i] * a2v[2] + acc[3][i] * a2v[3];
                #pragma unroll
                for (int o = 1; o < 16; o <<= 1) t += __shfl_xor(t, o);
                if (rv && n == 0) al2[r] = t;
            }
        }
    }
}

// ---------------------------------------------------------------------------
// Alpha-only path: alpha = x @ (W @ a).
// ---------------------------------------------------------------------------
__global__ void wvec_kernel(const void* __restrict__ W, const void* __restrict__ a,
                            float* __restrict__ wvec, int K, const int* __restrict__ flag)
{
    const bool f32 = (flag[0] != 0);
    int k = blockIdx.x * blockDim.x + threadIdx.x;
    if (k >= K) return;
    float s = 0.f;
    for (int c = 0; c < 64; ++c) s += ldx(W, (size_t)k * 64 + c, f32) * ldx(a, c, f32);
    wvec[k] = s;
}

template <int K>
__global__ __launch_bounds__(256) void alpha_mv_kernel(
    const void* __restrict__ X, const float* __restrict__ wvec,
    float* __restrict__ al, int N, const int* __restrict__ flag)
{
    const bool f32 = (flag[0] != 0);
    const int r    = (blockIdx.x * blockDim.x + threadIdx.x) >> 6;
    const int lane = threadIdx.x & 63;
    if (r >= N) return;
    float v = 0.f;
    #pragma unroll
    for (int k = lane; k < K; k += 64) v += ldx(X, (size_t)r * K + k, f32) * wvec[k];
    v = wave_sum(v);
    if (lane == 0) al[r] = v;
}

// ---------------------------------------------------------------------------
// CSR construction
// ---------------------------------------------------------------------------
__global__ void count_kernel(const int* __restrict__ dst, int E, int* __restrict__ deg)
{
    int e = blockIdx.x * blockDim.x + threadIdx.x;
    if (e < E) atomicAdd(&deg[dst[e]], 1);
}

__global__ __launch_bounds__(1024) void scan_a_kernel(const int* __restrict__ deg, int n,
                                                      int* __restrict__ rowptr,
                                                      int* __restrict__ partials)
{
    __shared__ int sh[1024];
    const int t = threadIdx.x;
    const int i = blockIdx.x * 1024 + t;
    int v = (i < n) ? deg[i] : 0;
    sh[t] = v;
    __syncthreads();
    for (int o = 1; o < 1024; o <<= 1) {
        int u = (t >= o) ? sh[t - o] : 0;
        __syncthreads();
        sh[t] += u;
        __syncthreads();
    }
    if (i < n) rowptr[i + 1] = sh[t];
    if (t == 1023) partials[blockIdx.x] = sh[t];
}

__global__ void scan_b_kernel(int* __restrict__ partials, int nb)
{
    int t = threadIdx.x;
    int v = (t < nb) ? partials[t] : 0;
    int orig = v;
    #pragma unroll
    for (int o = 1; o < 64; o <<= 1) {
        int u = __shfl_up(v, o);
        if (t >= o) v += u;
    }
    v -= orig;  // exclusive
    if (t < nb) partials[t] = v;
}

__global__ void scan_c_kernel(int* __restrict__ rowptr, const int* __restrict__ partials, int n)
{
    int i = blockIdx.x * blockDim.x + threadIdx.x;
    if (i == 0) rowptr[0] = 0;
    if (i < n) rowptr[i + 1] += partials[i >> 10];
}

// fill: edata[slot] = {src, exp(leaky_relu(alpha_s+alpha_d))}
__global__ void fill_kernel(const int* __restrict__ src, const int* __restrict__ dst, int E,
                            const float* __restrict__ as_, const float* __restrict__ ad_,
                            const int* __restrict__ rowptr, int* __restrict__ fillc,
                            int2* __restrict__ edata)
{
    int e = blockIdx.x * blockDim.x + threadIdx.x;
    if (e >= E) return;
    int s = src[e], d = dst[e];
    float l = as_[s] + ad_[d];
    l = (l > 0.f) ? l : 0.2f * l;       // leaky_relu 0.2
    float ew = __expf(l);               // logits bounded; max-subtraction unneeded
    int pos  = atomicAdd(&fillc[d], 1);
    int slot = rowptr[d] + pos;
    edata[slot] = make_int2(s, __float_as_int(ew));
}

// ---------------------------------------------------------------------------
// Pull-mode aggregation, single pass. One wave per dst node; lane = channel.
// Optional fused epilogue: out = dtype(0.5*(acc_prev + r + b1 + b2)).
// ---------------------------------------------------------------------------
__global__ __launch_bounds__(256) void aggregate_kernel(
    const int* __restrict__ rowptr, const int2* __restrict__ edata,
    const unsigned short* __restrict__ HS,   // bf16 bits
    float* __restrict__ acc, int n, int first,
    const void* __restrict__ b1, const void* __restrict__ b2,
    void* __restrict__ out, size_t out_off, const int* __restrict__ flag)
{
    const int gw   = (blockIdx.x * blockDim.x + threadIdx.x) >> 6;
    const int lane = threadIdx.x & 63;
    if (gw >= n) return;

    const int start = rowptr[gw];
    const int end   = rowptr[gw + 1];

    float a0 = 0.f, a1 = 0.f, a2 = 0.f, a3 = 0.f, den = 0.f;
    for (int base = start; base < end; base += 64) {
        int nn = end - base;
        if (nn > 64) nn = 64;
        int s_l = 0; float w_l = 0.f;
        if (lane < nn) {
            int2 ed = edata[base + lane];
            s_l = ed.x;
            w_l = __int_as_float(ed.y);
        }
        den += w_l;
        int j = 0;
        for (; j + 3 < nn; j += 4) {
            int   s0 = __shfl(s_l, j + 0), s1 = __shfl(s_l, j + 1);
            int   s2 = __shfl(s_l, j + 2), s3 = __shfl(s_l, j + 3);
            float w0 = __shfl(w_l, j + 0), w1 = __shfl(w_l, j + 1);
            float w2 = __shfl(w_l, j + 2), w3 = __shfl(w_l, j + 3);
            float h0 = bf2f(HS[(size_t)s0 * 64 + lane]);
            float h1 = bf2f(HS[(size_t)s1 * 64 + lane]);
            float h2 = bf2f(HS[(size_t)s2 * 64 + lane]);
            float h3 = bf2f(HS[(size_t)s3 * 64 + lane]);
            a0 = fmaf(w0, h0, a0); a1 = fmaf(w1, h1, a1);
            a2 = fmaf(w2, h2, a2); a3 = fmaf(w3, h3, a3);
        }
        for (; j < nn; ++j) {
            int   s = __shfl(s_l, j);
            float w = __shfl(w_l, j);
            a0 = fmaf(w, bf2f(HS[(size_t)s * 64 + lane]), a0);
        }
    }
    den = wave_sum(den);
    float r = (a0 + a1 + a2 + a3) / (den + 1e-16f);

    const size_t idx = (size_t)gw * 64 + lane;
    if (out) {
        const bool f32 = (flag[0] != 0);
        float prev = first ? 0.f : acc[idx];
        float v = 0.5f * (prev + r + ldx(b1, lane, f32) + ldx(b2, lane, f32));
        if (f32) ((float*)out)[out_off + idx] = v;
        else     ((bf16*)out)[out_off + idx] = __float2bfloat16(v);
    } else {
        if (first) acc[idx] = r;
        else       acc[idx] += r;
    }
}

// ---------------------------------------------------------------------------
extern "C" void kernel_launch(void* const* d_in, const int* in_sizes, int n_in,
                              void* d_out, int out_size, void* d_ws, size_t ws_size,
                              hipStream_t stream)
{
    const void* x_t = d_in[0];
    const void* x_d = d_in[1];
    const int* ei_tt = (const int*)d_in[2];
    const int* ei_dt = (const int*)d_in[3];
    const int* ei_dd = (const int*)d_in[4];
    const int* ei_td = (const int*)d_in[5];
    const void* W_tt     = d_in[6];
    const void* att_tt_s = d_in[7];
    const void* att_tt_d = d_in[8];
    const void* b_tt     = d_in[9];
    const void* W_dt_src = d_in[10];
    const void* W_dt_dst = d_in[11];
    const void* att_dt_s = d_in[12];
    const void* att_dt_d = d_in[13];
    const void* b_dt     = d_in[14];
    const void* W_dd     = d_in[15];
    const void* att_dd_s = d_in[16];
    const void* att_dd_d = d_in[17];
    const void* b_dd     = d_in[18];
    const void* W_td_src = d_in[19];
    const void* W_td_dst = d_in[20];
    const void* att_td_s = d_in[21];
    const void* att_td_d = d_in[22];
    const void* b_td     = d_in[23];

    const int NT = in_sizes[0] / 128;
    const int ND = in_sizes[1] / 128;
    const int Ett = in_sizes[2] / 2, Edt = in_sizes[3] / 2,
              Edd = in_sizes[4] / 2, Etd = in_sizes[5] / 2;
    const int NMAX = (NT > ND) ? NT : ND;
    int EMAX = Ett;
    if (Edt > EMAX) EMAX = Edt;
    if (Edd > EMAX) EMAX = Edd;
    if (Etd > EMAX) EMAX = Etd;

    // ---- workspace (~27 MB) ----
    char* wptr = (char*)d_ws;
    auto alloc = [&](size_t bytes) -> void* {
        void* p = (void*)wptr;
        wptr += (bytes + 255) & ~(size_t)255;
        return p;
    };
    float* acc     = (float*)alloc((size_t)NMAX * 64 * 4);
    bf16*  h_s     = (bf16*)alloc((size_t)NMAX * 64 * 2);
    float* al_s    = (float*)alloc((size_t)NMAX * 4);
    float* al_d    = (float*)alloc((size_t)NMAX * 4);
    int*   deg     = (int*)alloc((size_t)NMAX * 4);
    int*   rowptr  = (int*)alloc(((size_t)NMAX + 1) * 4);
    int*   fillc   = (int*)alloc((size_t)NMAX * 4);
    int2*  edata   = (int2*)alloc((size_t)EMAX * 8);
    int*   partials= (int*)alloc(256 * 4);
    float* wvec    = (float*)alloc(256 * 4);
    int*   flag    = (int*)alloc(256 * 4);

    auto csr = [&](const int* ei, int E, int n_dst) {
        hipMemsetAsync(deg,   0, (size_t)n_dst * 4, stream);
        hipMemsetAsync(fillc, 0, (size_t)n_dst * 4, stream);
        const int* srcv = ei;
        const int* dstv = ei + E;
        count_kernel<<<(E + 255) / 256, 256, 0, stream>>>(dstv, E, deg);
        int nb = (n_dst + 1023) / 1024;
        scan_a_kernel<<<nb, 1024, 0, stream>>>(deg, n_dst, rowptr, partials);
        scan_b_kernel<<<1, 64, 0, stream>>>(partials, nb);
        scan_c_kernel<<<(n_dst + 255) / 256, 256, 0, stream>>>(rowptr, partials, n_dst);
        fill_kernel<<<(E + 255) / 256, 256, 0, stream>>>(srcv, dstv, E, al_s, al_d,
                                                         rowptr, fillc, edata);
    };
    auto agg = [&](int n_dst, int first, const void* b1, const void* b2,
                   void* out, size_t out_off) {
        aggregate_kernel<<<(n_dst + 3) / 4, 256, 0, stream>>>(
            rowptr, edata, (const unsigned short*)h_s, acc, n_dst, first,
            b1, b2, out, out_off, flag);
    };

    const int PG = 320;   // proj grid (wave-level grid-stride over 16-row tiles)

    detect_kernel<<<1, 256, 0, stream>>>((const unsigned*)x_t, 4096, flag);

    // ================= target phase =================
    // tt: hs == hd == x_target @ W_tt (full GEMM + both alphas)
    proj_mfma_kernel<128><<<PG, 256, 0, stream>>>(
        x_t, W_tt, att_tt_s, att_tt_d, h_s, al_s, al_d, NT, flag);
    csr(ei_tt, Ett, NT);
    agg(NT, 1, nullptr, nullptr, nullptr, 0);

    // dt: hs = x_drug @ W_dt_src (GEMM + al_s); alpha_d = x_t @ (W_dt_dst @ a)
    proj_mfma_kernel<128><<<PG, 256, 0, stream>>>(
        x_d, W_dt_src, att_dt_s, nullptr, h_s, al_s, nullptr, ND, flag);
    wvec_kernel<<<1, 128, 0, stream>>>(W_dt_dst, att_dt_d, wvec, 128, flag);
    alpha_mv_kernel<128><<<(NT + 3) / 4, 256, 0, stream>>>(x_t, wvec, al_d, NT, flag);
    csr(ei_dt, Edt, NT);
    agg(NT, 0, b_tt, b_dt, d_out, 0);   // fused: x_target_new -> d_out

    // ================= drug phase =================
    // dd: hs == hd == x_drug @ W_dd
    proj_mfma_kernel<128><<<PG, 256, 0, stream>>>(
        x_d, W_dd, att_dd_s, att_dd_d, h_s, al_s, al_d, ND, flag);
    csr(ei_dd, Edd, ND);
    agg(ND, 1, nullptr, nullptr, nullptr, 0);

    // td: alpha_d = x_d @ (W_td_dst @ a); hs = x_target_new @ W_td_src (K=64)
    wvec_kernel<<<1, 128, 0, stream>>>(W_td_dst, att_td_d, wvec, 128, flag);
    alpha_mv_kernel<128><<<(ND + 3) / 4, 256, 0, stream>>>(x_d, wvec, al_d, ND, flag);
    proj_mfma_kernel<64><<<PG, 256, 0, stream>>>(
        d_out, W_td_src, att_td_s, nullptr, h_s, al_s, nullptr, NT, flag);
    csr(ei_td, Etd, ND);
    agg(ND, 0, b_dd, b_td, d_out, (size_t)NT * 64);   // x_drug_new
}

// Round 6
// 727.927 us; speedup vs baseline: 1.7172x; 1.0148x over previous
//
#include <hip/hip_runtime.h>
#include <hip/hip_bf16.h>

typedef __hip_bfloat16 bf16;

typedef __bf16 bf16v8 __attribute__((ext_vector_type(8)));
typedef short  s16v8  __attribute__((ext_vector_type(8)));
typedef float  f32v4  __attribute__((ext_vector_type(4)));

__device__ __forceinline__ float bf2f(unsigned short u) {
    return __uint_as_float(((unsigned)u) << 16);
}
__device__ __forceinline__ float ldx(const void* p, size_t i, bool f32) {
    return f32 ? ((const float*)p)[i] : bf2f(((const unsigned short*)p)[i]);
}
__device__ __forceinline__ unsigned short f2bfbits(float f) {
    union { bf16 h; unsigned short u; } cv;
    cv.h = __float2bfloat16(f);
    return cv.u;
}
__device__ __forceinline__ float wave_sum(float v) {
    #pragma unroll
    for (int o = 32; o > 0; o >>= 1) v += __shfl_xor(v, o);
    return v;
}

// ---------------------------------------------------------------------------
// dtype detector: f32 N(0,1) words have IEEE exponent in [100,150];
// bf16-pair words essentially never do. flag[0]=1 -> f32, 0 -> bf16.
// ---------------------------------------------------------------------------
__global__ void detect_kernel(const unsigned* __restrict__ x, int nwords,
                              int* __restrict__ flag)
{
    __shared__ int cnt;
    if (threadIdx.x == 0) cnt = 0;
    __syncthreads();
    int c = 0;
    for (int i = threadIdx.x; i < nwords; i += blockDim.x) {
        unsigned e = (x[i] >> 23) & 0xFFu;
        if (e >= 100u && e <= 150u) c++;
    }
    atomicAdd(&cnt, c);
    __syncthreads();
    if (threadIdx.x == 0) flag[0] = (2 * cnt > nwords) ? 1 : 0;
}

// ---------------------------------------------------------------------------
// MFMA projection: H[N,64] = X[N,K] @ W[K,64] (bf16 H), fused alpha = H@a.
// W held in registers as B-fragments; wave grid-strides over 16-row tiles.
// ---------------------------------------------------------------------------
template <int K>
__global__ __launch_bounds__(256) void proj_mfma_kernel(
    const void* __restrict__ X, const void* __restrict__ W,
    const void* __restrict__ a1, const void* __restrict__ a2,
    bf16* __restrict__ H, float* __restrict__ al1, float* __restrict__ al2,
    int N, const int* __restrict__ flag)
{
    constexpr int NKT = K / 32;                 // k-tiles
    __shared__ short Wf[NKT * 4 * 64 * 8];      // [frag(kt,ct)][lane][j]

    const bool f32 = (flag[0] != 0);
    const int tid = threadIdx.x;

    for (int idx = tid; idx < K * 64; idx += 256) {
        int k = idx >> 6, c = idx & 63;
        float w = ldx(W, idx, f32);
        int kt = k >> 5, quad = (k >> 3) & 3, j = k & 7;
        int ct = c >> 4, n = c & 15;
        Wf[(((kt * 4 + ct) * 64) + quad * 16 + n) * 8 + j] = (short)f2bfbits(w);
    }
    __syncthreads();

    const int wave = tid >> 6, lane = tid & 63;
    const int quad = lane >> 4, n = lane & 15;

    s16v8 Bf[NKT][4];
    #pragma unroll
    for (int kt = 0; kt < NKT; ++kt)
        #pragma unroll
        for (int ct = 0; ct < 4; ++ct)
            Bf[kt][ct] = *(const s16v8*)&Wf[((kt * 4 + ct) * 64 + lane) * 8];

    float a1v[4], a2v[4];
    #pragma unroll
    for (int ct = 0; ct < 4; ++ct) {
        a1v[ct] = a1 ? ldx(a1, ct * 16 + n, f32) : 0.f;
        a2v[ct] = a2 ? ldx(a2, ct * 16 + n, f32) : 0.f;
    }

    const int tiles = (N + 15) / 16;
    for (int tb = blockIdx.x * 4 + wave; tb < tiles; tb += gridDim.x * 4) {
        const int r0 = tb * 16;
        const int arow = r0 + n;
        const int ars  = (arow < N) ? arow : 0;

        f32v4 acc[4];
        #pragma unroll
        for (int ct = 0; ct < 4; ++ct) acc[ct] = (f32v4){0.f, 0.f, 0.f, 0.f};

        #pragma unroll
        for (int kt = 0; kt < NKT; ++kt) {
            s16v8 As;
            if (f32) {
                const float4* xp = (const float4*)X +
                    ((size_t)ars * K + kt * 32 + quad * 8) / 4;
                float4 x0 = xp[0], x1 = xp[1];
                As[0] = (short)f2bfbits(x0.x); As[1] = (short)f2bfbits(x0.y);
                As[2] = (short)f2bfbits(x0.z); As[3] = (short)f2bfbits(x0.w);
                As[4] = (short)f2bfbits(x1.x); As[5] = (short)f2bfbits(x1.y);
                As[6] = (short)f2bfbits(x1.z); As[7] = (short)f2bfbits(x1.w);
            } else {
                As = *(const s16v8*)((const unsigned short*)X +
                    (size_t)ars * K + kt * 32 + quad * 8);
            }
            bf16v8 Ab = __builtin_bit_cast(bf16v8, As);
            #pragma unroll
            for (int ct = 0; ct < 4; ++ct)
                acc[ct] = __builtin_amdgcn_mfma_f32_16x16x32_bf16(
                    Ab, __builtin_bit_cast(bf16v8, Bf[kt][ct]), acc[ct], 0, 0, 0);
        }

        #pragma unroll
        for (int i = 0; i < 4; ++i) {
            const int r = r0 + quad * 4 + i;
            const bool rv = (r < N);
            if (rv && H) {
                #pragma unroll
                for (int ct = 0; ct < 4; ++ct)
                    H[(size_t)r * 64 + ct * 16 + n] = __float2bfloat16(acc[ct][i]);
            }
            if (al1) {
                float t = acc[0][i] * a1v[0] + acc[1][i] * a1v[1] +
                          acc[2][i] * a1v[2] + acc[3][i] * a1v[3];
                #pragma unroll
                for (int o = 1; o < 16; o <<= 1) t += __shfl_xor(t, o);
                if (rv && n == 0) al1[r] = t;
            }
            if (al2) {
                float t = acc[0][i] * a2v[0] + acc[1][i] * a2v[1] +
                          acc[2][i] * a2v[2] + acc[3][i] * a2v[3];
                #pragma unroll
                for (int o = 1; o < 16; o <<= 1) t += __shfl_xor(t, o);
                if (rv && n == 0) al2[r] = t;
            }
        }
    }
}

// ---------------------------------------------------------------------------
// Alpha-only path: alpha = x @ (W @ a).
// ---------------------------------------------------------------------------
__global__ void wvec_kernel(const void* __restrict__ W, const void* __restrict__ a,
                            float* __restrict__ wvec, int K, const int* __restrict__ flag)
{
    const bool f32 = (flag[0] != 0);
    int k = blockIdx.x * blockDim.x + threadIdx.x;
    if (k >= K) return;
    float s = 0.f;
    for (int c = 0; c < 64; ++c) s += ldx(W, (size_t)k * 64 + c, f32) * ldx(a, c, f32);
    wvec[k] = s;
}

template <int K>
__global__ __launch_bounds__(256) void alpha_mv_kernel(
    const void* __restrict__ X, const float* __restrict__ wvec,
    float* __restrict__ al, int N, const int* __restrict__ flag)
{
    const bool f32 = (flag[0] != 0);
    const int r    = (blockIdx.x * blockDim.x + threadIdx.x) >> 6;
    const int lane = threadIdx.x & 63;
    if (r >= N) return;
    float v = 0.f;
    #pragma unroll
    for (int k = lane; k < K; k += 64) v += ldx(X, (size_t)r * K + k, f32) * wvec[k];
    v = wave_sum(v);
    if (lane == 0) al[r] = v;
}

// ---------------------------------------------------------------------------
// CSR construction
// ---------------------------------------------------------------------------
__global__ void count_kernel(const int* __restrict__ dst, int E, int* __restrict__ deg)
{
    int e = blockIdx.x * blockDim.x + threadIdx.x;
    if (e < E) atomicAdd(&deg[dst[e]], 1);
}

__global__ __launch_bounds__(1024) void scan_a_kernel(const int* __restrict__ deg, int n,
                                                      int* __restrict__ rowptr,
                                                      int* __restrict__ partials)
{
    __shared__ int sh[1024];
    const int t = threadIdx.x;
    const int i = blockIdx.x * 1024 + t;
    int v = (i < n) ? deg[i] : 0;
    sh[t] = v;
    __syncthreads();
    for (int o = 1; o < 1024; o <<= 1) {
        int u = (t >= o) ? sh[t - o] : 0;
        __syncthreads();
        sh[t] += u;
        __syncthreads();
    }
    if (i < n) rowptr[i + 1] = sh[t];
    if (t == 1023) partials[blockIdx.x] = sh[t];
}

__global__ void scan_b_kernel(int* __restrict__ partials, int nb)
{
    int t = threadIdx.x;
    int v = (t < nb) ? partials[t] : 0;
    int orig = v;
    #pragma unroll
    for (int o = 1; o < 64; o <<= 1) {
        int u = __shfl_up(v, o);
        if (t >= o) v += u;
    }
    v -= orig;  // exclusive
    if (t < nb) partials[t] = v;
}

__global__ void scan_c_kernel(int* __restrict__ rowptr, const int* __restrict__ partials, int n)
{
    int i = blockIdx.x * blockDim.x + threadIdx.x;
    if (i == 0) rowptr[0] = 0;
    if (i < n) rowptr[i + 1] += partials[i >> 10];
}

// fill: esrc[slot] = src only (4B scatter; weight recomputed in aggregate)
__global__ void fill_kernel(const int* __restrict__ src, const int* __restrict__ dst, int E,
                            const int* __restrict__ rowptr, int* __restrict__ fillc,
                            int* __restrict__ esrc)
{
    int e = blockIdx.x * blockDim.x + threadIdx.x;
    if (e >= E) return;
    int d = dst[e];
    int pos = atomicAdd(&fillc[d], 1);
    esrc[rowptr[d] + pos] = src[e];
}

// ---------------------------------------------------------------------------
// One relation's softmax-weighted sum for dst node gw (lane = channel).
// w = exp(leaky_relu(als[src] + ad)); returns sum(w*HS[src,lane]) / sum(w).
// ---------------------------------------------------------------------------
__device__ __forceinline__ float seg_agg(
    const int* __restrict__ rowptr, const int* __restrict__ esrc,
    const unsigned short* __restrict__ HS, const float* __restrict__ als,
    float ad, int gw, int lane)
{
    const int start = rowptr[gw];
    const int end   = rowptr[gw + 1];

    float a0 = 0.f, a1 = 0.f, a2 = 0.f, a3 = 0.f, den = 0.f;
    for (int base = start; base < end; base += 64) {
        int nn = end - base;
        if (nn > 64) nn = 64;
        int s_l = 0; float w_l = 0.f;
        if (lane < nn) {
            s_l = esrc[base + lane];              // coalesced
            float l = als[s_l] + ad;              // L2-resident gather
            l = (l > 0.f) ? l : 0.2f * l;
            w_l = __expf(l);
        }
        den += w_l;
        int j = 0;
        for (; j + 7 < nn; j += 8) {
            int   s0 = __shfl(s_l, j + 0), s1 = __shfl(s_l, j + 1);
            int   s2 = __shfl(s_l, j + 2), s3 = __shfl(s_l, j + 3);
            int   s4 = __shfl(s_l, j + 4), s5 = __shfl(s_l, j + 5);
            int   s6 = __shfl(s_l, j + 6), s7 = __shfl(s_l, j + 7);
            float w0 = __shfl(w_l, j + 0), w1 = __shfl(w_l, j + 1);
            float w2 = __shfl(w_l, j + 2), w3 = __shfl(w_l, j + 3);
            float w4 = __shfl(w_l, j + 4), w5 = __shfl(w_l, j + 5);
            float w6 = __shfl(w_l, j + 6), w7 = __shfl(w_l, j + 7);
            float h0 = bf2f(HS[(size_t)s0 * 64 + lane]);
            float h1 = bf2f(HS[(size_t)s1 * 64 + lane]);
            float h2 = bf2f(HS[(size_t)s2 * 64 + lane]);
            float h3 = bf2f(HS[(size_t)s3 * 64 + lane]);
            float h4 = bf2f(HS[(size_t)s4 * 64 + lane]);
            float h5 = bf2f(HS[(size_t)s5 * 64 + lane]);
            float h6 = bf2f(HS[(size_t)s6 * 64 + lane]);
            float h7 = bf2f(HS[(size_t)s7 * 64 + lane]);
            a0 = fmaf(w0, h0, a0); a1 = fmaf(w1, h1, a1);
            a2 = fmaf(w2, h2, a2); a3 = fmaf(w3, h3, a3);
            a0 = fmaf(w4, h4, a0); a1 = fmaf(w5, h5, a1);
            a2 = fmaf(w6, h6, a2); a3 = fmaf(w7, h7, a3);
        }
        for (; j < nn; ++j) {
            int   s = __shfl(s_l, j);
            float w = __shfl(w_l, j);
            a0 = fmaf(w, bf2f(HS[(size_t)s * 64 + lane]), a0);
        }
    }
    den = wave_sum(den);
    return (a0 + a1 + a2 + a3) / (den + 1e-16f);
}

// ---------------------------------------------------------------------------
// Fused phase aggregate: out = dtype(0.5*(r1 + r2 + b1 + b2)). One wave/node.
// ---------------------------------------------------------------------------
__global__ __launch_bounds__(256) void agg2_kernel(
    const int* __restrict__ rowptr1, const int* __restrict__ esrc1,
    const unsigned short* __restrict__ HS1, const float* __restrict__ als1,
    const float* __restrict__ ald1,
    const int* __restrict__ rowptr2, const int* __restrict__ esrc2,
    const unsigned short* __restrict__ HS2, const float* __restrict__ als2,
    const float* __restrict__ ald2,
    const void* __restrict__ b1, const void* __restrict__ b2,
    void* __restrict__ out, size_t out_off, int n, const int* __restrict__ flag)
{
    const int gw   = (blockIdx.x * blockDim.x + threadIdx.x) >> 6;
    const int lane = threadIdx.x & 63;
    if (gw >= n) return;

    float r1 = seg_agg(rowptr1, esrc1, HS1, als1, ald1[gw], gw, lane);
    float r2 = seg_agg(rowptr2, esrc2, HS2, als2, ald2[gw], gw, lane);

    const bool f32 = (flag[0] != 0);
    float v = 0.5f * (r1 + r2 + ldx(b1, lane, f32) + ldx(b2, lane, f32));
    const size_t idx = out_off + (size_t)gw * 64 + lane;
    if (f32) ((float*)out)[idx] = v;
    else     ((bf16*)out)[idx] = __float2bfloat16(v);
}

// ---------------------------------------------------------------------------
extern "C" void kernel_launch(void* const* d_in, const int* in_sizes, int n_in,
                              void* d_out, int out_size, void* d_ws, size_t ws_size,
                              hipStream_t stream)
{
    const void* x_t = d_in[0];
    const void* x_d = d_in[1];
    const int* ei_tt = (const int*)d_in[2];
    const int* ei_dt = (const int*)d_in[3];
    const int* ei_dd = (const int*)d_in[4];
    const int* ei_td = (const int*)d_in[5];
    const void* W_tt     = d_in[6];
    const void* att_tt_s = d_in[7];
    const void* att_tt_d = d_in[8];
    const void* b_tt     = d_in[9];
    const void* W_dt_src = d_in[10];
    const void* W_dt_dst = d_in[11];
    const void* att_dt_s = d_in[12];
    const void* att_dt_d = d_in[13];
    const void* b_dt     = d_in[14];
    const void* W_dd     = d_in[15];
    const void* att_dd_s = d_in[16];
    const void* att_dd_d = d_in[17];
    const void* b_dd     = d_in[18];
    const void* W_td_src = d_in[19];
    const void* W_td_dst = d_in[20];
    const void* att_td_s = d_in[21];
    const void* att_td_d = d_in[22];
    const void* b_td     = d_in[23];

    const int NT = in_sizes[0] / 128;
    const int ND = in_sizes[1] / 128;
    const int Ett = in_sizes[2] / 2, Edt = in_sizes[3] / 2,
              Edd = in_sizes[4] / 2, Etd = in_sizes[5] / 2;
    const int NMAX = (NT > ND) ? NT : ND;
    int EMAX = Ett;
    if (Edt > EMAX) EMAX = Edt;
    if (Edd > EMAX) EMAX = Edd;
    if (Etd > EMAX) EMAX = Etd;

    // ---- workspace (~21 MB) ----
    char* wptr = (char*)d_ws;
    auto alloc = [&](size_t bytes) -> void* {
        void* p = (void*)wptr;
        wptr += (bytes + 255) & ~(size_t)255;
        return p;
    };
    bf16*  h1      = (bf16*)alloc((size_t)NMAX * 64 * 2);
    bf16*  h2      = (bf16*)alloc((size_t)NMAX * 64 * 2);
    float* als1    = (float*)alloc((size_t)NMAX * 4);
    float* als2    = (float*)alloc((size_t)NMAX * 4);
    float* ald1    = (float*)alloc((size_t)NMAX * 4);
    float* ald2    = (float*)alloc((size_t)NMAX * 4);
    int*   deg     = (int*)alloc((size_t)NMAX * 4);
    int*   fillc   = (int*)alloc((size_t)NMAX * 4);
    int*   rowptr1 = (int*)alloc(((size_t)NMAX + 1) * 4);
    int*   rowptr2 = (int*)alloc(((size_t)NMAX + 1) * 4);
    int*   esrc1   = (int*)alloc((size_t)EMAX * 4);
    int*   esrc2   = (int*)alloc((size_t)EMAX * 4);
    int*   partials= (int*)alloc(256 * 4);
    float* wvec    = (float*)alloc(256 * 4);
    int*   flag    = (int*)alloc(256 * 4);

    auto csr = [&](const int* ei, int E, int n_dst, int* rowptr, int* esrc) {
        hipMemsetAsync(deg,   0, (size_t)n_dst * 4, stream);
        hipMemsetAsync(fillc, 0, (size_t)n_dst * 4, stream);
        const int* srcv = ei;
        const int* dstv = ei + E;
        count_kernel<<<(E + 255) / 256, 256, 0, stream>>>(dstv, E, deg);
        int nb = (n_dst + 1023) / 1024;
        scan_a_kernel<<<nb, 1024, 0, stream>>>(deg, n_dst, rowptr, partials);
        scan_b_kernel<<<1, 64, 0, stream>>>(partials, nb);
        scan_c_kernel<<<(n_dst + 255) / 256, 256, 0, stream>>>(rowptr, partials, n_dst);
        fill_kernel<<<(E + 255) / 256, 256, 0, stream>>>(srcv, dstv, E,
                                                         rowptr, fillc, esrc);
    };

    const int PG = 320;   // proj grid (wave-level grid-stride over 16-row tiles)

    detect_kernel<<<1, 256, 0, stream>>>((const unsigned*)x_t, 4096, flag);

    // ================= target phase (tt + dt -> x_target_new) =================
    proj_mfma_kernel<128><<<PG, 256, 0, stream>>>(
        x_t, W_tt, att_tt_s, att_tt_d, h1, als1, ald1, NT, flag);
    proj_mfma_kernel<128><<<PG, 256, 0, stream>>>(
        x_d, W_dt_src, att_dt_s, nullptr, h2, als2, nullptr, ND, flag);
    wvec_kernel<<<1, 128, 0, stream>>>(W_dt_dst, att_dt_d, wvec, 128, flag);
    alpha_mv_kernel<128><<<(NT + 3) / 4, 256, 0, stream>>>(x_t, wvec, ald2, NT, flag);
    csr(ei_tt, Ett, NT, rowptr1, esrc1);
    csr(ei_dt, Edt, NT, rowptr2, esrc2);
    agg2_kernel<<<(NT + 3) / 4, 256, 0, stream>>>(
        rowptr1, esrc1, (const unsigned short*)h1, als1, ald1,
        rowptr2, esrc2, (const unsigned short*)h2, als2, ald2,
        b_tt, b_dt, d_out, 0, NT, flag);

    // ================= drug phase (dd + td -> x_drug_new) =================
    proj_mfma_kernel<128><<<PG, 256, 0, stream>>>(
        x_d, W_dd, att_dd_s, att_dd_d, h1, als1, ald1, ND, flag);
    wvec_kernel<<<1, 128, 0, stream>>>(W_td_dst, att_td_d, wvec, 128, flag);
    alpha_mv_kernel<128><<<(ND + 3) / 4, 256, 0, stream>>>(x_d, wvec, ald2, ND, flag);
    proj_mfma_kernel<64><<<PG, 256, 0, stream>>>(
        d_out, W_td_src, att_td_s, nullptr, h2, als2, nullptr, NT, flag);
    csr(ei_dd, Edd, ND, rowptr1, esrc1);
    csr(ei_td, Etd, ND, rowptr2, esrc2);
    agg2_kernel<<<(ND + 3) / 4, 256, 0, stream>>>(
        rowptr1, esrc1, (const unsigned short*)h1, als1, ald1,
        rowptr2, esrc2, (const unsigned short*)h2, als2, ald2,
        b_dd, b_td, d_out, (size_t)NT * 64, ND, flag);
}

// Round 7
// 601.222 us; speedup vs baseline: 2.0791x; 1.2107x over previous
//
#include <hip/hip_runtime.h>
#include <hip/hip_bf16.h>

typedef __hip_bfloat16 bf16;

typedef __bf16 bf16v8 __attribute__((ext_vector_type(8)));
typedef short  s16v8  __attribute__((ext_vector_type(8)));
typedef float  f32v4  __attribute__((ext_vector_type(4)));

__device__ __forceinline__ float bf2f(unsigned short u) {
    return __uint_as_float(((unsigned)u) << 16);
}
__device__ __forceinline__ float ldx(const void* p, size_t i, bool f32) {
    return f32 ? ((const float*)p)[i] : bf2f(((const unsigned short*)p)[i]);
}
__device__ __forceinline__ unsigned short f2bfbits(float f) {
    union { bf16 h; unsigned short u; } cv;
    cv.h = __float2bfloat16(f);
    return cv.u;
}
__device__ __forceinline__ float wave_sum(float v) {
    #pragma unroll
    for (int o = 32; o > 0; o >>= 1) v += __shfl_xor(v, o);
    return v;
}

// ---------------------------------------------------------------------------
// dtype detector (f32 vs bf16 inputs)
// ---------------------------------------------------------------------------
__global__ void detect_kernel(const unsigned* __restrict__ x, int nwords,
                              int* __restrict__ flag)
{
    __shared__ int cnt;
    if (threadIdx.x == 0) cnt = 0;
    __syncthreads();
    int c = 0;
    for (int i = threadIdx.x; i < nwords; i += blockDim.x) {
        unsigned e = (x[i] >> 23) & 0xFFu;
        if (e >= 100u && e <= 150u) c++;
    }
    atomicAdd(&cnt, c);
    __syncthreads();
    if (threadIdx.x == 0) flag[0] = (2 * cnt > nwords) ? 1 : 0;
}

// ---------------------------------------------------------------------------
// Batched CSR over all 4 relations
// ---------------------------------------------------------------------------
struct RelSet {
    const int *src0, *dst0, *src1, *dst1, *src2, *dst2, *src3, *dst3;
    int off1, off2, off3, off4;      // cumulative edge offsets
    int nd0, nd1, nd2, nd3;          // dst-node counts
};

__device__ __forceinline__ void pick(const RelSet& rs, int e, int& r,
                                     const int*& s, const int*& d, int& le)
{
    if (e < rs.off1)      { r = 0; s = rs.src0; d = rs.dst0; le = e; }
    else if (e < rs.off2) { r = 1; s = rs.src1; d = rs.dst1; le = e - rs.off1; }
    else if (e < rs.off3) { r = 2; s = rs.src2; d = rs.dst2; le = e - rs.off2; }
    else                  { r = 3; s = rs.src3; d = rs.dst3; le = e - rs.off3; }
}
__device__ __forceinline__ int ndst_of(const RelSet& rs, int r)
{
    return r == 0 ? rs.nd0 : r == 1 ? rs.nd1 : r == 2 ? rs.nd2 : rs.nd3;
}

__global__ void count_all_kernel(RelSet rs, int* __restrict__ deg4, int NP)
{
    int e = blockIdx.x * blockDim.x + threadIdx.x;
    if (e >= rs.off4) return;
    int r, le; const int *s, *d;
    pick(rs, e, r, s, d, le);
    atomicAdd(&deg4[r * NP + d[le]], 1);
}

__global__ __launch_bounds__(1024) void scan_a_all_kernel(
    RelSet rs, const int* __restrict__ deg4, int NP,
    int* __restrict__ rowptr4, int* __restrict__ partials, int nbmax)
{
    __shared__ int sh[1024];
    const int r = blockIdx.x / nbmax;
    const int chunk = blockIdx.x % nbmax;
    const int n = ndst_of(rs, r);
    const int t = threadIdx.x;
    const int i = chunk * 1024 + t;
    int v = (i < n) ? deg4[r * NP + i] : 0;
    sh[t] = v;
    __syncthreads();
    for (int o = 1; o < 1024; o <<= 1) {
        int u = (t >= o) ? sh[t - o] : 0;
        __syncthreads();
        sh[t] += u;
        __syncthreads();
    }
    if (i < n) rowptr4[r * (NP + 1) + i + 1] = sh[t];
    if (t == 1023) partials[r * 64 + chunk] = sh[t];
}

// 4 independent exclusive scans (wave r -> relation r), <=64 partials each
__global__ void scan_b_all_kernel(RelSet rs, int* __restrict__ partials)
{
    const int r = threadIdx.x >> 6;
    const int t = threadIdx.x & 63;
    const int nb = (ndst_of(rs, r) + 1023) >> 10;
    int v = (t < nb) ? partials[r * 64 + t] : 0;
    int orig = v;
    #pragma unroll
    for (int o = 1; o < 64; o <<= 1) {
        int u = __shfl_up(v, o);
        if ((threadIdx.x & 63) >= o) v += u;
    }
    v -= orig;
    if (t < nb) partials[r * 64 + t] = v;
}

__global__ void scan_c_all_kernel(RelSet rs, int* __restrict__ rowptr4,
                                  const int* __restrict__ partials, int NP, int nc)
{
    const int r = blockIdx.x / nc;
    const int i = (blockIdx.x % nc) * 256 + threadIdx.x;
    const int n = ndst_of(rs, r);
    int* rp = rowptr4 + r * (NP + 1);
    if (i == 0) rp[0] = 0;
    if (i < n) rp[i + 1] += partials[r * 64 + (i >> 10)];
}

__global__ void fill_all_kernel(RelSet rs, const int* __restrict__ rowptr4,
                                int* __restrict__ fillc4,
                                unsigned short* __restrict__ esrc4,
                                int NP, int EP)
{
    int e = blockIdx.x * blockDim.x + threadIdx.x;
    if (e >= rs.off4) return;
    int r, le; const int *s, *d;
    pick(rs, e, r, s, d, le);
    int dd = d[le];
    int pos  = atomicAdd(&fillc4[r * NP + dd], 1);
    int slot = rowptr4[r * (NP + 1) + dd] + pos;
    esrc4[(size_t)r * EP + slot] = (unsigned short)s[le];
}

// ---------------------------------------------------------------------------
// wvec2: wv1 = W1 @ a1, wv2 = W2 @ a2 (both K=128)
// ---------------------------------------------------------------------------
__global__ void wvec2_kernel(const void* __restrict__ W1, const void* __restrict__ a1,
                             const void* __restrict__ W2, const void* __restrict__ a2,
                             float* __restrict__ wv1, float* __restrict__ wv2,
                             const int* __restrict__ flag)
{
    const bool f32 = (flag[0] != 0);
    const int t = threadIdx.x;
    const void* W = (t < 128) ? W1 : W2;
    const void* a = (t < 128) ? a1 : a2;
    const int k = t & 127;
    float s = 0.f;
    for (int c = 0; c < 64; ++c) s += ldx(W, (size_t)k * 64 + c, f32) * ldx(a, c, f32);
    ((t < 128) ? wv1 : wv2)[k] = s;
}

// ---------------------------------------------------------------------------
// Fused MFMA projection pair. Per projection: H = X@W (bf16), al1 = H@a1,
// al2 = H@a2, alx = X@wvx (all optional).
// ---------------------------------------------------------------------------
struct ProjArg {
    const void* X; const void* W; const void* a1; const void* a2;
    const float* wvx;
    bf16* H; float* al1; float* al2; float* alx;
    int N;
};

template <int K>
__device__ __forceinline__ void proj_body(const ProjArg& P, bool f32,
                                          int bid, int nblocks, short* Wf)
{
    constexpr int NKT = K / 32;
    const int tid = threadIdx.x;

    for (int idx = tid; idx < K * 64; idx += 256) {
        int k = idx >> 6, c = idx & 63;
        float w = ldx(P.W, idx, f32);
        int kt = k >> 5, q = (k >> 3) & 3, j = k & 7;
        int ct = c >> 4, n = c & 15;
        Wf[(((kt * 4 + ct) * 64) + q * 16 + n) * 8 + j] = (short)f2bfbits(w);
    }
    __syncthreads();

    const int wave = tid >> 6, lane = tid & 63;
    const int quad = lane >> 4, n = lane & 15;

    s16v8 Bf[NKT][4];
    #pragma unroll
    for (int kt = 0; kt < NKT; ++kt)
        #pragma unroll
        for (int ct = 0; ct < 4; ++ct)
            Bf[kt][ct] = *(const s16v8*)&Wf[((kt * 4 + ct) * 64 + lane) * 8];

    float a1v[4], a2v[4];
    #pragma unroll
    for (int ct = 0; ct < 4; ++ct) {
        a1v[ct] = P.a1 ? ldx(P.a1, ct * 16 + n, f32) : 0.f;
        a2v[ct] = P.a2 ? ldx(P.a2, ct * 16 + n, f32) : 0.f;
    }
    float wv[NKT][8];
    if (P.wvx) {
        #pragma unroll
        for (int kt = 0; kt < NKT; ++kt)
            #pragma unroll
            for (int j = 0; j < 8; ++j)
                wv[kt][j] = P.wvx[kt * 32 + quad * 8 + j];
    }

    const int tiles = (P.N + 15) / 16;
    for (int tb = bid * 4 + wave; tb < tiles; tb += nblocks * 4) {
        const int r0 = tb * 16;
        const int arow = r0 + n;
        const int ars  = (arow < P.N) ? arow : 0;

        f32v4 acc[4];
        #pragma unroll
        for (int ct = 0; ct < 4; ++ct) acc[ct] = (f32v4){0.f, 0.f, 0.f, 0.f};
        float txd = 0.f;

        #pragma unroll
        for (int kt = 0; kt < NKT; ++kt) {
            s16v8 As;
            if (f32) {
                const float4* xp = (const float4*)P.X +
                    ((size_t)ars * K + kt * 32 + quad * 8) / 4;
                float4 x0 = xp[0], x1 = xp[1];
                As[0] = (short)f2bfbits(x0.x); As[1] = (short)f2bfbits(x0.y);
                As[2] = (short)f2bfbits(x0.z); As[3] = (short)f2bfbits(x0.w);
                As[4] = (short)f2bfbits(x1.x); As[5] = (short)f2bfbits(x1.y);
                As[6] = (short)f2bfbits(x1.z); As[7] = (short)f2bfbits(x1.w);
            } else {
                As = *(const s16v8*)((const unsigned short*)P.X +
                    (size_t)ars * K + kt * 32 + quad * 8);
            }
            if (P.wvx) {
                #pragma unroll
                for (int j = 0; j < 8; ++j)
                    txd = fmaf(bf2f((unsigned short)As[j]), wv[kt][j], txd);
            }
            bf16v8 Ab = __builtin_bit_cast(bf16v8, As);
            #pragma unroll
            for (int ct = 0; ct < 4; ++ct)
                acc[ct] = __builtin_amdgcn_mfma_f32_16x16x32_bf16(
                    Ab, __builtin_bit_cast(bf16v8, Bf[kt][ct]), acc[ct], 0, 0, 0);
        }

        if (P.alx) {   // alx[row] = X_row . wvx ; reduce across quads
            txd += __shfl_xor(txd, 16);
            txd += __shfl_xor(txd, 32);
            if (lane < 16 && r0 + lane < P.N) P.alx[r0 + lane] = txd;
        }

        #pragma unroll
        for (int i = 0; i < 4; ++i) {
            const int r = r0 + quad * 4 + i;
            const bool rv = (r < P.N);
            if (rv && P.H) {
                #pragma unroll
                for (int ct = 0; ct < 4; ++ct)
                    P.H[(size_t)r * 64 + ct * 16 + n] = __float2bfloat16(acc[ct][i]);
            }
            if (P.al1) {
                float t = acc[0][i] * a1v[0] + acc[1][i] * a1v[1] +
                          acc[2][i] * a1v[2] + acc[3][i] * a1v[3];
                #pragma unroll
                for (int o = 1; o < 16; o <<= 1) t += __shfl_xor(t, o);
                if (rv && n == 0) P.al1[r] = t;
            }
            if (P.al2) {
                float t = acc[0][i] * a2v[0] + acc[1][i] * a2v[1] +
                          acc[2][i] * a2v[2] + acc[3][i] * a2v[3];
                #pragma unroll
                for (int o = 1; o < 16; o <<= 1) t += __shfl_xor(t, o);
                if (rv && n == 0) P.al2[r] = t;
            }
        }
    }
}

template <int KA, int KB>
__global__ __launch_bounds__(256) void proj2_kernel(ProjArg A, ProjArg B, int nA,
                                                    const int* __restrict__ flag)
{
    __shared__ short Wf[4 * 4 * 64 * 8];   // 16 KB, shared by both branches
    const bool f32 = (flag[0] != 0);
    if ((int)blockIdx.x < nA) proj_body<KA>(A, f32, blockIdx.x, nA, Wf);
    else                      proj_body<KB>(B, f32, blockIdx.x - nA,
                                            gridDim.x - nA, Wf);
}

// ---------------------------------------------------------------------------
// Fused dual-relation softmax aggregation. One wave per dst node; lane=channel.
// Both relations' edge loops interleaved (zero-padded) -> 8 gathers in flight.
// ---------------------------------------------------------------------------
__global__ __launch_bounds__(256) void agg2_kernel(
    const int* __restrict__ rp1, const unsigned short* __restrict__ es1,
    const unsigned short* __restrict__ HS1, const float* __restrict__ als1,
    const float* __restrict__ ald1,
    const int* __restrict__ rp2, const unsigned short* __restrict__ es2,
    const unsigned short* __restrict__ HS2, const float* __restrict__ als2,
    const float* __restrict__ ald2,
    const void* __restrict__ b1, const void* __restrict__ b2,
    void* __restrict__ out, size_t out_off, int n, const int* __restrict__ flag)
{
    const int gw   = (blockIdx.x * blockDim.x + threadIdx.x) >> 6;
    const int lane = threadIdx.x & 63;
    if (gw >= n) return;

    int p1 = rp1[gw], e1 = rp1[gw + 1];
    int p2 = rp2[gw], e2 = rp2[gw + 1];
    const float ad1 = ald1[gw], ad2 = ald2[gw];

    float c10 = 0.f, c11 = 0.f, c12 = 0.f, c13 = 0.f, den1 = 0.f;
    float c20 = 0.f, c21 = 0.f, c22 = 0.f, c23 = 0.f, den2 = 0.f;

    while (p1 < e1 || p2 < e2) {
        int nn1 = e1 - p1; nn1 = nn1 < 0 ? 0 : (nn1 > 64 ? 64 : nn1);
        int nn2 = e2 - p2; nn2 = nn2 < 0 ? 0 : (nn2 > 64 ? 64 : nn2);
        int s1 = 0, s2 = 0; float w1 = 0.f, w2 = 0.f;
        if (lane < nn1) {
            s1 = es1[p1 + lane];
            float l = als1[s1] + ad1;
            l = (l > 0.f) ? l : 0.2f * l;
            w1 = __expf(l);
        }
        if (lane < nn2) {
            s2 = es2[p2 + lane];
            float l = als2[s2] + ad2;
            l = (l > 0.f) ? l : 0.2f * l;
            w2 = __expf(l);
        }
        den1 += w1; den2 += w2;

        const int jm = (nn1 > nn2) ? nn1 : nn2;
        for (int j = 0; j < jm; j += 4) {
            int   a0 = __shfl(s1, j),     a1 = __shfl(s1, j + 1);
            int   a2 = __shfl(s1, j + 2), a3 = __shfl(s1, j + 3);
            int   b0 = __shfl(s2, j),     b1i = __shfl(s2, j + 1);
            int   b2i = __shfl(s2, j + 2), b3 = __shfl(s2, j + 3);
            float u0 = __shfl(w1, j),     u1 = __shfl(w1, j + 1);
            float u2 = __shfl(w1, j + 2), u3 = __shfl(w1, j + 3);
            float v0 = __shfl(w2, j),     v1 = __shfl(w2, j + 1);
            float v2 = __shfl(w2, j + 2), v3 = __shfl(w2, j + 3);
            float h10 = bf2f(HS1[(size_t)a0 * 64 + lane]);
            float h11 = bf2f(HS1[(size_t)a1 * 64 + lane]);
            float h12 = bf2f(HS1[(size_t)a2 * 64 + lane]);
            float h13 = bf2f(HS1[(size_t)a3 * 64 + lane]);
            float h20 = bf2f(HS2[(size_t)b0 * 64 + lane]);
            float h21 = bf2f(HS2[(size_t)b1i * 64 + lane]);
            float h22 = bf2f(HS2[(size_t)b2i * 64 + lane]);
            float h23 = bf2f(HS2[(size_t)b3 * 64 + lane]);
            c10 = fmaf(u0, h10, c10); c11 = fmaf(u1, h11, c11);
            c12 = fmaf(u2, h12, c12); c13 = fmaf(u3, h13, c13);
            c20 = fmaf(v0, h20, c20); c21 = fmaf(v1, h21, c21);
            c22 = fmaf(v2, h22, c22); c23 = fmaf(v3, h23, c23);
        }
        p1 += nn1; p2 += nn2;
    }

    den1 = wave_sum(den1);
    den2 = wave_sum(den2);
    const float r1 = (c10 + c11 + c12 + c13) / (den1 + 1e-16f);
    const float r2 = (c20 + c21 + c22 + c23) / (den2 + 1e-16f);

    const bool f32 = (flag[0] != 0);
    float v = 0.5f * (r1 + r2 + ldx(b1, lane, f32) + ldx(b2, lane, f32));
    const size_t idx = out_off + (size_t)gw * 64 + lane;
    if (f32) ((float*)out)[idx] = v;
    else     ((bf16*)out)[idx] = __float2bfloat16(v);
}

// ---------------------------------------------------------------------------
extern "C" void kernel_launch(void* const* d_in, const int* in_sizes, int n_in,
                              void* d_out, int out_size, void* d_ws, size_t ws_size,
                              hipStream_t stream)
{
    const void* x_t = d_in[0];
    const void* x_d = d_in[1];
    const int* ei_tt = (const int*)d_in[2];
    const int* ei_dt = (const int*)d_in[3];
    const int* ei_dd = (const int*)d_in[4];
    const int* ei_td = (const int*)d_in[5];
    const void* W_tt     = d_in[6];
    const void* att_tt_s = d_in[7];
    const void* att_tt_d = d_in[8];
    const void* b_tt     = d_in[9];
    const void* W_dt_src = d_in[10];
    const void* W_dt_dst = d_in[11];
    const void* att_dt_s = d_in[12];
    const void* att_dt_d = d_in[13];
    const void* b_dt     = d_in[14];
    const void* W_dd     = d_in[15];
    const void* att_dd_s = d_in[16];
    const void* att_dd_d = d_in[17];
    const void* b_dd     = d_in[18];
    const void* W_td_src = d_in[19];
    const void* W_td_dst = d_in[20];
    const void* att_td_s = d_in[21];
    const void* att_td_d = d_in[22];
    const void* b_td     = d_in[23];

    const int NT = in_sizes[0] / 128;
    const int ND = in_sizes[1] / 128;
    const int Ett = in_sizes[2] / 2, Edt = in_sizes[3] / 2,
              Edd = in_sizes[4] / 2, Etd = in_sizes[5] / 2;
    const int NMAX = (NT > ND) ? NT : ND;
    int EMAX = Ett;
    if (Edt > EMAX) EMAX = Edt;
    if (Edd > EMAX) EMAX = Edd;
    if (Etd > EMAX) EMAX = Etd;
    const int TE = Ett + Edt + Edd + Etd;

    // ---- workspace (~23 MB) ----
    char* wptr = (char*)d_ws;
    auto alloc = [&](size_t bytes) -> void* {
        void* p = (void*)wptr;
        wptr += (bytes + 255) & ~(size_t)255;
        return p;
    };
    bf16*  h1      = (bf16*)alloc((size_t)NMAX * 64 * 2);
    bf16*  h2      = (bf16*)alloc((size_t)NMAX * 64 * 2);
    float* als[4]; float* ald[4];
    for (int r = 0; r < 4; ++r) {
        als[r] = (float*)alloc((size_t)NMAX * 4);
        ald[r] = (float*)alloc((size_t)NMAX * 4);
    }
    int*   degfill = (int*)alloc((size_t)8 * NMAX * 4);  // deg4 | fillc4
    int*   deg4    = degfill;
    int*   fillc4  = degfill + 4 * NMAX;
    int*   rowptr4 = (int*)alloc((size_t)4 * (NMAX + 1) * 4);
    unsigned short* esrc4 = (unsigned short*)alloc((size_t)4 * EMAX * 2);
    int*   partials= (int*)alloc(256 * 4);
    float* wvec_dt = (float*)alloc(128 * 4);
    float* wvec_td = (float*)alloc(128 * 4);
    int*   flag    = (int*)alloc(256 * 4);

    RelSet rs;
    rs.src0 = ei_tt; rs.dst0 = ei_tt + Ett;
    rs.src1 = ei_dt; rs.dst1 = ei_dt + Edt;
    rs.src2 = ei_dd; rs.dst2 = ei_dd + Edd;
    rs.src3 = ei_td; rs.dst3 = ei_td + Etd;
    rs.off1 = Ett; rs.off2 = Ett + Edt; rs.off3 = Ett + Edt + Edd; rs.off4 = TE;
    rs.nd0 = NT; rs.nd1 = NT; rs.nd2 = ND; rs.nd3 = ND;

    detect_kernel<<<1, 256, 0, stream>>>((const unsigned*)x_t, 4096, flag);

    // ---- CSR for all 4 relations (6 dispatches) ----
    hipMemsetAsync(degfill, 0, (size_t)8 * NMAX * 4, stream);
    count_all_kernel<<<(TE + 255) / 256, 256, 0, stream>>>(rs, deg4, NMAX);
    const int nbmax = (NMAX + 1023) / 1024;
    scan_a_all_kernel<<<4 * nbmax, 1024, 0, stream>>>(rs, deg4, NMAX, rowptr4,
                                                      partials, nbmax);
    scan_b_all_kernel<<<1, 256, 0, stream>>>(rs, partials);
    const int nc = (NMAX + 255) / 256;
    scan_c_all_kernel<<<4 * nc, 256, 0, stream>>>(rs, rowptr4, partials, NMAX, nc);
    fill_all_kernel<<<(TE + 255) / 256, 256, 0, stream>>>(rs, rowptr4, fillc4,
                                                          esrc4, NMAX, EMAX);

    // ---- wvec for the two alpha-only projections ----
    wvec2_kernel<<<1, 256, 0, stream>>>(W_dt_dst, att_dt_d, W_td_dst, att_td_d,
                                        wvec_dt, wvec_td, flag);

    // ---- phase 1 projections: tt -> h1 (+ald_dt fused), dt -> h2 (+ald_td) ----
    ProjArg Ptt{ x_t, W_tt, att_tt_s, att_tt_d, wvec_dt,
                 h1, als[0], ald[0], ald[1], NT };
    ProjArg Pdt{ x_d, W_dt_src, att_dt_s, nullptr, wvec_td,
                 h2, als[1], nullptr, ald[3], ND };
    proj2_kernel<128, 128><<<512, 256, 0, stream>>>(Ptt, Pdt, 256, flag);

    // ---- target aggregate (tt rel0 + dt rel1) -> x_target_new ----
    agg2_kernel<<<(NT + 3) / 4, 256, 0, stream>>>(
        rowptr4 + 0 * (NMAX + 1), esrc4 + (size_t)0 * EMAX,
        (const unsigned short*)h1, als[0], ald[0],
        rowptr4 + 1 * (NMAX + 1), esrc4 + (size_t)1 * EMAX,
        (const unsigned short*)h2, als[1], ald[1],
        b_tt, b_dt, d_out, 0, NT, flag);

    // ---- phase 2 projections: dd -> h1, td (reads x_target_new) -> h2 ----
    ProjArg Pdd{ x_d, W_dd, att_dd_s, att_dd_d, nullptr,
                 h1, als[2], ald[2], nullptr, ND };
    ProjArg Ptd{ d_out, W_td_src, att_td_s, nullptr, nullptr,
                 h2, als[3], nullptr, nullptr, NT };
    proj2_kernel<128, 64><<<512, 256, 0, stream>>>(Pdd, Ptd, 256, flag);

    // ---- drug aggregate (dd rel2 + td rel3) -> x_drug_new ----
    agg2_kernel<<<(ND + 3) / 4, 256, 0, stream>>>(
        rowptr4 + 2 * (NMAX + 1), esrc4 + (size_t)2 * EMAX,
        (const unsigned short*)h1, als[2], ald[2],
        rowptr4 + 3 * (NMAX + 1), esrc4 + (size_t)3 * EMAX,
        (const unsigned short*)h2, als[3], ald[3],
        b_dd, b_td, d_out, (size_t)NT * 64, ND, flag);
}

// Round 8
// 565.819 us; speedup vs baseline: 2.2092x; 1.0626x over previous
//
#include <hip/hip_runtime.h>
#include <hip/hip_bf16.h>

typedef __hip_bfloat16 bf16;

typedef __bf16 bf16v8 __attribute__((ext_vector_type(8)));
typedef short  s16v8  __attribute__((ext_vector_type(8)));
typedef float  f32v4  __attribute__((ext_vector_type(4)));

__device__ __forceinline__ float bf2f(unsigned short u) {
    return __uint_as_float(((unsigned)u) << 16);
}
__device__ __forceinline__ float ldx(const void* p, size_t i, bool f32) {
    return f32 ? ((const float*)p)[i] : bf2f(((const unsigned short*)p)[i]);
}
__device__ __forceinline__ unsigned short f2bfbits(float f) {
    union { bf16 h; unsigned short u; } cv;
    cv.h = __float2bfloat16(f);
    return cv.u;
}
__device__ __forceinline__ float wave_sum(float v) {
    #pragma unroll
    for (int o = 32; o > 0; o >>= 1) v += __shfl_xor(v, o);
    return v;
}

// ---------------------------------------------------------------------------
// dtype detector (f32 vs bf16 inputs)
// ---------------------------------------------------------------------------
__global__ void detect_kernel(const unsigned* __restrict__ x, int nwords,
                              int* __restrict__ flag)
{
    __shared__ int cnt;
    if (threadIdx.x == 0) cnt = 0;
    __syncthreads();
    int c = 0;
    for (int i = threadIdx.x; i < nwords; i += blockDim.x) {
        unsigned e = (x[i] >> 23) & 0xFFu;
        if (e >= 100u && e <= 150u) c++;
    }
    atomicAdd(&cnt, c);
    __syncthreads();
    if (threadIdx.x == 0) flag[0] = (2 * cnt > nwords) ? 1 : 0;
}

// ---------------------------------------------------------------------------
// Relation set
// ---------------------------------------------------------------------------
struct RelSet {
    const int *src0, *dst0, *src1, *dst1, *src2, *dst2, *src3, *dst3;
    int off1, off2, off3, off4;
    int nd0, nd1, nd2, nd3;
};

__device__ __forceinline__ void pick(const RelSet& rs, int e, int& r,
                                     const int*& s, const int*& d, int& le)
{
    if (e < rs.off1)      { r = 0; s = rs.src0; d = rs.dst0; le = e; }
    else if (e < rs.off2) { r = 1; s = rs.src1; d = rs.dst1; le = e - rs.off1; }
    else if (e < rs.off3) { r = 2; s = rs.src2; d = rs.dst2; le = e - rs.off2; }
    else                  { r = 3; s = rs.src3; d = rs.dst3; le = e - rs.off3; }
}
__device__ __forceinline__ int ndst_of(const RelSet& rs, int r)
{
    return r == 0 ? rs.nd0 : r == 1 ? rs.nd1 : r == 2 ? rs.nd2 : rs.nd3;
}

// ---------------------------------------------------------------------------
// Pass 1: per-dst degree (global atomics, small array) +
//         per-(block, bucket) histogram (LDS) -> hist[bucket*NBLK + block]
// bucket = r*NBr + (dst>>7)
// ---------------------------------------------------------------------------
__global__ __launch_bounds__(256) void pass1_kernel(
    RelSet rs, int* __restrict__ deg4, int* __restrict__ hist,
    int NP, int NBr, int NBLK)
{
    extern __shared__ int lh[];
    const int NBtot = 4 * NBr;
    for (int i = threadIdx.x; i < NBtot; i += 256) lh[i] = 0;
    __syncthreads();
    for (int e = blockIdx.x * 256 + threadIdx.x; e < rs.off4; e += NBLK * 256) {
        int r, le; const int *s, *d;
        pick(rs, e, r, s, d, le);
        int dd = d[le];
        atomicAdd(&deg4[r * NP + dd], 1);
        atomicAdd(&lh[r * NBr + (dd >> 7)], 1);
    }
    __syncthreads();
    for (int i = threadIdx.x; i < NBtot; i += 256)
        hist[i * NBLK + blockIdx.x] = lh[i];
}

// ---------------------------------------------------------------------------
// Generic exclusive scan (3 stages, chunk=1024, up to 1024 chunks)
// ---------------------------------------------------------------------------
__global__ __launch_bounds__(1024) void gscan_a_kernel(
    const int* __restrict__ in, int n, int* __restrict__ excl,
    int* __restrict__ partials)
{
    __shared__ int sh[1024];
    const int t = threadIdx.x;
    const int i = blockIdx.x * 1024 + t;
    int v = (i < n) ? in[i] : 0;
    sh[t] = v;
    __syncthreads();
    for (int o = 1; o < 1024; o <<= 1) {
        int u = (t >= o) ? sh[t - o] : 0;
        __syncthreads();
        sh[t] += u;
        __syncthreads();
    }
    if (i < n) excl[i] = sh[t] - v;
    if (t == 1023) partials[blockIdx.x] = sh[t];
}

__global__ __launch_bounds__(1024) void gscan_b_kernel(int* __restrict__ partials,
                                                       int nb)
{
    __shared__ int sh[1024];
    const int t = threadIdx.x;
    int v = (t < nb) ? partials[t] : 0;
    sh[t] = v;
    __syncthreads();
    for (int o = 1; o < 1024; o <<= 1) {
        int u = (t >= o) ? sh[t - o] : 0;
        __syncthreads();
        sh[t] += u;
        __syncthreads();
    }
    if (t < nb) partials[t] = sh[t] - v;   // exclusive
}

__global__ void gscan_c_kernel(int* __restrict__ excl,
                               const int* __restrict__ partials, int n)
{
    int i = blockIdx.x * blockDim.x + threadIdx.x;
    if (i < n) excl[i] += partials[i >> 10];
}

// ---------------------------------------------------------------------------
// Scatter pass: append (src | dfine<<16) into block-private bucket ranges.
// ---------------------------------------------------------------------------
__global__ __launch_bounds__(256) void scatter_kernel(
    RelSet rs, const int* __restrict__ O, unsigned* __restrict__ temp,
    int NBr, int NBLK)
{
    extern __shared__ int cur[];
    const int NBtot = 4 * NBr;
    for (int i = threadIdx.x; i < NBtot; i += 256)
        cur[i] = O[i * NBLK + blockIdx.x];
    __syncthreads();
    for (int e = blockIdx.x * 256 + threadIdx.x; e < rs.off4; e += NBLK * 256) {
        int r, le; const int *s, *d;
        pick(rs, e, r, s, d, le);
        int dd = d[le];
        int b = r * NBr + (dd >> 7);
        int pos = atomicAdd(&cur[b], 1);
        temp[pos] = (unsigned)s[le] | ((unsigned)(dd & 127) << 16);
    }
}

// ---------------------------------------------------------------------------
// Fill: one block per bucket; slots land in the bucket's contiguous CSR
// window (block-local writes), fine positions from LDS counters.
// ---------------------------------------------------------------------------
__global__ __launch_bounds__(256) void fillb_kernel(
    const int* __restrict__ O, const unsigned* __restrict__ temp,
    const int* __restrict__ rowptr4, unsigned short* __restrict__ esrc4,
    int NBr, int NBLK, int NP, int EP, int TE)
{
    __shared__ int cnt[128];
    const int b = blockIdx.x;
    const int NBtot = 4 * NBr;
    const int r = b / NBr;
    const int dbase = (b % NBr) << 7;
    const int bstart = O[b * NBLK];
    const int bend   = (b + 1 < NBtot) ? O[(b + 1) * NBLK] : TE;
    if (threadIdx.x < 128) cnt[threadIdx.x] = 0;
    __syncthreads();
    const int* rp = rowptr4 + r * (NP + 1);
    unsigned short* es = esrc4 + (size_t)r * EP;
    for (int i = bstart + threadIdx.x; i < bend; i += 256) {
        unsigned u = temp[i];
        int df = (int)(u >> 16);
        int pos = atomicAdd(&cnt[df], 1);
        es[rp[dbase + df] + pos] = (unsigned short)(u & 0xFFFFu);
    }
}

// ---------------------------------------------------------------------------
// Per-relation rowptr scan (4 relations batched)
// ---------------------------------------------------------------------------
__global__ __launch_bounds__(1024) void scan_a_all_kernel(
    RelSet rs, const int* __restrict__ deg4, int NP,
    int* __restrict__ rowptr4, int* __restrict__ partials, int nbmax)
{
    __shared__ int sh[1024];
    const int r = blockIdx.x / nbmax;
    const int chunk = blockIdx.x % nbmax;
    const int n = ndst_of(rs, r);
    const int t = threadIdx.x;
    const int i = chunk * 1024 + t;
    int v = (i < n) ? deg4[r * NP + i] : 0;
    sh[t] = v;
    __syncthreads();
    for (int o = 1; o < 1024; o <<= 1) {
        int u = (t >= o) ? sh[t - o] : 0;
        __syncthreads();
        sh[t] += u;
        __syncthreads();
    }
    if (i < n) rowptr4[r * (NP + 1) + i + 1] = sh[t];
    if (t == 1023) partials[r * 64 + chunk] = sh[t];
}

__global__ void scan_b_all_kernel(RelSet rs, int* __restrict__ partials)
{
    const int r = threadIdx.x >> 6;
    const int t = threadIdx.x & 63;
    const int nb = (ndst_of(rs, r) + 1023) >> 10;
    int v = (t < nb) ? partials[r * 64 + t] : 0;
    int orig = v;
    #pragma unroll
    for (int o = 1; o < 64; o <<= 1) {
        int u = __shfl_up(v, o);
        if ((threadIdx.x & 63) >= o) v += u;
    }
    v -= orig;
    if (t < nb) partials[r * 64 + t] = v;
}

__global__ void scan_c_all_kernel(RelSet rs, int* __restrict__ rowptr4,
                                  const int* __restrict__ partials, int NP, int nc)
{
    const int r = blockIdx.x / nc;
    const int i = (blockIdx.x % nc) * 256 + threadIdx.x;
    const int n = ndst_of(rs, r);
    int* rp = rowptr4 + r * (NP + 1);
    if (i == 0) rp[0] = 0;
    if (i < n) rp[i + 1] += partials[r * 64 + (i >> 10)];
}

// ---------------------------------------------------------------------------
// wvec2: wv1 = W1 @ a1, wv2 = W2 @ a2 (both K=128)
// ---------------------------------------------------------------------------
__global__ void wvec2_kernel(const void* __restrict__ W1, const void* __restrict__ a1,
                             const void* __restrict__ W2, const void* __restrict__ a2,
                             float* __restrict__ wv1, float* __restrict__ wv2,
                             const int* __restrict__ flag)
{
    const bool f32 = (flag[0] != 0);
    const int t = threadIdx.x;
    const void* W = (t < 128) ? W1 : W2;
    const void* a = (t < 128) ? a1 : a2;
    const int k = t & 127;
    float s = 0.f;
    for (int c = 0; c < 64; ++c) s += ldx(W, (size_t)k * 64 + c, f32) * ldx(a, c, f32);
    ((t < 128) ? wv1 : wv2)[k] = s;
}

// ---------------------------------------------------------------------------
// Fused MFMA projection pair
// ---------------------------------------------------------------------------
struct ProjArg {
    const void* X; const void* W; const void* a1; const void* a2;
    const float* wvx;
    bf16* H; float* al1; float* al2; float* alx;
    int N;
};

template <int K>
__device__ __forceinline__ void proj_body(const ProjArg& P, bool f32,
                                          int bid, int nblocks, short* Wf)
{
    constexpr int NKT = K / 32;
    const int tid = threadIdx.x;

    for (int idx = tid; idx < K * 64; idx += 256) {
        int k = idx >> 6, c = idx & 63;
        float w = ldx(P.W, idx, f32);
        int kt = k >> 5, q = (k >> 3) & 3, j = k & 7;
        int ct = c >> 4, n = c & 15;
        Wf[(((kt * 4 + ct) * 64) + q * 16 + n) * 8 + j] = (short)f2bfbits(w);
    }
    __syncthreads();

    const int wave = tid >> 6, lane = tid & 63;
    const int quad = lane >> 4, n = lane & 15;

    s16v8 Bf[NKT][4];
    #pragma unroll
    for (int kt = 0; kt < NKT; ++kt)
        #pragma unroll
        for (int ct = 0; ct < 4; ++ct)
            Bf[kt][ct] = *(const s16v8*)&Wf[((kt * 4 + ct) * 64 + lane) * 8];

    float a1v[4], a2v[4];
    #pragma unroll
    for (int ct = 0; ct < 4; ++ct) {
        a1v[ct] = P.a1 ? ldx(P.a1, ct * 16 + n, f32) : 0.f;
        a2v[ct] = P.a2 ? ldx(P.a2, ct * 16 + n, f32) : 0.f;
    }
    float wv[NKT][8];
    if (P.wvx) {
        #pragma unroll
        for (int kt = 0; kt < NKT; ++kt)
            #pragma unroll
            for (int j = 0; j < 8; ++j)
                wv[kt][j] = P.wvx[kt * 32 + quad * 8 + j];
    }

    const int tiles = (P.N + 15) / 16;
    for (int tb = bid * 4 + wave; tb < tiles; tb += nblocks * 4) {
        const int r0 = tb * 16;
        const int arow = r0 + n;
        const int ars  = (arow < P.N) ? arow : 0;

        f32v4 acc[4];
        #pragma unroll
        for (int ct = 0; ct < 4; ++ct) acc[ct] = (f32v4){0.f, 0.f, 0.f, 0.f};
        float txd = 0.f;

        #pragma unroll
        for (int kt = 0; kt < NKT; ++kt) {
            s16v8 As;
            if (f32) {
                const float4* xp = (const float4*)P.X +
                    ((size_t)ars * K + kt * 32 + quad * 8) / 4;
                float4 x0 = xp[0], x1 = xp[1];
                As[0] = (short)f2bfbits(x0.x); As[1] = (short)f2bfbits(x0.y);
                As[2] = (short)f2bfbits(x0.z); As[3] = (short)f2bfbits(x0.w);
                As[4] = (short)f2bfbits(x1.x); As[5] = (short)f2bfbits(x1.y);
                As[6] = (short)f2bfbits(x1.z); As[7] = (short)f2bfbits(x1.w);
            } else {
                As = *(const s16v8*)((const unsigned short*)P.X +
                    (size_t)ars * K + kt * 32 + quad * 8);
            }
            if (P.wvx) {
                #pragma unroll
                for (int j = 0; j < 8; ++j)
                    txd = fmaf(bf2f((unsigned short)As[j]), wv[kt][j], txd);
            }
            bf16v8 Ab = __builtin_bit_cast(bf16v8, As);
            #pragma unroll
            for (int ct = 0; ct < 4; ++ct)
                acc[ct] = __builtin_amdgcn_mfma_f32_16x16x32_bf16(
                    Ab, __builtin_bit_cast(bf16v8, Bf[kt][ct]), acc[ct], 0, 0, 0);
        }

        if (P.alx) {
            txd += __shfl_xor(txd, 16);
            txd += __shfl_xor(txd, 32);
            if (lane < 16 && r0 + lane < P.N) P.alx[r0 + lane] = txd;
        }

        #pragma unroll
        for (int i = 0; i < 4; ++i) {
            const int r = r0 + quad * 4 + i;
            const bool rv = (r < P.N);
            if (rv && P.H) {
                #pragma unroll
                for (int ct = 0; ct < 4; ++ct)
                    P.H[(size_t)r * 64 + ct * 16 + n] = __float2bfloat16(acc[ct][i]);
            }
            if (P.al1) {
                float t = acc[0][i] * a1v[0] + acc[1][i] * a1v[1] +
                          acc[2][i] * a1v[2] + acc[3][i] * a1v[3];
                #pragma unroll
                for (int o = 1; o < 16; o <<= 1) t += __shfl_xor(t, o);
                if (rv && n == 0) P.al1[r] = t;
            }
            if (P.al2) {
                float t = acc[0][i] * a2v[0] + acc[1][i] * a2v[1] +
                          acc[2][i] * a2v[2] + acc[3][i] * a2v[3];
                #pragma unroll
                for (int o = 1; o < 16; o <<= 1) t += __shfl_xor(t, o);
                if (rv && n == 0) P.al2[r] = t;
            }
        }
    }
}

template <int KA, int KB>
__global__ __launch_bounds__(256) void proj2_kernel(ProjArg A, ProjArg B, int nA,
                                                    const int* __restrict__ flag)
{
    __shared__ short Wf[4 * 4 * 64 * 8];
    const bool f32 = (flag[0] != 0);
    if ((int)blockIdx.x < nA) proj_body<KA>(A, f32, blockIdx.x, nA, Wf);
    else                      proj_body<KB>(B, f32, blockIdx.x - nA,
                                            gridDim.x - nA, Wf);
}

// ---------------------------------------------------------------------------
// Fused dual-relation softmax aggregation. One wave per dst node; lane=channel.
// ---------------------------------------------------------------------------
__global__ __launch_bounds__(256) void agg2_kernel(
    const int* __restrict__ rp1, const unsigned short* __restrict__ es1,
    const unsigned short* __restrict__ HS1, const float* __restrict__ als1,
    const float* __restrict__ ald1,
    const int* __restrict__ rp2, const unsigned short* __restrict__ es2,
    const unsigned short* __restrict__ HS2, const float* __restrict__ als2,
    const float* __restrict__ ald2,
    const void* __restrict__ b1, const void* __restrict__ b2,
    void* __restrict__ out, size_t out_off, int n, const int* __restrict__ flag)
{
    const int gw   = (blockIdx.x * blockDim.x + threadIdx.x) >> 6;
    const int lane = threadIdx.x & 63;
    if (gw >= n) return;

    int p1 = rp1[gw], e1 = rp1[gw + 1];
    int p2 = rp2[gw], e2 = rp2[gw + 1];
    const float ad1 = ald1[gw], ad2 = ald2[gw];

    float c10 = 0.f, c11 = 0.f, c12 = 0.f, c13 = 0.f, den1 = 0.f;
    float c20 = 0.f, c21 = 0.f, c22 = 0.f, c23 = 0.f, den2 = 0.f;

    while (p1 < e1 || p2 < e2) {
        int nn1 = e1 - p1; nn1 = nn1 < 0 ? 0 : (nn1 > 64 ? 64 : nn1);
        int nn2 = e2 - p2; nn2 = nn2 < 0 ? 0 : (nn2 > 64 ? 64 : nn2);
        int s1 = 0, s2 = 0; float w1 = 0.f, w2 = 0.f;
        if (lane < nn1) {
            s1 = es1[p1 + lane];
            float l = als1[s1] + ad1;
            l = (l > 0.f) ? l : 0.2f * l;
            w1 = __expf(l);
        }
        if (lane < nn2) {
            s2 = es2[p2 + lane];
            float l = als2[s2] + ad2;
            l = (l > 0.f) ? l : 0.2f * l;
            w2 = __expf(l);
        }
        den1 += w1; den2 += w2;

        const int jm = (nn1 > nn2) ? nn1 : nn2;
        for (int j = 0; j < jm; j += 4) {
            int   a0 = __shfl(s1, j),     a1 = __shfl(s1, j + 1);
            int   a2 = __shfl(s1, j + 2), a3 = __shfl(s1, j + 3);
            int   b0 = __shfl(s2, j),     b1i = __shfl(s2, j + 1);
            int   b2i = __shfl(s2, j + 2), b3 = __shfl(s2, j + 3);
            float u0 = __shfl(w1, j),     u1 = __shfl(w1, j + 1);
            float u2 = __shfl(w1, j + 2), u3 = __shfl(w1, j + 3);
            float v0 = __shfl(w2, j),     v1 = __shfl(w2, j + 1);
            float v2 = __shfl(w2, j + 2), v3 = __shfl(w2, j + 3);
            float h10 = bf2f(HS1[(size_t)a0 * 64 + lane]);
            float h11 = bf2f(HS1[(size_t)a1 * 64 + lane]);
            float h12 = bf2f(HS1[(size_t)a2 * 64 + lane]);
            float h13 = bf2f(HS1[(size_t)a3 * 64 + lane]);
            float h20 = bf2f(HS2[(size_t)b0 * 64 + lane]);
            float h21 = bf2f(HS2[(size_t)b1i * 64 + lane]);
            float h22 = bf2f(HS2[(size_t)b2i * 64 + lane]);
            float h23 = bf2f(HS2[(size_t)b3 * 64 + lane]);
            c10 = fmaf(u0, h10, c10); c11 = fmaf(u1, h11, c11);
            c12 = fmaf(u2, h12, c12); c13 = fmaf(u3, h13, c13);
            c20 = fmaf(v0, h20, c20); c21 = fmaf(v1, h21, c21);
            c22 = fmaf(v2, h22, c22); c23 = fmaf(v3, h23, c23);
        }
        p1 += nn1; p2 += nn2;
    }

    den1 = wave_sum(den1);
    den2 = wave_sum(den2);
    const float r1 = (c10 + c11 + c12 + c13) / (den1 + 1e-16f);
    const float r2 = (c20 + c21 + c22 + c23) / (den2 + 1e-16f);

    const bool f32 = (flag[0] != 0);
    float v = 0.5f * (r1 + r2 + ldx(b1, lane, f32) + ldx(b2, lane, f32));
    const size_t idx = out_off + (size_t)gw * 64 + lane;
    if (f32) ((float*)out)[idx] = v;
    else     ((bf16*)out)[idx] = __float2bfloat16(v);
}

// ---------------------------------------------------------------------------
extern "C" void kernel_launch(void* const* d_in, const int* in_sizes, int n_in,
                              void* d_out, int out_size, void* d_ws, size_t ws_size,
                              hipStream_t stream)
{
    const void* x_t = d_in[0];
    const void* x_d = d_in[1];
    const int* ei_tt = (const int*)d_in[2];
    const int* ei_dt = (const int*)d_in[3];
    const int* ei_dd = (const int*)d_in[4];
    const int* ei_td = (const int*)d_in[5];
    const void* W_tt     = d_in[6];
    const void* att_tt_s = d_in[7];
    const void* att_tt_d = d_in[8];
    const void* b_tt     = d_in[9];
    const void* W_dt_src = d_in[10];
    const void* W_dt_dst = d_in[11];
    const void* att_dt_s = d_in[12];
    const void* att_dt_d = d_in[13];
    const void* b_dt     = d_in[14];
    const void* W_dd     = d_in[15];
    const void* att_dd_s = d_in[16];
    const void* att_dd_d = d_in[17];
    const void* b_dd     = d_in[18];
    const void* W_td_src = d_in[19];
    const void* W_td_dst = d_in[20];
    const void* att_td_s = d_in[21];
    const void* att_td_d = d_in[22];
    const void* b_td     = d_in[23];

    const int NT = in_sizes[0] / 128;
    const int ND = in_sizes[1] / 128;
    const int Ett = in_sizes[2] / 2, Edt = in_sizes[3] / 2,
              Edd = in_sizes[4] / 2, Etd = in_sizes[5] / 2;
    const int NMAX = (NT > ND) ? NT : ND;
    int EMAX = Ett;
    if (Edt > EMAX) EMAX = Edt;
    if (Edd > EMAX) EMAX = Edd;
    if (Etd > EMAX) EMAX = Etd;
    const int TE = Ett + Edt + Edd + Etd;

    const int NBLK = 128;                    // scatter blocks
    const int NBr  = (NMAX + 127) >> 7;      // buckets per relation
    const int NBtot = 4 * NBr;
    const int HM = NBtot * NBLK;             // histogram matrix size

    // ---- workspace ----
    char* wptr = (char*)d_ws;
    auto alloc = [&](size_t bytes) -> void* {
        void* p = (void*)wptr;
        wptr += (bytes + 255) & ~(size_t)255;
        return p;
    };
    bf16*  h1      = (bf16*)alloc((size_t)NMAX * 64 * 2);
    bf16*  h2      = (bf16*)alloc((size_t)NMAX * 64 * 2);
    float* als[4]; float* ald[4];
    for (int r = 0; r < 4; ++r) {
        als[r] = (float*)alloc((size_t)NMAX * 4);
        ald[r] = (float*)alloc((size_t)NMAX * 4);
    }
    int*   deghist = (int*)alloc(((size_t)4 * NMAX + HM) * 4);  // deg4 | hist
    int*   deg4    = deghist;
    int*   hist    = deghist + 4 * NMAX;
    int*   rowptr4 = (int*)alloc((size_t)4 * (NMAX + 1) * 4);
    unsigned short* esrc4 = (unsigned short*)alloc((size_t)4 * EMAX * 2);
    unsigned* temp = (unsigned*)alloc((size_t)TE * 4);
    int*   partials= (int*)alloc(1024 * 4);
    int*   gpart   = (int*)alloc(1024 * 4);
    float* wvec_dt = (float*)alloc(128 * 4);
    float* wvec_td = (float*)alloc(128 * 4);
    int*   flag    = (int*)alloc(256 * 4);

    RelSet rs;
    rs.src0 = ei_tt; rs.dst0 = ei_tt + Ett;
    rs.src1 = ei_dt; rs.dst1 = ei_dt + Edt;
    rs.src2 = ei_dd; rs.dst2 = ei_dd + Edd;
    rs.src3 = ei_td; rs.dst3 = ei_td + Etd;
    rs.off1 = Ett; rs.off2 = Ett + Edt; rs.off3 = Ett + Edt + Edd; rs.off4 = TE;
    rs.nd0 = NT; rs.nd1 = NT; rs.nd2 = ND; rs.nd3 = ND;

    detect_kernel<<<1, 256, 0, stream>>>((const unsigned*)x_t, 4096, flag);

    // ---- CSR build: histogram -> scans -> locality-aware scatter -> fill ----
    hipMemsetAsync(deghist, 0, ((size_t)4 * NMAX + HM) * 4, stream);
    const size_t ldsB = (size_t)NBtot * 4;
    pass1_kernel<<<NBLK, 256, ldsB, stream>>>(rs, deg4, hist, NMAX, NBr, NBLK);

    // rowptr scan (per relation)
    const int nbmax = (NMAX + 1023) / 1024;
    scan_a_all_kernel<<<4 * nbmax, 1024, 0, stream>>>(rs, deg4, NMAX, rowptr4,
                                                      partials, nbmax);
    scan_b_all_kernel<<<1, 256, 0, stream>>>(rs, partials);
    const int nc = (NMAX + 255) / 256;
    scan_c_all_kernel<<<4 * nc, 256, 0, stream>>>(rs, rowptr4, partials, NMAX, nc);

    // bucket-matrix exclusive scan (in place over hist)
    const int gnb = (HM + 1023) / 1024;
    gscan_a_kernel<<<gnb, 1024, 0, stream>>>(hist, HM, hist, gpart);
    gscan_b_kernel<<<1, 1024, 0, stream>>>(gpart, gnb);
    gscan_c_kernel<<<(HM + 255) / 256, 256, 0, stream>>>(hist, gpart, HM);

    scatter_kernel<<<NBLK, 256, ldsB, stream>>>(rs, hist, temp, NBr, NBLK);
    fillb_kernel<<<NBtot, 256, 0, stream>>>(hist, temp, rowptr4, esrc4,
                                            NBr, NBLK, NMAX, EMAX, TE);

    // ---- wvec for the two alpha-only projections ----
    wvec2_kernel<<<1, 256, 0, stream>>>(W_dt_dst, att_dt_d, W_td_dst, att_td_d,
                                        wvec_dt, wvec_td, flag);

    // ---- phase 1 projections: tt -> h1 (+ald_dt fused), dt -> h2 (+ald_td) ----
    ProjArg Ptt{ x_t, W_tt, att_tt_s, att_tt_d, wvec_dt,
                 h1, als[0], ald[0], ald[1], NT };
    ProjArg Pdt{ x_d, W_dt_src, att_dt_s, nullptr, wvec_td,
                 h2, als[1], nullptr, ald[3], ND };
    proj2_kernel<128, 128><<<512, 256, 0, stream>>>(Ptt, Pdt, 256, flag);

    // ---- target aggregate (tt rel0 + dt rel1) -> x_target_new ----
    agg2_kernel<<<(NT + 3) / 4, 256, 0, stream>>>(
        rowptr4 + 0 * (NMAX + 1), esrc4 + (size_t)0 * EMAX,
        (const unsigned short*)h1, als[0], ald[0],
        rowptr4 + 1 * (NMAX + 1), esrc4 + (size_t)1 * EMAX,
        (const unsigned short*)h2, als[1], ald[1],
        b_tt, b_dt, d_out, 0, NT, flag);

    // ---- phase 2 projections: dd -> h1, td (reads x_target_new) -> h2 ----
    ProjArg Pdd{ x_d, W_dd, att_dd_s, att_dd_d, nullptr,
                 h1, als[2], ald[2], nullptr, ND };
    ProjArg Ptd{ d_out, W_td_src, att_td_s, nullptr, nullptr,
                 h2, als[3], nullptr, nullptr, NT };
    proj2_kernel<128, 64><<<512, 256, 0, stream>>>(Pdd, Ptd, 256, flag);

    // ---- drug aggregate (dd rel2 + td rel3) -> x_drug_new ----
    agg2_kernel<<<(ND + 3) / 4, 256, 0, stream>>>(
        rowptr4 + 2 * (NMAX + 1), esrc4 + (size_t)2 * EMAX,
        (const unsigned short*)h1, als[2], ald[2],
        rowptr4 + 3 * (NMAX + 1), esrc4 + (size_t)3 * EMAX,
        (const unsigned short*)h2, als[3], ald[3],
        b_dd, b_td, d_out, (size_t)NT * 64, ND, flag);
}

// Round 9
// 442.982 us; speedup vs baseline: 2.8218x; 1.2773x over previous
//
#include <hip/hip_runtime.h>
#include <hip/hip_bf16.h>

typedef __hip_bfloat16 bf16;

typedef __bf16 bf16v8 __attribute__((ext_vector_type(8)));
typedef short  s16v8  __attribute__((ext_vector_type(8)));
typedef float  f32v4  __attribute__((ext_vector_type(4)));

__device__ __forceinline__ float bf2f(unsigned short u) {
    return __uint_as_float(((unsigned)u) << 16);
}
__device__ __forceinline__ float ldx(const void* p, size_t i, bool f32) {
    return f32 ? ((const float*)p)[i] : bf2f(((const unsigned short*)p)[i]);
}
__device__ __forceinline__ unsigned short f2bfbits(float f) {
    union { bf16 h; unsigned short u; } cv;
    cv.h = __float2bfloat16(f);
    return cv.u;
}
__device__ __forceinline__ float wave_sum(float v) {
    #pragma unroll
    for (int o = 32; o > 0; o >>= 1) v += __shfl_xor(v, o);
    return v;
}

// ---------------------------------------------------------------------------
// dtype detector (f32 vs bf16 inputs)
// ---------------------------------------------------------------------------
__global__ void detect_kernel(const unsigned* __restrict__ x, int nwords,
                              int* __restrict__ flag)
{
    __shared__ int cnt;
    if (threadIdx.x == 0) cnt = 0;
    __syncthreads();
    int c = 0;
    for (int i = threadIdx.x; i < nwords; i += blockDim.x) {
        unsigned e = (x[i] >> 23) & 0xFFu;
        if (e >= 100u && e <= 150u) c++;
    }
    atomicAdd(&cnt, c);
    __syncthreads();
    if (threadIdx.x == 0) flag[0] = (2 * cnt > nwords) ? 1 : 0;
}

// ---------------------------------------------------------------------------
// Relation set
// ---------------------------------------------------------------------------
struct RelSet {
    const int *src0, *dst0, *src1, *dst1, *src2, *dst2, *src3, *dst3;
    int off1, off2, off3, off4;
    int nd0, nd1, nd2, nd3;
};

__device__ __forceinline__ void pick(const RelSet& rs, int e, int& r,
                                     const int*& s, const int*& d, int& le)
{
    if (e < rs.off1)      { r = 0; s = rs.src0; d = rs.dst0; le = e; }
    else if (e < rs.off2) { r = 1; s = rs.src1; d = rs.dst1; le = e - rs.off1; }
    else if (e < rs.off3) { r = 2; s = rs.src2; d = rs.dst2; le = e - rs.off2; }
    else                  { r = 3; s = rs.src3; d = rs.dst3; le = e - rs.off3; }
}
__device__ __forceinline__ int ndst_of(const RelSet& rs, int r)
{
    return r == 0 ? rs.nd0 : r == 1 ? rs.nd1 : r == 2 ? rs.nd2 : rs.nd3;
}

// ---------------------------------------------------------------------------
// Pass 1: per-(block,bucket) histogram (LDS only; no global atomics).
// Every hist element is overwritten -> no memset needed.
// ---------------------------------------------------------------------------
__global__ __launch_bounds__(256) void pass1_kernel(
    RelSet rs, int* __restrict__ hist, int NBr, int NBLK)
{
    extern __shared__ int lh[];
    const int NBtot = 4 * NBr;
    for (int i = threadIdx.x; i < NBtot; i += 256) lh[i] = 0;
    __syncthreads();
    for (int e = blockIdx.x * 256 + threadIdx.x; e < rs.off4; e += NBLK * 256) {
        int r, le; const int *s, *d;
        pick(rs, e, r, s, d, le);
        atomicAdd(&lh[r * NBr + (d[le] >> 7)], 1);
    }
    __syncthreads();
    for (int i = threadIdx.x; i < NBtot; i += 256)
        hist[i * NBLK + blockIdx.x] = lh[i];
}

// ---------------------------------------------------------------------------
// Generic exclusive scan (3 stages, chunk=1024, up to 1024 chunks)
// ---------------------------------------------------------------------------
__global__ __launch_bounds__(1024) void gscan_a_kernel(
    const int* __restrict__ in, int n, int* __restrict__ excl,
    int* __restrict__ partials)
{
    __shared__ int sh[1024];
    const int t = threadIdx.x;
    const int i = blockIdx.x * 1024 + t;
    int v = (i < n) ? in[i] : 0;
    sh[t] = v;
    __syncthreads();
    for (int o = 1; o < 1024; o <<= 1) {
        int u = (t >= o) ? sh[t - o] : 0;
        __syncthreads();
        sh[t] += u;
        __syncthreads();
    }
    if (i < n) excl[i] = sh[t] - v;
    if (t == 1023) partials[blockIdx.x] = sh[t];
}

__global__ __launch_bounds__(1024) void gscan_b_kernel(int* __restrict__ partials,
                                                       int nb)
{
    __shared__ int sh[1024];
    const int t = threadIdx.x;
    int v = (t < nb) ? partials[t] : 0;
    sh[t] = v;
    __syncthreads();
    for (int o = 1; o < 1024; o <<= 1) {
        int u = (t >= o) ? sh[t - o] : 0;
        __syncthreads();
        sh[t] += u;
        __syncthreads();
    }
    if (t < nb) partials[t] = sh[t] - v;   // exclusive
}

__global__ void gscan_c_kernel(int* __restrict__ excl,
                               const int* __restrict__ partials, int n)
{
    int i = blockIdx.x * blockDim.x + threadIdx.x;
    if (i < n) excl[i] += partials[i >> 10];
}

// ---------------------------------------------------------------------------
// Scatter pass: append (src | dfine<<16) into block-private bucket ranges.
// ---------------------------------------------------------------------------
__global__ __launch_bounds__(256) void scatter_kernel(
    RelSet rs, const int* __restrict__ O, unsigned* __restrict__ temp,
    int NBr, int NBLK)
{
    extern __shared__ int cur[];
    const int NBtot = 4 * NBr;
    for (int i = threadIdx.x; i < NBtot; i += 256)
        cur[i] = O[i * NBLK + blockIdx.x];
    __syncthreads();
    for (int e = blockIdx.x * 256 + threadIdx.x; e < rs.off4; e += NBLK * 256) {
        int r, le; const int *s, *d;
        pick(rs, e, r, s, d, le);
        int dd = d[le];
        int b = r * NBr + (dd >> 7);
        int pos = atomicAdd(&cur[b], 1);
        temp[pos] = (unsigned)s[le] | ((unsigned)(dd & 127) << 16);
    }
}

// ---------------------------------------------------------------------------
// Fill: one block per bucket. Counts its 128 per-dst degrees in LDS,
// scans, writes rowptr (coalesced) AND places edges -- all block-local.
// ---------------------------------------------------------------------------
__global__ __launch_bounds__(256) void fillb_kernel(
    RelSet rs, const int* __restrict__ O, const unsigned* __restrict__ temp,
    int* __restrict__ rowptr4, unsigned short* __restrict__ esrc4,
    int NBr, int NBLK, int NP, int EP, int TE)
{
    __shared__ int cnt[128];
    __shared__ int cur[128];
    const int b = blockIdx.x;
    const int NBtot = 4 * NBr;
    const int r = b / NBr;
    const int bloc = b - r * NBr;
    const int dbase = bloc << 7;
    const int nd = ndst_of(rs, r);
    const int bstart = O[b * NBLK];
    const int bend   = (b + 1 < NBtot) ? O[(b + 1) * NBLK] : TE;
    const int relstart = O[(r * NBr) * NBLK];
    const int relend   = (r + 1 < 4) ? O[((r + 1) * NBr) * NBLK] : TE;
    const int t = threadIdx.x;

    if (t < 128) cnt[t] = 0;
    __syncthreads();
    for (int i = bstart + t; i < bend; i += 256)
        atomicAdd(&cnt[temp[i] >> 16], 1);
    __syncthreads();
    const int orig = (t < 128) ? cnt[t] : 0;
    // inclusive Hillis-Steele scan over the 128 counters
    for (int o = 1; o < 128; o <<= 1) {
        int add = 0;
        if (t < 128 && t >= o) add = cnt[t - o];
        __syncthreads();
        if (t < 128) cnt[t] += add;
        __syncthreads();
    }
    const int bucket_base = bstart - relstart;   // relation-local slot base
    if (t < 128) {
        const int excl = cnt[t] - orig;
        cur[t] = bucket_base + excl;
        const int d = dbase + t;
        if (d < nd) rowptr4[r * (NP + 1) + d] = bucket_base + excl;
    }
    if (t == 0 && bloc == NBr - 1)
        rowptr4[r * (NP + 1) + nd] = relend - relstart;
    __syncthreads();
    unsigned short* es = esrc4 + (size_t)r * EP;
    for (int i = bstart + t; i < bend; i += 256) {
        unsigned u = temp[i];
        int pos = atomicAdd(&cur[u >> 16], 1);
        es[pos] = (unsigned short)(u & 0xFFFFu);
    }
}

// ---------------------------------------------------------------------------
// wvec2: wv1 = W1 @ a1, wv2 = W2 @ a2 (both K=128)
// ---------------------------------------------------------------------------
__global__ void wvec2_kernel(const void* __restrict__ W1, const void* __restrict__ a1,
                             const void* __restrict__ W2, const void* __restrict__ a2,
                             float* __restrict__ wv1, float* __restrict__ wv2,
                             const int* __restrict__ flag)
{
    const bool f32 = (flag[0] != 0);
    const int t = threadIdx.x;
    const void* W = (t < 128) ? W1 : W2;
    const void* a = (t < 128) ? a1 : a2;
    const int k = t & 127;
    float s = 0.f;
    for (int c = 0; c < 64; ++c) s += ldx(W, (size_t)k * 64 + c, f32) * ldx(a, c, f32);
    ((t < 128) ? wv1 : wv2)[k] = s;
}

// ---------------------------------------------------------------------------
// Fused MFMA projection pair
// ---------------------------------------------------------------------------
struct ProjArg {
    const void* X; const void* W; const void* a1; const void* a2;
    const float* wvx;
    bf16* H; float* al1; float* al2; float* alx;
    int N;
};

template <int K>
__device__ __forceinline__ void proj_body(const ProjArg& P, bool f32,
                                          int bid, int nblocks, short* Wf)
{
    constexpr int NKT = K / 32;
    const int tid = threadIdx.x;

    for (int idx = tid; idx < K * 64; idx += 256) {
        int k = idx >> 6, c = idx & 63;
        float w = ldx(P.W, idx, f32);
        int kt = k >> 5, q = (k >> 3) & 3, j = k & 7;
        int ct = c >> 4, n = c & 15;
        Wf[(((kt * 4 + ct) * 64) + q * 16 + n) * 8 + j] = (short)f2bfbits(w);
    }
    __syncthreads();

    const int wave = tid >> 6, lane = tid & 63;
    const int quad = lane >> 4, n = lane & 15;

    s16v8 Bf[NKT][4];
    #pragma unroll
    for (int kt = 0; kt < NKT; ++kt)
        #pragma unroll
        for (int ct = 0; ct < 4; ++ct)
            Bf[kt][ct] = *(const s16v8*)&Wf[((kt * 4 + ct) * 64 + lane) * 8];

    float a1v[4], a2v[4];
    #pragma unroll
    for (int ct = 0; ct < 4; ++ct) {
        a1v[ct] = P.a1 ? ldx(P.a1, ct * 16 + n, f32) : 0.f;
        a2v[ct] = P.a2 ? ldx(P.a2, ct * 16 + n, f32) : 0.f;
    }
    float wv[NKT][8];
    if (P.wvx) {
        #pragma unroll
        for (int kt = 0; kt < NKT; ++kt)
            #pragma unroll
            for (int j = 0; j < 8; ++j)
                wv[kt][j] = P.wvx[kt * 32 + quad * 8 + j];
    }

    const int tiles = (P.N + 15) / 16;
    for (int tb = bid * 4 + wave; tb < tiles; tb += nblocks * 4) {
        const int r0 = tb * 16;
        const int arow = r0 + n;
        const int ars  = (arow < P.N) ? arow : 0;

        f32v4 acc[4];
        #pragma unroll
        for (int ct = 0; ct < 4; ++ct) acc[ct] = (f32v4){0.f, 0.f, 0.f, 0.f};
        float txd = 0.f;

        #pragma unroll
        for (int kt = 0; kt < NKT; ++kt) {
            s16v8 As;
            if (f32) {
                const float4* xp = (const float4*)P.X +
                    ((size_t)ars * K + kt * 32 + quad * 8) / 4;
                float4 x0 = xp[0], x1 = xp[1];
                As[0] = (short)f2bfbits(x0.x); As[1] = (short)f2bfbits(x0.y);
                As[2] = (short)f2bfbits(x0.z); As[3] = (short)f2bfbits(x0.w);
                As[4] = (short)f2bfbits(x1.x); As[5] = (short)f2bfbits(x1.y);
                As[6] = (short)f2bfbits(x1.z); As[7] = (short)f2bfbits(x1.w);
            } else {
                As = *(const s16v8*)((const unsigned short*)P.X +
                    (size_t)ars * K + kt * 32 + quad * 8);
            }
            if (P.wvx) {
                #pragma unroll
                for (int j = 0; j < 8; ++j)
                    txd = fmaf(bf2f((unsigned short)As[j]), wv[kt][j], txd);
            }
            bf16v8 Ab = __builtin_bit_cast(bf16v8, As);
            #pragma unroll
            for (int ct = 0; ct < 4; ++ct)
                acc[ct] = __builtin_amdgcn_mfma_f32_16x16x32_bf16(
                    Ab, __builtin_bit_cast(bf16v8, Bf[kt][ct]), acc[ct], 0, 0, 0);
        }

        if (P.alx) {
            txd += __shfl_xor(txd, 16);
            txd += __shfl_xor(txd, 32);
            if (lane < 16 && r0 + lane < P.N) P.alx[r0 + lane] = txd;
        }

        #pragma unroll
        for (int i = 0; i < 4; ++i) {
            const int r = r0 + quad * 4 + i;
            const bool rv = (r < P.N);
            if (rv && P.H) {
                #pragma unroll
                for (int ct = 0; ct < 4; ++ct)
                    P.H[(size_t)r * 64 + ct * 16 + n] = __float2bfloat16(acc[ct][i]);
            }
            if (P.al1) {
                float t = acc[0][i] * a1v[0] + acc[1][i] * a1v[1] +
                          acc[2][i] * a1v[2] + acc[3][i] * a1v[3];
                #pragma unroll
                for (int o = 1; o < 16; o <<= 1) t += __shfl_xor(t, o);
                if (rv && n == 0) P.al1[r] = t;
            }
            if (P.al2) {
                float t = acc[0][i] * a2v[0] + acc[1][i] * a2v[1] +
                          acc[2][i] * a2v[2] + acc[3][i] * a2v[3];
                #pragma unroll
                for (int o = 1; o < 16; o <<= 1) t += __shfl_xor(t, o);
                if (rv && n == 0) P.al2[r] = t;
            }
        }
    }
}

template <int KA, int KB>
__global__ __launch_bounds__(256) void proj2_kernel(ProjArg A, ProjArg B, int nA,
                                                    const int* __restrict__ flag)
{
    __shared__ short Wf[4 * 4 * 64 * 8];
    const bool f32 = (flag[0] != 0);
    if ((int)blockIdx.x < nA) proj_body<KA>(A, f32, blockIdx.x, nA, Wf);
    else                      proj_body<KB>(B, f32, blockIdx.x - nA,
                                            gridDim.x - nA, Wf);
}

// ---------------------------------------------------------------------------
// Fused dual-relation softmax aggregation. One wave per dst node; lane=channel.
// ---------------------------------------------------------------------------
__global__ __launch_bounds__(256) void agg2_kernel(
    const int* __restrict__ rp1, const unsigned short* __restrict__ es1,
    const unsigned short* __restrict__ HS1, const float* __restrict__ als1,
    const float* __restrict__ ald1,
    const int* __restrict__ rp2, const unsigned short* __restrict__ es2,
    const unsigned short* __restrict__ HS2, const float* __restrict__ als2,
    const float* __restrict__ ald2,
    const void* __restrict__ b1, const void* __restrict__ b2,
    void* __restrict__ out, size_t out_off, int n, const int* __restrict__ flag)
{
    const int gw   = (blockIdx.x * blockDim.x + threadIdx.x) >> 6;
    const int lane = threadIdx.x & 63;
    if (gw >= n) return;

    int p1 = rp1[gw], e1 = rp1[gw + 1];
    int p2 = rp2[gw], e2 = rp2[gw + 1];
    const float ad1 = ald1[gw], ad2 = ald2[gw];

    float c10 = 0.f, c11 = 0.f, c12 = 0.f, c13 = 0.f, den1 = 0.f;
    float c20 = 0.f, c21 = 0.f, c22 = 0.f, c23 = 0.f, den2 = 0.f;

    while (p1 < e1 || p2 < e2) {
        int nn1 = e1 - p1; nn1 = nn1 < 0 ? 0 : (nn1 > 64 ? 64 : nn1);
        int nn2 = e2 - p2; nn2 = nn2 < 0 ? 0 : (nn2 > 64 ? 64 : nn2);
        int s1 = 0, s2 = 0; float w1 = 0.f, w2 = 0.f;
        if (lane < nn1) {
            s1 = es1[p1 + lane];
            float l = als1[s1] + ad1;
            l = (l > 0.f) ? l : 0.2f * l;
            w1 = __expf(l);
        }
        if (lane < nn2) {
            s2 = es2[p2 + lane];
            float l = als2[s2] + ad2;
            l = (l > 0.f) ? l : 0.2f * l;
            w2 = __expf(l);
        }
        den1 += w1; den2 += w2;

        const int jm = (nn1 > nn2) ? nn1 : nn2;
        for (int j = 0; j < jm; j += 4) {
            int   a0 = __shfl(s1, j),     a1 = __shfl(s1, j + 1);
            int   a2 = __shfl(s1, j + 2), a3 = __shfl(s1, j + 3);
            int   b0 = __shfl(s2, j),     b1i = __shfl(s2, j + 1);
            int   b2i = __shfl(s2, j + 2), b3 = __shfl(s2, j + 3);
            float u0 = __shfl(w1, j),     u1 = __shfl(w1, j + 1);
            float u2 = __shfl(w1, j + 2), u3 = __shfl(w1, j + 3);
            float v0 = __shfl(w2, j),     v1 = __shfl(w2, j + 1);
            float v2 = __shfl(w2, j + 2), v3 = __shfl(w2, j + 3);
            float h10 = bf2f(HS1[(size_t)a0 * 64 + lane]);
            float h11 = bf2f(HS1[(size_t)a1 * 64 + lane]);
            float h12 = bf2f(HS1[(size_t)a2 * 64 + lane]);
            float h13 = bf2f(HS1[(size_t)a3 * 64 + lane]);
            float h20 = bf2f(HS2[(size_t)b0 * 64 + lane]);
            float h21 = bf2f(HS2[(size_t)b1i * 64 + lane]);
            float h22 = bf2f(HS2[(size_t)b2i * 64 + lane]);
            float h23 = bf2f(HS2[(size_t)b3 * 64 + lane]);
            c10 = fmaf(u0, h10, c10); c11 = fmaf(u1, h11, c11);
            c12 = fmaf(u2, h12, c12); c13 = fmaf(u3, h13, c13);
            c20 = fmaf(v0, h20, c20); c21 = fmaf(v1, h21, c21);
            c22 = fmaf(v2, h22, c22); c23 = fmaf(v3, h23, c23);
        }
        p1 += nn1; p2 += nn2;
    }

    den1 = wave_sum(den1);
    den2 = wave_sum(den2);
    const float r1 = (c10 + c11 + c12 + c13) / (den1 + 1e-16f);
    const float r2 = (c20 + c21 + c22 + c23) / (den2 + 1e-16f);

    const bool f32 = (flag[0] != 0);
    float v = 0.5f * (r1 + r2 + ldx(b1, lane, f32) + ldx(b2, lane, f32));
    const size_t idx = out_off + (size_t)gw * 64 + lane;
    if (f32) ((float*)out)[idx] = v;
    else     ((bf16*)out)[idx] = __float2bfloat16(v);
}

// ---------------------------------------------------------------------------
extern "C" void kernel_launch(void* const* d_in, const int* in_sizes, int n_in,
                              void* d_out, int out_size, void* d_ws, size_t ws_size,
                              hipStream_t stream)
{
    const void* x_t = d_in[0];
    const void* x_d = d_in[1];
    const int* ei_tt = (const int*)d_in[2];
    const int* ei_dt = (const int*)d_in[3];
    const int* ei_dd = (const int*)d_in[4];
    const int* ei_td = (const int*)d_in[5];
    const void* W_tt     = d_in[6];
    const void* att_tt_s = d_in[7];
    const void* att_tt_d = d_in[8];
    const void* b_tt     = d_in[9];
    const void* W_dt_src = d_in[10];
    const void* W_dt_dst = d_in[11];
    const void* att_dt_s = d_in[12];
    const void* att_dt_d = d_in[13];
    const void* b_dt     = d_in[14];
    const void* W_dd     = d_in[15];
    const void* att_dd_s = d_in[16];
    const void* att_dd_d = d_in[17];
    const void* b_dd     = d_in[18];
    const void* W_td_src = d_in[19];
    const void* W_td_dst = d_in[20];
    const void* att_td_s = d_in[21];
    const void* att_td_d = d_in[22];
    const void* b_td     = d_in[23];

    const int NT = in_sizes[0] / 128;
    const int ND = in_sizes[1] / 128;
    const int Ett = in_sizes[2] / 2, Edt = in_sizes[3] / 2,
              Edd = in_sizes[4] / 2, Etd = in_sizes[5] / 2;
    const int NMAX = (NT > ND) ? NT : ND;
    int EMAX = Ett;
    if (Edt > EMAX) EMAX = Edt;
    if (Edd > EMAX) EMAX = Edd;
    if (Etd > EMAX) EMAX = Etd;
    const int TE = Ett + Edt + Edd + Etd;

    const int NBLK = 128;                    // histogram/scatter blocks
    const int NBr  = (NMAX + 127) >> 7;      // buckets per relation
    const int NBtot = 4 * NBr;
    const int HM = NBtot * NBLK;             // histogram matrix size

    // ---- workspace ----
    char* wptr = (char*)d_ws;
    auto alloc = [&](size_t bytes) -> void* {
        void* p = (void*)wptr;
        wptr += (bytes + 255) & ~(size_t)255;
        return p;
    };
    bf16*  h1      = (bf16*)alloc((size_t)NMAX * 64 * 2);
    bf16*  h2      = (bf16*)alloc((size_t)NMAX * 64 * 2);
    float* als[4]; float* ald[4];
    for (int r = 0; r < 4; ++r) {
        als[r] = (float*)alloc((size_t)NMAX * 4);
        ald[r] = (float*)alloc((size_t)NMAX * 4);
    }
    int*   hist    = (int*)alloc((size_t)HM * 4);
    int*   rowptr4 = (int*)alloc((size_t)4 * (NMAX + 1) * 4);
    unsigned short* esrc4 = (unsigned short*)alloc((size_t)4 * EMAX * 2);
    unsigned* temp = (unsigned*)alloc((size_t)TE * 4);
    int*   gpart   = (int*)alloc(1024 * 4);
    float* wvec_dt = (float*)alloc(128 * 4);
    float* wvec_td = (float*)alloc(128 * 4);
    int*   flag    = (int*)alloc(256 * 4);

    RelSet rs;
    rs.src0 = ei_tt; rs.dst0 = ei_tt + Ett;
    rs.src1 = ei_dt; rs.dst1 = ei_dt + Edt;
    rs.src2 = ei_dd; rs.dst2 = ei_dd + Edd;
    rs.src3 = ei_td; rs.dst3 = ei_td + Etd;
    rs.off1 = Ett; rs.off2 = Ett + Edt; rs.off3 = Ett + Edt + Edd; rs.off4 = TE;
    rs.nd0 = NT; rs.nd1 = NT; rs.nd2 = ND; rs.nd3 = ND;

    detect_kernel<<<1, 256, 0, stream>>>((const unsigned*)x_t, 4096, flag);

    // ---- CSR build: LDS histogram -> scan -> scatter -> fill(+rowptr) ----
    const size_t ldsB = (size_t)NBtot * 4;
    pass1_kernel<<<NBLK, 256, ldsB, stream>>>(rs, hist, NBr, NBLK);

    const int gnb = (HM + 1023) / 1024;
    gscan_a_kernel<<<gnb, 1024, 0, stream>>>(hist, HM, hist, gpart);
    gscan_b_kernel<<<1, 1024, 0, stream>>>(gpart, gnb);
    gscan_c_kernel<<<(HM + 255) / 256, 256, 0, stream>>>(hist, gpart, HM);

    scatter_kernel<<<NBLK, 256, ldsB, stream>>>(rs, hist, temp, NBr, NBLK);
    fillb_kernel<<<NBtot, 256, 0, stream>>>(rs, hist, temp, rowptr4, esrc4,
                                            NBr, NBLK, NMAX, EMAX, TE);

    // ---- wvec for the two alpha-only projections ----
    wvec2_kernel<<<1, 256, 0, stream>>>(W_dt_dst, att_dt_d, W_td_dst, att_td_d,
                                        wvec_dt, wvec_td, flag);

    // ---- phase 1 projections: tt -> h1 (+ald_dt fused), dt -> h2 (+ald_td) ----
    ProjArg Ptt{ x_t, W_tt, att_tt_s, att_tt_d, wvec_dt,
                 h1, als[0], ald[0], ald[1], NT };
    ProjArg Pdt{ x_d, W_dt_src, att_dt_s, nullptr, wvec_td,
                 h2, als[1], nullptr, ald[3], ND };
    proj2_kernel<128, 128><<<512, 256, 0, stream>>>(Ptt, Pdt, 256, flag);

    // ---- target aggregate (tt rel0 + dt rel1) -> x_target_new ----
    agg2_kernel<<<(NT + 3) / 4, 256, 0, stream>>>(
        rowptr4 + 0 * (NMAX + 1), esrc4 + (size_t)0 * EMAX,
        (const unsigned short*)h1, als[0], ald[0],
        rowptr4 + 1 * (NMAX + 1), esrc4 + (size_t)1 * EMAX,
        (const unsigned short*)h2, als[1], ald[1],
        b_tt, b_dt, d_out, 0, NT, flag);

    // ---- phase 2 projections: dd -> h1, td (reads x_target_new) -> h2 ----
    ProjArg Pdd{ x_d, W_dd, att_dd_s, att_dd_d, nullptr,
                 h1, als[2], ald[2], nullptr, ND };
    ProjArg Ptd{ d_out, W_td_src, att_td_s, nullptr, nullptr,
                 h2, als[3], nullptr, nullptr, NT };
    proj2_kernel<128, 64><<<512, 256, 0, stream>>>(Pdd, Ptd, 256, flag);

    // ---- drug aggregate (dd rel2 + td rel3) -> x_drug_new ----
    agg2_kernel<<<(ND + 3) / 4, 256, 0, stream>>>(
        rowptr4 + 2 * (NMAX + 1), esrc4 + (size_t)2 * EMAX,
        (const unsigned short*)h1, als[2], ald[2],
        rowptr4 + 3 * (NMAX + 1), esrc4 + (size_t)3 * EMAX,
        (const unsigned short*)h2, als[3], ald[3],
        b_dd, b_td, d_out, (size_t)NT * 64, ND, flag);
}

// Round 10
// 391.485 us; speedup vs baseline: 3.1930x; 1.1315x over previous
//
#include <hip/hip_runtime.h>
#include <hip/hip_bf16.h>

typedef __hip_bfloat16 bf16;

typedef __bf16 bf16v8 __attribute__((ext_vector_type(8)));
typedef short  s16v8  __attribute__((ext_vector_type(8)));
typedef float  f32v4  __attribute__((ext_vector_type(4)));

#define NBLK  256      // edge-pass blocks (power of 2)
#define NBLKL 8        // log2(NBLK)

__device__ __forceinline__ float bf2f(unsigned short u) {
    return __uint_as_float(((unsigned)u) << 16);
}
__device__ __forceinline__ float ldx(const void* p, size_t i, bool f32) {
    return f32 ? ((const float*)p)[i] : bf2f(((const unsigned short*)p)[i]);
}
__device__ __forceinline__ unsigned short f2bfbits(float f) {
    union { bf16 h; unsigned short u; } cv;
    cv.h = __float2bfloat16(f);
    return cv.u;
}
__device__ __forceinline__ float wave_sum(float v) {
    #pragma unroll
    for (int o = 32; o > 0; o >>= 1) v += __shfl_xor(v, o);
    return v;
}
// logical (bucket-major) -> physical (block-major) index for the hist matrix
__device__ __forceinline__ int physidx(int l, int NBtot) {
    return (l & (NBLK - 1)) * NBtot + (l >> NBLKL);
}

// ---------------------------------------------------------------------------
// dtype detector (f32 vs bf16 inputs)
// ---------------------------------------------------------------------------
__global__ void detect_kernel(const unsigned* __restrict__ x, int nwords,
                              int* __restrict__ flag)
{
    __shared__ int cnt;
    if (threadIdx.x == 0) cnt = 0;
    __syncthreads();
    int c = 0;
    for (int i = threadIdx.x; i < nwords; i += blockDim.x) {
        unsigned e = (x[i] >> 23) & 0xFFu;
        if (e >= 100u && e <= 150u) c++;
    }
    atomicAdd(&cnt, c);
    __syncthreads();
    if (threadIdx.x == 0) flag[0] = (2 * cnt > nwords) ? 1 : 0;
}

// ---------------------------------------------------------------------------
// Relation set
// ---------------------------------------------------------------------------
struct RelSet {
    const int *src0, *dst0, *src1, *dst1, *src2, *dst2, *src3, *dst3;
    int off1, off2, off3, off4;
    int nd0, nd1, nd2, nd3;
};

__device__ __forceinline__ void pick(const RelSet& rs, int e, int& r,
                                     const int*& s, const int*& d, int& le)
{
    if (e < rs.off1)      { r = 0; s = rs.src0; d = rs.dst0; le = e; }
    else if (e < rs.off2) { r = 1; s = rs.src1; d = rs.dst1; le = e - rs.off1; }
    else if (e < rs.off3) { r = 2; s = rs.src2; d = rs.dst2; le = e - rs.off2; }
    else                  { r = 3; s = rs.src3; d = rs.dst3; le = e - rs.off3; }
}
__device__ __forceinline__ int ndst_of(const RelSet& rs, int r)
{
    return r == 0 ? rs.nd0 : r == 1 ? rs.nd1 : r == 2 ? rs.nd2 : rs.nd3;
}

// ---------------------------------------------------------------------------
// Pass 1: per-(block,bucket) LDS histogram -> hist[block*NBtot + bucket]
// (block-major: coalesced, block-local lines; no memset needed)
// ---------------------------------------------------------------------------
__global__ __launch_bounds__(1024) void pass1_kernel(
    RelSet rs, int* __restrict__ hist, int NBr)
{
    extern __shared__ int lh[];
    const int NBtot = 4 * NBr;
    for (int i = threadIdx.x; i < NBtot; i += 1024) lh[i] = 0;
    __syncthreads();
    for (int e = blockIdx.x * 1024 + threadIdx.x; e < rs.off4; e += NBLK * 1024) {
        int r, le; const int *s, *d;
        pick(rs, e, r, s, d, le);
        atomicAdd(&lh[r * NBr + (d[le] >> 7)], 1);
    }
    __syncthreads();
    for (int i = threadIdx.x; i < NBtot; i += 1024)
        hist[blockIdx.x * NBtot + i] = lh[i];
}

// ---------------------------------------------------------------------------
// Exclusive scan over the hist matrix in LOGICAL (bucket-major) order,
// physical layout block-major. 4096 logical elems per scan block.
// ---------------------------------------------------------------------------
__global__ __launch_bounds__(1024) void gscan_a_kernel(
    int* __restrict__ buf, int n, int NBtot, int* __restrict__ partials)
{
    __shared__ int sh[1024];
    const int t = threadIdx.x;
    const int base = blockIdx.x * 4096 + t * 4;
    int p0 = 0, p1 = 0, p2 = 0, p3 = 0;
    int v0 = 0, v1 = 0, v2 = 0, v3 = 0;
    if (base < n)     { p0 = physidx(base,     NBtot); v0 = buf[p0]; }
    if (base + 1 < n) { p1 = physidx(base + 1, NBtot); v1 = buf[p1]; }
    if (base + 2 < n) { p2 = physidx(base + 2, NBtot); v2 = buf[p2]; }
    if (base + 3 < n) { p3 = physidx(base + 3, NBtot); v3 = buf[p3]; }
    const int tsum = v0 + v1 + v2 + v3;
    sh[t] = tsum;
    __syncthreads();
    for (int o = 1; o < 1024; o <<= 1) {
        int u = (t >= o) ? sh[t - o] : 0;
        __syncthreads();
        sh[t] += u;
        __syncthreads();
    }
    const int texcl = sh[t] - tsum;
    if (base < n)     buf[p0] = texcl;
    if (base + 1 < n) buf[p1] = texcl + v0;
    if (base + 2 < n) buf[p2] = texcl + v0 + v1;
    if (base + 3 < n) buf[p3] = texcl + v0 + v1 + v2;
    if (t == 1023) partials[blockIdx.x] = sh[t];
}

__global__ __launch_bounds__(1024) void gscan_b_kernel(int* __restrict__ partials,
                                                       int nb)
{
    __shared__ int sh[1024];
    const int t = threadIdx.x;
    int v = (t < nb) ? partials[t] : 0;
    sh[t] = v;
    __syncthreads();
    for (int o = 1; o < 1024; o <<= 1) {
        int u = (t >= o) ? sh[t - o] : 0;
        __syncthreads();
        sh[t] += u;
        __syncthreads();
    }
    if (t < nb) partials[t] = sh[t] - v;   // exclusive
}

__global__ void gscan_c_kernel(int* __restrict__ buf,
                               const int* __restrict__ partials, int n, int NBtot)
{
    int l = blockIdx.x * blockDim.x + threadIdx.x;
    if (l < n) buf[physidx(l, NBtot)] += partials[l >> 12];
}

// ---------------------------------------------------------------------------
// Scatter pass: append (src | dfine<<16) into block-private bucket ranges.
// O is block-major -> coalesced staging.
// ---------------------------------------------------------------------------
__global__ __launch_bounds__(1024) void scatter_kernel(
    RelSet rs, const int* __restrict__ O, unsigned* __restrict__ temp, int NBr)
{
    extern __shared__ int cur[];
    const int NBtot = 4 * NBr;
    for (int i = threadIdx.x; i < NBtot; i += 1024)
        cur[i] = O[blockIdx.x * NBtot + i];
    __syncthreads();
    for (int e = blockIdx.x * 1024 + threadIdx.x; e < rs.off4; e += NBLK * 1024) {
        int r, le; const int *s, *d;
        pick(rs, e, r, s, d, le);
        int dd = d[le];
        int b = r * NBr + (dd >> 7);
        int pos = atomicAdd(&cur[b], 1);
        temp[pos] = (unsigned)s[le] | ((unsigned)(dd & 127) << 16);
    }
}

// ---------------------------------------------------------------------------
// Fill: one block per bucket. Bucket boundaries are contiguous in O
// (logical l=b*NBLK -> physical index b). Counts 128 per-dst degrees in LDS,
// scans, writes rowptr (coalesced) AND places edges -- all block-local.
// ---------------------------------------------------------------------------
__global__ __launch_bounds__(256) void fillb_kernel(
    RelSet rs, const int* __restrict__ O, const unsigned* __restrict__ temp,
    int* __restrict__ rowptr4, unsigned short* __restrict__ esrc4,
    int NBr, int NP, int EP, int TE)
{
    __shared__ int cnt[128];
    __shared__ int cur[128];
    const int b = blockIdx.x;
    const int NBtot = 4 * NBr;
    const int r = b / NBr;
    const int bloc = b - r * NBr;
    const int dbase = bloc << 7;
    const int nd = ndst_of(rs, r);
    const int bstart = O[b];
    const int bend   = (b + 1 < NBtot) ? O[b + 1] : TE;
    const int relstart = O[r * NBr];
    const int relend   = (r + 1 < 4) ? O[(r + 1) * NBr] : TE;
    const int t = threadIdx.x;

    if (t < 128) cnt[t] = 0;
    __syncthreads();
    for (int i = bstart + t; i < bend; i += 256)
        atomicAdd(&cnt[temp[i] >> 16], 1);
    __syncthreads();
    const int orig = (t < 128) ? cnt[t] : 0;
    for (int o = 1; o < 128; o <<= 1) {
        int add = 0;
        if (t < 128 && t >= o) add = cnt[t - o];
        __syncthreads();
        if (t < 128) cnt[t] += add;
        __syncthreads();
    }
    const int bucket_base = bstart - relstart;
    if (t < 128) {
        const int excl = cnt[t] - orig;
        cur[t] = bucket_base + excl;
        const int d = dbase + t;
        if (d < nd) rowptr4[r * (NP + 1) + d] = bucket_base + excl;
    }
    if (t == 0 && bloc == NBr - 1)
        rowptr4[r * (NP + 1) + nd] = relend - relstart;
    __syncthreads();
    unsigned short* es = esrc4 + (size_t)r * EP;
    for (int i = bstart + t; i < bend; i += 256) {
        unsigned u = temp[i];
        int pos = atomicAdd(&cur[u >> 16], 1);
        es[pos] = (unsigned short)(u & 0xFFFFu);
    }
}

// ---------------------------------------------------------------------------
// wvec2: wv1 = W1 @ a1, wv2 = W2 @ a2 (both K=128)
// ---------------------------------------------------------------------------
__global__ void wvec2_kernel(const void* __restrict__ W1, const void* __restrict__ a1,
                             const void* __restrict__ W2, const void* __restrict__ a2,
                             float* __restrict__ wv1, float* __restrict__ wv2,
                             const int* __restrict__ flag)
{
    const bool f32 = (flag[0] != 0);
    const int t = threadIdx.x;
    const void* W = (t < 128) ? W1 : W2;
    const void* a = (t < 128) ? a1 : a2;
    const int k = t & 127;
    float s = 0.f;
    for (int c = 0; c < 64; ++c) s += ldx(W, (size_t)k * 64 + c, f32) * ldx(a, c, f32);
    ((t < 128) ? wv1 : wv2)[k] = s;
}

// ---------------------------------------------------------------------------
// Fused MFMA projection pair
// ---------------------------------------------------------------------------
struct ProjArg {
    const void* X; const void* W; const void* a1; const void* a2;
    const float* wvx;
    bf16* H; float* al1; float* al2; float* alx;
    int N;
};

template <int K>
__device__ __forceinline__ void proj_body(const ProjArg& P, bool f32,
                                          int bid, int nblocks, short* Wf)
{
    constexpr int NKT = K / 32;
    const int tid = threadIdx.x;

    for (int idx = tid; idx < K * 64; idx += 256) {
        int k = idx >> 6, c = idx & 63;
        float w = ldx(P.W, idx, f32);
        int kt = k >> 5, q = (k >> 3) & 3, j = k & 7;
        int ct = c >> 4, n = c & 15;
        Wf[(((kt * 4 + ct) * 64) + q * 16 + n) * 8 + j] = (short)f2bfbits(w);
    }
    __syncthreads();

    const int wave = tid >> 6, lane = tid & 63;
    const int quad = lane >> 4, n = lane & 15;

    s16v8 Bf[NKT][4];
    #pragma unroll
    for (int kt = 0; kt < NKT; ++kt)
        #pragma unroll
        for (int ct = 0; ct < 4; ++ct)
            Bf[kt][ct] = *(const s16v8*)&Wf[((kt * 4 + ct) * 64 + lane) * 8];

    float a1v[4], a2v[4];
    #pragma unroll
    for (int ct = 0; ct < 4; ++ct) {
        a1v[ct] = P.a1 ? ldx(P.a1, ct * 16 + n, f32) : 0.f;
        a2v[ct] = P.a2 ? ldx(P.a2, ct * 16 + n, f32) : 0.f;
    }
    float wv[NKT][8];
    if (P.wvx) {
        #pragma unroll
        for (int kt = 0; kt < NKT; ++kt)
            #pragma unroll
            for (int j = 0; j < 8; ++j)
                wv[kt][j] = P.wvx[kt * 32 + quad * 8 + j];
    }

    const int tiles = (P.N + 15) / 16;
    for (int tb = bid * 4 + wave; tb < tiles; tb += nblocks * 4) {
        const int r0 = tb * 16;
        const int arow = r0 + n;
        const int ars  = (arow < P.N) ? arow : 0;

        f32v4 acc[4];
        #pragma unroll
        for (int ct = 0; ct < 4; ++ct) acc[ct] = (f32v4){0.f, 0.f, 0.f, 0.f};
        float txd = 0.f;

        #pragma unroll
        for (int kt = 0; kt < NKT; ++kt) {
            s16v8 As;
            if (f32) {
                const float4* xp = (const float4*)P.X +
                    ((size_t)ars * K + kt * 32 + quad * 8) / 4;
                float4 x0 = xp[0], x1 = xp[1];
                As[0] = (short)f2bfbits(x0.x); As[1] = (short)f2bfbits(x0.y);
                As[2] = (short)f2bfbits(x0.z); As[3] = (short)f2bfbits(x0.w);
                As[4] = (short)f2bfbits(x1.x); As[5] = (short)f2bfbits(x1.y);
                As[6] = (short)f2bfbits(x1.z); As[7] = (short)f2bfbits(x1.w);
            } else {
                As = *(const s16v8*)((const unsigned short*)P.X +
                    (size_t)ars * K + kt * 32 + quad * 8);
            }
            if (P.wvx) {
                #pragma unroll
                for (int j = 0; j < 8; ++j)
                    txd = fmaf(bf2f((unsigned short)As[j]), wv[kt][j], txd);
            }
            bf16v8 Ab = __builtin_bit_cast(bf16v8, As);
            #pragma unroll
            for (int ct = 0; ct < 4; ++ct)
                acc[ct] = __builtin_amdgcn_mfma_f32_16x16x32_bf16(
                    Ab, __builtin_bit_cast(bf16v8, Bf[kt][ct]), acc[ct], 0, 0, 0);
        }

        if (P.alx) {
            txd += __shfl_xor(txd, 16);
            txd += __shfl_xor(txd, 32);
            if (lane < 16 && r0 + lane < P.N) P.alx[r0 + lane] = txd;
        }

        #pragma unroll
        for (int i = 0; i < 4; ++i) {
            const int r = r0 + quad * 4 + i;
            const bool rv = (r < P.N);
            if (rv && P.H) {
                #pragma unroll
                for (int ct = 0; ct < 4; ++ct)
                    P.H[(size_t)r * 64 + ct * 16 + n] = __float2bfloat16(acc[ct][i]);
            }
            if (P.al1) {
                float t = acc[0][i] * a1v[0] + acc[1][i] * a1v[1] +
                          acc[2][i] * a1v[2] + acc[3][i] * a1v[3];
                #pragma unroll
                for (int o = 1; o < 16; o <<= 1) t += __shfl_xor(t, o);
                if (rv && n == 0) P.al1[r] = t;
            }
            if (P.al2) {
                float t = acc[0][i] * a2v[0] + acc[1][i] * a2v[1] +
                          acc[2][i] * a2v[2] + acc[3][i] * a2v[3];
                #pragma unroll
                for (int o = 1; o < 16; o <<= 1) t += __shfl_xor(t, o);
                if (rv && n == 0) P.al2[r] = t;
            }
        }
    }
}

template <int KA, int KB>
__global__ __launch_bounds__(256) void proj2_kernel(ProjArg A, ProjArg B, int nA,
                                                    const int* __restrict__ flag)
{
    __shared__ short Wf[4 * 4 * 64 * 8];
    const bool f32 = (flag[0] != 0);
    if ((int)blockIdx.x < nA) proj_body<KA>(A, f32, blockIdx.x, nA, Wf);
    else                      proj_body<KB>(B, f32, blockIdx.x - nA,
                                            gridDim.x - nA, Wf);
}

// ---------------------------------------------------------------------------
// Fused dual-relation softmax aggregation. One wave per dst node; lane=channel.
// ---------------------------------------------------------------------------
__global__ __launch_bounds__(256) void agg2_kernel(
    const int* __restrict__ rp1, const unsigned short* __restrict__ es1,
    const unsigned short* __restrict__ HS1, const float* __restrict__ als1,
    const float* __restrict__ ald1,
    const int* __restrict__ rp2, const unsigned short* __restrict__ es2,
    const unsigned short* __restrict__ HS2, const float* __restrict__ als2,
    const float* __restrict__ ald2,
    const void* __restrict__ b1, const void* __restrict__ b2,
    void* __restrict__ out, size_t out_off, int n, const int* __restrict__ flag)
{
    const int gw   = (blockIdx.x * blockDim.x + threadIdx.x) >> 6;
    const int lane = threadIdx.x & 63;
    if (gw >= n) return;

    int p1 = rp1[gw], e1 = rp1[gw + 1];
    int p2 = rp2[gw], e2 = rp2[gw + 1];
    const float ad1 = ald1[gw], ad2 = ald2[gw];

    float c10 = 0.f, c11 = 0.f, c12 = 0.f, c13 = 0.f, den1 = 0.f;
    float c20 = 0.f, c21 = 0.f, c22 = 0.f, c23 = 0.f, den2 = 0.f;

    while (p1 < e1 || p2 < e2) {
        int nn1 = e1 - p1; nn1 = nn1 < 0 ? 0 : (nn1 > 64 ? 64 : nn1);
        int nn2 = e2 - p2; nn2 = nn2 < 0 ? 0 : (nn2 > 64 ? 64 : nn2);
        int s1 = 0, s2 = 0; float w1 = 0.f, w2 = 0.f;
        if (lane < nn1) {
            s1 = es1[p1 + lane];
            float l = als1[s1] + ad1;
            l = (l > 0.f) ? l : 0.2f * l;
            w1 = __expf(l);
        }
        if (lane < nn2) {
            s2 = es2[p2 + lane];
            float l = als2[s2] + ad2;
            l = (l > 0.f) ? l : 0.2f * l;
            w2 = __expf(l);
        }
        den1 += w1; den2 += w2;

        const int jm = (nn1 > nn2) ? nn1 : nn2;
        for (int j = 0; j < jm; j += 4) {
            int   a0 = __shfl(s1, j),     a1 = __shfl(s1, j + 1);
            int   a2 = __shfl(s1, j + 2), a3 = __shfl(s1, j + 3);
            int   b0 = __shfl(s2, j),     b1i = __shfl(s2, j + 1);
            int   b2i = __shfl(s2, j + 2), b3 = __shfl(s2, j + 3);
            float u0 = __shfl(w1, j),     u1 = __shfl(w1, j + 1);
            float u2 = __shfl(w1, j + 2), u3 = __shfl(w1, j + 3);
            float v0 = __shfl(w2, j),     v1 = __shfl(w2, j + 1);
            float v2 = __shfl(w2, j + 2), v3 = __shfl(w2, j + 3);
            float h10 = bf2f(HS1[(size_t)a0 * 64 + lane]);
            float h11 = bf2f(HS1[(size_t)a1 * 64 + lane]);
            float h12 = bf2f(HS1[(size_t)a2 * 64 + lane]);
            float h13 = bf2f(HS1[(size_t)a3 * 64 + lane]);
            float h20 = bf2f(HS2[(size_t)b0 * 64 + lane]);
            float h21 = bf2f(HS2[(size_t)b1i * 64 + lane]);
            float h22 = bf2f(HS2[(size_t)b2i * 64 + lane]);
            float h23 = bf2f(HS2[(size_t)b3 * 64 + lane]);
            c10 = fmaf(u0, h10, c10); c11 = fmaf(u1, h11, c11);
            c12 = fmaf(u2, h12, c12); c13 = fmaf(u3, h13, c13);
            c20 = fmaf(v0, h20, c20); c21 = fmaf(v1, h21, c21);
            c22 = fmaf(v2, h22, c22); c23 = fmaf(v3, h23, c23);
        }
        p1 += nn1; p2 += nn2;
    }

    den1 = wave_sum(den1);
    den2 = wave_sum(den2);
    const float r1 = (c10 + c11 + c12 + c13) / (den1 + 1e-16f);
    const float r2 = (c20 + c21 + c22 + c23) / (den2 + 1e-16f);

    const bool f32 = (flag[0] != 0);
    float v = 0.5f * (r1 + r2 + ldx(b1, lane, f32) + ldx(b2, lane, f32));
    const size_t idx = out_off + (size_t)gw * 64 + lane;
    if (f32) ((float*)out)[idx] = v;
    else     ((bf16*)out)[idx] = __float2bfloat16(v);
}

// ---------------------------------------------------------------------------
extern "C" void kernel_launch(void* const* d_in, const int* in_sizes, int n_in,
                              void* d_out, int out_size, void* d_ws, size_t ws_size,
                              hipStream_t stream)
{
    const void* x_t = d_in[0];
    const void* x_d = d_in[1];
    const int* ei_tt = (const int*)d_in[2];
    const int* ei_dt = (const int*)d_in[3];
    const int* ei_dd = (const int*)d_in[4];
    const int* ei_td = (const int*)d_in[5];
    const void* W_tt     = d_in[6];
    const void* att_tt_s = d_in[7];
    const void* att_tt_d = d_in[8];
    const void* b_tt     = d_in[9];
    const void* W_dt_src = d_in[10];
    const void* W_dt_dst = d_in[11];
    const void* att_dt_s = d_in[12];
    const void* att_dt_d = d_in[13];
    const void* b_dt     = d_in[14];
    const void* W_dd     = d_in[15];
    const void* att_dd_s = d_in[16];
    const void* att_dd_d = d_in[17];
    const void* b_dd     = d_in[18];
    const void* W_td_src = d_in[19];
    const void* W_td_dst = d_in[20];
    const void* att_td_s = d_in[21];
    const void* att_td_d = d_in[22];
    const void* b_td     = d_in[23];

    const int NT = in_sizes[0] / 128;
    const int ND = in_sizes[1] / 128;
    const int Ett = in_sizes[2] / 2, Edt = in_sizes[3] / 2,
              Edd = in_sizes[4] / 2, Etd = in_sizes[5] / 2;
    const int NMAX = (NT > ND) ? NT : ND;
    int EMAX = Ett;
    if (Edt > EMAX) EMAX = Edt;
    if (Edd > EMAX) EMAX = Edd;
    if (Etd > EMAX) EMAX = Etd;
    const int TE = Ett + Edt + Edd + Etd;

    const int NBr  = (NMAX + 127) >> 7;      // buckets per relation
    const int NBtot = 4 * NBr;
    const int HM = NBtot * NBLK;             // histogram matrix size

    // ---- workspace ----
    char* wptr = (char*)d_ws;
    auto alloc = [&](size_t bytes) -> void* {
        void* p = (void*)wptr;
        wptr += (bytes + 255) & ~(size_t)255;
        return p;
    };
    bf16*  h1      = (bf16*)alloc((size_t)NMAX * 64 * 2);
    bf16*  h2      = (bf16*)alloc((size_t)NMAX * 64 * 2);
    float* als[4]; float* ald[4];
    for (int r = 0; r < 4; ++r) {
        als[r] = (float*)alloc((size_t)NMAX * 4);
        ald[r] = (float*)alloc((size_t)NMAX * 4);
    }
    int*   hist    = (int*)alloc((size_t)HM * 4);
    int*   rowptr4 = (int*)alloc((size_t)4 * (NMAX + 1) * 4);
    unsigned short* esrc4 = (unsigned short*)alloc((size_t)4 * EMAX * 2);
    unsigned* temp = (unsigned*)alloc((size_t)TE * 4);
    int*   gpart   = (int*)alloc(1024 * 4);
    float* wvec_dt = (float*)alloc(128 * 4);
    float* wvec_td = (float*)alloc(128 * 4);
    int*   flag    = (int*)alloc(256 * 4);

    RelSet rs;
    rs.src0 = ei_tt; rs.dst0 = ei_tt + Ett;
    rs.src1 = ei_dt; rs.dst1 = ei_dt + Edt;
    rs.src2 = ei_dd; rs.dst2 = ei_dd + Edd;
    rs.src3 = ei_td; rs.dst3 = ei_td + Etd;
    rs.off1 = Ett; rs.off2 = Ett + Edt; rs.off3 = Ett + Edt + Edd; rs.off4 = TE;
    rs.nd0 = NT; rs.nd1 = NT; rs.nd2 = ND; rs.nd3 = ND;

    detect_kernel<<<1, 256, 0, stream>>>((const unsigned*)x_t, 4096, flag);

    // ---- CSR build: LDS histogram -> permuted scan -> scatter -> fill ----
    const size_t ldsB = (size_t)NBtot * 4;
    pass1_kernel<<<NBLK, 1024, ldsB, stream>>>(rs, hist, NBr);

    const int gnb = (HM + 4095) / 4096;
    gscan_a_kernel<<<gnb, 1024, 0, stream>>>(hist, HM, NBtot, gpart);
    gscan_b_kernel<<<1, 1024, 0, stream>>>(gpart, gnb);
    gscan_c_kernel<<<(HM + 255) / 256, 256, 0, stream>>>(hist, gpart, HM, NBtot);

    scatter_kernel<<<NBLK, 1024, ldsB, stream>>>(rs, hist, temp, NBr);
    fillb_kernel<<<NBtot, 256, 0, stream>>>(rs, hist, temp, rowptr4, esrc4,
                                            NBr, NMAX, EMAX, TE);

    // ---- wvec for the two alpha-only projections ----
    wvec2_kernel<<<1, 256, 0, stream>>>(W_dt_dst, att_dt_d, W_td_dst, att_td_d,
                                        wvec_dt, wvec_td, flag);

    // ---- phase 1 projections: tt -> h1 (+ald_dt fused), dt -> h2 (+ald_td) ----
    ProjArg Ptt{ x_t, W_tt, att_tt_s, att_tt_d, wvec_dt,
                 h1, als[0], ald[0], ald[1], NT };
    ProjArg Pdt{ x_d, W_dt_src, att_dt_s, nullptr, wvec_td,
                 h2, als[1], nullptr, ald[3], ND };
    proj2_kernel<128, 128><<<512, 256, 0, stream>>>(Ptt, Pdt, 256, flag);

    // ---- target aggregate (tt rel0 + dt rel1) -> x_target_new ----
    agg2_kernel<<<(NT + 3) / 4, 256, 0, stream>>>(
        rowptr4 + 0 * (NMAX + 1), esrc4 + (size_t)0 * EMAX,
        (const unsigned short*)h1, als[0], ald[0],
        rowptr4 + 1 * (NMAX + 1), esrc4 + (size_t)1 * EMAX,
        (const unsigned short*)h2, als[1], ald[1],
        b_tt, b_dt, d_out, 0, NT, flag);

    // ---- phase 2 projections: dd -> h1, td (reads x_target_new) -> h2 ----
    ProjArg Pdd{ x_d, W_dd, att_dd_s, att_dd_d, nullptr,
                 h1, als[2], ald[2], nullptr, ND };
    ProjArg Ptd{ d_out, W_td_src, att_td_s, nullptr, nullptr,
                 h2, als[3], nullptr, nullptr, NT };
    proj2_kernel<128, 64><<<512, 256, 0, stream>>>(Pdd, Ptd, 256, flag);

    // ---- drug aggregate (dd rel2 + td rel3) -> x_drug_new ----
    agg2_kernel<<<(ND + 3) / 4, 256, 0, stream>>>(
        rowptr4 + 2 * (NMAX + 1), esrc4 + (size_t)2 * EMAX,
        (const unsigned short*)h1, als[2], ald[2],
        rowptr4 + 3 * (NMAX + 1), esrc4 + (size_t)3 * EMAX,
        (const unsigned short*)h2, als[3], ald[3],
        b_dd, b_td, d_out, (size_t)NT * 64, ND, flag);
}

// Round 11
// 371.985 us; speedup vs baseline: 3.3604x; 1.0524x over previous
//
#include <hip/hip_runtime.h>
#include <hip/hip_bf16.h>

typedef __hip_bfloat16 bf16;

typedef __bf16 bf16v8 __attribute__((ext_vector_type(8)));
typedef short  s16v8  __attribute__((ext_vector_type(8)));
typedef float  f32v4  __attribute__((ext_vector_type(4)));

#define NBLK  256      // edge-pass blocks (power of 2)
#define NBLKL 8        // log2(NBLK)

__device__ __forceinline__ float bf2f(unsigned short u) {
    return __uint_as_float(((unsigned)u) << 16);
}
__device__ __forceinline__ float bflo(unsigned v) {
    return __uint_as_float(v << 16);
}
__device__ __forceinline__ float bfhi(unsigned v) {
    return __uint_as_float(v & 0xFFFF0000u);
}
__device__ __forceinline__ float ldx(const void* p, size_t i, bool f32) {
    return f32 ? ((const float*)p)[i] : bf2f(((const unsigned short*)p)[i]);
}
__device__ __forceinline__ unsigned short f2bfbits(float f) {
    union { bf16 h; unsigned short u; } cv;
    cv.h = __float2bfloat16(f);
    return cv.u;
}
__device__ __forceinline__ float wave_sum(float v) {
    #pragma unroll
    for (int o = 32; o > 0; o >>= 1) v += __shfl_xor(v, o);
    return v;
}
// logical (bucket-major) -> physical (block-major) index for the hist matrix
__device__ __forceinline__ int physidx(int l, int NBtot) {
    return (l & (NBLK - 1)) * NBtot + (l >> NBLKL);
}

// ---------------------------------------------------------------------------
// dtype detector (f32 vs bf16 inputs)
// ---------------------------------------------------------------------------
__global__ void detect_kernel(const unsigned* __restrict__ x, int nwords,
                              int* __restrict__ flag)
{
    __shared__ int cnt;
    if (threadIdx.x == 0) cnt = 0;
    __syncthreads();
    int c = 0;
    for (int i = threadIdx.x; i < nwords; i += blockDim.x) {
        unsigned e = (x[i] >> 23) & 0xFFu;
        if (e >= 100u && e <= 150u) c++;
    }
    atomicAdd(&cnt, c);
    __syncthreads();
    if (threadIdx.x == 0) flag[0] = (2 * cnt > nwords) ? 1 : 0;
}

// ---------------------------------------------------------------------------
// Relation set
// ---------------------------------------------------------------------------
struct RelSet {
    const int *src0, *dst0, *src1, *dst1, *src2, *dst2, *src3, *dst3;
    int off1, off2, off3, off4;
    int nd0, nd1, nd2, nd3;
};

__device__ __forceinline__ void pick(const RelSet& rs, int e, int& r,
                                     const int*& s, const int*& d, int& le)
{
    if (e < rs.off1)      { r = 0; s = rs.src0; d = rs.dst0; le = e; }
    else if (e < rs.off2) { r = 1; s = rs.src1; d = rs.dst1; le = e - rs.off1; }
    else if (e < rs.off3) { r = 2; s = rs.src2; d = rs.dst2; le = e - rs.off2; }
    else                  { r = 3; s = rs.src3; d = rs.dst3; le = e - rs.off3; }
}
__device__ __forceinline__ int ndst_of(const RelSet& rs, int r)
{
    return r == 0 ? rs.nd0 : r == 1 ? rs.nd1 : r == 2 ? rs.nd2 : rs.nd3;
}

// ---------------------------------------------------------------------------
// Pass 1: per-(block,bucket) LDS histogram -> hist[block*NBtot + bucket]
// ---------------------------------------------------------------------------
__global__ __launch_bounds__(1024) void pass1_kernel(
    RelSet rs, int* __restrict__ hist, int NBr)
{
    extern __shared__ int lh[];
    const int NBtot = 4 * NBr;
    for (int i = threadIdx.x; i < NBtot; i += 1024) lh[i] = 0;
    __syncthreads();
    for (int e = blockIdx.x * 1024 + threadIdx.x; e < rs.off4; e += NBLK * 1024) {
        int r, le; const int *s, *d;
        pick(rs, e, r, s, d, le);
        atomicAdd(&lh[r * NBr + (d[le] >> 7)], 1);
    }
    __syncthreads();
    for (int i = threadIdx.x; i < NBtot; i += 1024)
        hist[blockIdx.x * NBtot + i] = lh[i];
}

// ---------------------------------------------------------------------------
// Exclusive scan over the hist matrix in LOGICAL (bucket-major) order.
// ---------------------------------------------------------------------------
__global__ __launch_bounds__(1024) void gscan_a_kernel(
    int* __restrict__ buf, int n, int NBtot, int* __restrict__ partials)
{
    __shared__ int sh[1024];
    const int t = threadIdx.x;
    const int base = blockIdx.x * 4096 + t * 4;
    int p0 = 0, p1 = 0, p2 = 0, p3 = 0;
    int v0 = 0, v1 = 0, v2 = 0, v3 = 0;
    if (base < n)     { p0 = physidx(base,     NBtot); v0 = buf[p0]; }
    if (base + 1 < n) { p1 = physidx(base + 1, NBtot); v1 = buf[p1]; }
    if (base + 2 < n) { p2 = physidx(base + 2, NBtot); v2 = buf[p2]; }
    if (base + 3 < n) { p3 = physidx(base + 3, NBtot); v3 = buf[p3]; }
    const int tsum = v0 + v1 + v2 + v3;
    sh[t] = tsum;
    __syncthreads();
    for (int o = 1; o < 1024; o <<= 1) {
        int u = (t >= o) ? sh[t - o] : 0;
        __syncthreads();
        sh[t] += u;
        __syncthreads();
    }
    const int texcl = sh[t] - tsum;
    if (base < n)     buf[p0] = texcl;
    if (base + 1 < n) buf[p1] = texcl + v0;
    if (base + 2 < n) buf[p2] = texcl + v0 + v1;
    if (base + 3 < n) buf[p3] = texcl + v0 + v1 + v2;
    if (t == 1023) partials[blockIdx.x] = sh[t];
}

__global__ __launch_bounds__(1024) void gscan_b_kernel(int* __restrict__ partials,
                                                       int nb)
{
    __shared__ int sh[1024];
    const int t = threadIdx.x;
    int v = (t < nb) ? partials[t] : 0;
    sh[t] = v;
    __syncthreads();
    for (int o = 1; o < 1024; o <<= 1) {
        int u = (t >= o) ? sh[t - o] : 0;
        __syncthreads();
        sh[t] += u;
        __syncthreads();
    }
    if (t < nb) partials[t] = sh[t] - v;   // exclusive
}

__global__ void gscan_c_kernel(int* __restrict__ buf,
                               const int* __restrict__ partials, int n, int NBtot)
{
    int l = blockIdx.x * blockDim.x + threadIdx.x;
    if (l < n) buf[physidx(l, NBtot)] += partials[l >> 12];
}

// ---------------------------------------------------------------------------
// Scatter pass: append (src | dfine<<16) into block-private bucket ranges.
// ---------------------------------------------------------------------------
__global__ __launch_bounds__(1024) void scatter_kernel(
    RelSet rs, const int* __restrict__ O, unsigned* __restrict__ temp, int NBr)
{
    extern __shared__ int cur[];
    const int NBtot = 4 * NBr;
    for (int i = threadIdx.x; i < NBtot; i += 1024)
        cur[i] = O[blockIdx.x * NBtot + i];
    __syncthreads();
    for (int e = blockIdx.x * 1024 + threadIdx.x; e < rs.off4; e += NBLK * 1024) {
        int r, le; const int *s, *d;
        pick(rs, e, r, s, d, le);
        int dd = d[le];
        int b = r * NBr + (dd >> 7);
        int pos = atomicAdd(&cur[b], 1);
        temp[pos] = (unsigned)s[le] | ((unsigned)(dd & 127) << 16);
    }
}

// ---------------------------------------------------------------------------
// Fill: one block per bucket; rowptr + edge placement, all block-local.
// ---------------------------------------------------------------------------
__global__ __launch_bounds__(256) void fillb_kernel(
    RelSet rs, const int* __restrict__ O, const unsigned* __restrict__ temp,
    int* __restrict__ rowptr4, unsigned short* __restrict__ esrc4,
    int NBr, int NP, int EP, int TE)
{
    __shared__ int cnt[128];
    __shared__ int cur[128];
    const int b = blockIdx.x;
    const int NBtot = 4 * NBr;
    const int r = b / NBr;
    const int bloc = b - r * NBr;
    const int dbase = bloc << 7;
    const int nd = ndst_of(rs, r);
    const int bstart = O[b];
    const int bend   = (b + 1 < NBtot) ? O[b + 1] : TE;
    const int relstart = O[r * NBr];
    const int relend   = (r + 1 < 4) ? O[(r + 1) * NBr] : TE;
    const int t = threadIdx.x;

    if (t < 128) cnt[t] = 0;
    __syncthreads();
    for (int i = bstart + t; i < bend; i += 256)
        atomicAdd(&cnt[temp[i] >> 16], 1);
    __syncthreads();
    const int orig = (t < 128) ? cnt[t] : 0;
    for (int o = 1; o < 128; o <<= 1) {
        int add = 0;
        if (t < 128 && t >= o) add = cnt[t - o];
        __syncthreads();
        if (t < 128) cnt[t] += add;
        __syncthreads();
    }
    const int bucket_base = bstart - relstart;
    if (t < 128) {
        const int excl = cnt[t] - orig;
        cur[t] = bucket_base + excl;
        const int d = dbase + t;
        if (d < nd) rowptr4[r * (NP + 1) + d] = bucket_base + excl;
    }
    if (t == 0 && bloc == NBr - 1)
        rowptr4[r * (NP + 1) + nd] = relend - relstart;
    __syncthreads();
    unsigned short* es = esrc4 + (size_t)r * EP;
    for (int i = bstart + t; i < bend; i += 256) {
        unsigned u = temp[i];
        int pos = atomicAdd(&cur[u >> 16], 1);
        es[pos] = (unsigned short)(u & 0xFFFFu);
    }
}

// ---------------------------------------------------------------------------
// wvec2: wv1 = W1 @ a1, wv2 = W2 @ a2 (both K=128)
// ---------------------------------------------------------------------------
__global__ void wvec2_kernel(const void* __restrict__ W1, const void* __restrict__ a1,
                             const void* __restrict__ W2, const void* __restrict__ a2,
                             float* __restrict__ wv1, float* __restrict__ wv2,
                             const int* __restrict__ flag)
{
    const bool f32 = (flag[0] != 0);
    const int t = threadIdx.x;
    const void* W = (t < 128) ? W1 : W2;
    const void* a = (t < 128) ? a1 : a2;
    const int k = t & 127;
    float s = 0.f;
    for (int c = 0; c < 64; ++c) s += ldx(W, (size_t)k * 64 + c, f32) * ldx(a, c, f32);
    ((t < 128) ? wv1 : wv2)[k] = s;
}

// ---------------------------------------------------------------------------
// MFMA projection body (unchanged math)
// ---------------------------------------------------------------------------
struct ProjArg {
    const void* X; const void* W; const void* a1; const void* a2;
    const float* wvx;
    bf16* H; float* al1; float* al2; float* alx;
    int N;
};

template <int K>
__device__ __forceinline__ void proj_body(const ProjArg& P, bool f32,
                                          int bid, int nblocks, short* Wf)
{
    constexpr int NKT = K / 32;
    const int tid = threadIdx.x;

    for (int idx = tid; idx < K * 64; idx += 256) {
        int k = idx >> 6, c = idx & 63;
        float w = ldx(P.W, idx, f32);
        int kt = k >> 5, q = (k >> 3) & 3, j = k & 7;
        int ct = c >> 4, n = c & 15;
        Wf[(((kt * 4 + ct) * 64) + q * 16 + n) * 8 + j] = (short)f2bfbits(w);
    }
    __syncthreads();

    const int wave = tid >> 6, lane = tid & 63;
    const int quad = lane >> 4, n = lane & 15;

    s16v8 Bf[NKT][4];
    #pragma unroll
    for (int kt = 0; kt < NKT; ++kt)
        #pragma unroll
        for (int ct = 0; ct < 4; ++ct)
            Bf[kt][ct] = *(const s16v8*)&Wf[((kt * 4 + ct) * 64 + lane) * 8];

    float a1v[4], a2v[4];
    #pragma unroll
    for (int ct = 0; ct < 4; ++ct) {
        a1v[ct] = P.a1 ? ldx(P.a1, ct * 16 + n, f32) : 0.f;
        a2v[ct] = P.a2 ? ldx(P.a2, ct * 16 + n, f32) : 0.f;
    }
    float wv[NKT][8];
    if (P.wvx) {
        #pragma unroll
        for (int kt = 0; kt < NKT; ++kt)
            #pragma unroll
            for (int j = 0; j < 8; ++j)
                wv[kt][j] = P.wvx[kt * 32 + quad * 8 + j];
    }

    const int tiles = (P.N + 15) / 16;
    for (int tb = bid * 4 + wave; tb < tiles; tb += nblocks * 4) {
        const int r0 = tb * 16;
        const int arow = r0 + n;
        const int ars  = (arow < P.N) ? arow : 0;

        f32v4 acc[4];
        #pragma unroll
        for (int ct = 0; ct < 4; ++ct) acc[ct] = (f32v4){0.f, 0.f, 0.f, 0.f};
        float txd = 0.f;

        #pragma unroll
        for (int kt = 0; kt < NKT; ++kt) {
            s16v8 As;
            if (f32) {
                const float4* xp = (const float4*)P.X +
                    ((size_t)ars * K + kt * 32 + quad * 8) / 4;
                float4 x0 = xp[0], x1 = xp[1];
                As[0] = (short)f2bfbits(x0.x); As[1] = (short)f2bfbits(x0.y);
                As[2] = (short)f2bfbits(x0.z); As[3] = (short)f2bfbits(x0.w);
                As[4] = (short)f2bfbits(x1.x); As[5] = (short)f2bfbits(x1.y);
                As[6] = (short)f2bfbits(x1.z); As[7] = (short)f2bfbits(x1.w);
            } else {
                As = *(const s16v8*)((const unsigned short*)P.X +
                    (size_t)ars * K + kt * 32 + quad * 8);
            }
            if (P.wvx) {
                #pragma unroll
                for (int j = 0; j < 8; ++j)
                    txd = fmaf(bf2f((unsigned short)As[j]), wv[kt][j], txd);
            }
            bf16v8 Ab = __builtin_bit_cast(bf16v8, As);
            #pragma unroll
            for (int ct = 0; ct < 4; ++ct)
                acc[ct] = __builtin_amdgcn_mfma_f32_16x16x32_bf16(
                    Ab, __builtin_bit_cast(bf16v8, Bf[kt][ct]), acc[ct], 0, 0, 0);
        }

        if (P.alx) {
            txd += __shfl_xor(txd, 16);
            txd += __shfl_xor(txd, 32);
            if (lane < 16 && r0 + lane < P.N) P.alx[r0 + lane] = txd;
        }

        #pragma unroll
        for (int i = 0; i < 4; ++i) {
            const int r = r0 + quad * 4 + i;
            const bool rv = (r < P.N);
            if (rv && P.H) {
                #pragma unroll
                for (int ct = 0; ct < 4; ++ct)
                    P.H[(size_t)r * 64 + ct * 16 + n] = __float2bfloat16(acc[ct][i]);
            }
            if (P.al1) {
                float t = acc[0][i] * a1v[0] + acc[1][i] * a1v[1] +
                          acc[2][i] * a1v[2] + acc[3][i] * a1v[3];
                #pragma unroll
                for (int o = 1; o < 16; o <<= 1) t += __shfl_xor(t, o);
                if (rv && n == 0) P.al1[r] = t;
            }
            if (P.al2) {
                float t = acc[0][i] * a2v[0] + acc[1][i] * a2v[1] +
                          acc[2][i] * a2v[2] + acc[3][i] * a2v[3];
                #pragma unroll
                for (int o = 1; o < 16; o <<= 1) t += __shfl_xor(t, o);
                if (rv && n == 0) P.al2[r] = t;
            }
        }
    }
}

// three projections in one launch (blocks partitioned)
template <int KA, int KB, int KC>
__global__ __launch_bounds__(256) void proj3_kernel(ProjArg A, ProjArg B, ProjArg C,
                                                    int nA, int nB,
                                                    const int* __restrict__ flag)
{
    __shared__ short Wf[4 * 4 * 64 * 8];
    const bool f32 = (flag[0] != 0);
    const int bx = blockIdx.x;
    if (bx < nA)            proj_body<KA>(A, f32, bx, nA, Wf);
    else if (bx < nA + nB)  proj_body<KB>(B, f32, bx - nA, nB, Wf);
    else                    proj_body<KC>(C, f32, bx - nA - nB,
                                          gridDim.x - nA - nB, Wf);
}

template <int K>
__global__ __launch_bounds__(256) void proj1_kernel(ProjArg A,
                                                    const int* __restrict__ flag)
{
    __shared__ short Wf[(K / 32) * 4 * 64 * 8];
    proj_body<K>(A, flag[0] != 0, blockIdx.x, gridDim.x, Wf);
}

// ---------------------------------------------------------------------------
// Fused dual-relation softmax aggregation, 2 channels/lane.
// Lanes 0-31 process edge j, lanes 32-63 edge j+1 (per-lane shfl index);
// 4-edge unroll per relation -> 4 gathers in flight. ~4 wave-inst/edge.
// ---------------------------------------------------------------------------
__global__ __launch_bounds__(256) void agg2_kernel(
    const int* __restrict__ rp1, const unsigned short* __restrict__ es1,
    const unsigned* __restrict__ HS1, const float* __restrict__ als1,
    const float* __restrict__ ald1,
    const int* __restrict__ rp2, const unsigned short* __restrict__ es2,
    const unsigned* __restrict__ HS2, const float* __restrict__ als2,
    const float* __restrict__ ald2,
    const void* __restrict__ b1, const void* __restrict__ b2,
    void* __restrict__ out, size_t out_off, int n, const int* __restrict__ flag)
{
    const int gw   = (blockIdx.x * blockDim.x + threadIdx.x) >> 6;
    const int lane = threadIdx.x & 63;
    if (gw >= n) return;
    const int half = lane >> 5;      // 0: edge j, 1: edge j+1
    const int ch2  = lane & 31;      // channel pair (2*ch2, 2*ch2+1)

    int p1 = rp1[gw], e1 = rp1[gw + 1];
    int p2 = rp2[gw], e2 = rp2[gw + 1];
    const float ad1 = ald1[gw], ad2 = ald2[gw];

    float l1a = 0.f, h1a = 0.f, l1b = 0.f, h1b = 0.f, den1 = 0.f;
    float l2a = 0.f, h2a = 0.f, l2b = 0.f, h2b = 0.f, den2 = 0.f;

    while (p1 < e1 || p2 < e2) {
        int nn1 = e1 - p1; nn1 = nn1 < 0 ? 0 : (nn1 > 64 ? 64 : nn1);
        int nn2 = e2 - p2; nn2 = nn2 < 0 ? 0 : (nn2 > 64 ? 64 : nn2);
        int s1 = 0, s2 = 0; float w1 = 0.f, w2 = 0.f;
        if (lane < nn1) {
            s1 = es1[p1 + lane];
            float l = als1[s1] + ad1;
            l = (l > 0.f) ? l : 0.2f * l;
            w1 = __expf(l);
        }
        if (lane < nn2) {
            s2 = es2[p2 + lane];
            float l = als2[s2] + ad2;
            l = (l > 0.f) ? l : 0.2f * l;
            w2 = __expf(l);
        }
        den1 += w1; den2 += w2;

        const int jm = (nn1 > nn2) ? nn1 : nn2;
        for (int j = 0; j < jm; j += 4) {
            // rel1: edges j+half (A) and j+2+half (B); idx <= 63 always
            int   sA1 = __shfl(s1, j + half), sB1 = __shfl(s1, j + 2 + half);
            float wA1 = __shfl(w1, j + half), wB1 = __shfl(w1, j + 2 + half);
            int   sA2 = __shfl(s2, j + half), sB2 = __shfl(s2, j + 2 + half);
            float wA2 = __shfl(w2, j + half), wB2 = __shfl(w2, j + 2 + half);
            unsigned vA1 = HS1[(size_t)sA1 * 32 + ch2];
            unsigned vB1 = HS1[(size_t)sB1 * 32 + ch2];
            unsigned vA2 = HS2[(size_t)sA2 * 32 + ch2];
            unsigned vB2 = HS2[(size_t)sB2 * 32 + ch2];
            l1a = fmaf(wA1, bflo(vA1), l1a); h1a = fmaf(wA1, bfhi(vA1), h1a);
            l1b = fmaf(wB1, bflo(vB1), l1b); h1b = fmaf(wB1, bfhi(vB1), h1b);
            l2a = fmaf(wA2, bflo(vA2), l2a); h2a = fmaf(wA2, bfhi(vA2), h2a);
            l2b = fmaf(wB2, bflo(vB2), l2b); h2b = fmaf(wB2, bfhi(vB2), h2b);
        }
        p1 += nn1; p2 += nn2;
    }

    float lo1 = l1a + l1b, hi1 = h1a + h1b;
    float lo2 = l2a + l2b, hi2 = h2a + h2b;
    lo1 += __shfl_xor(lo1, 32); hi1 += __shfl_xor(hi1, 32);
    lo2 += __shfl_xor(lo2, 32); hi2 += __shfl_xor(hi2, 32);
    den1 = wave_sum(den1);
    den2 = wave_sum(den2);
    const float inv1 = 1.0f / (den1 + 1e-16f);
    const float inv2 = 1.0f / (den2 + 1e-16f);

    if (half == 0) {
        const bool f32 = (flag[0] != 0);
        const int c0 = 2 * ch2;
        float vlo = 0.5f * (lo1 * inv1 + lo2 * inv2 +
                            ldx(b1, c0, f32) + ldx(b2, c0, f32));
        float vhi = 0.5f * (hi1 * inv1 + hi2 * inv2 +
                            ldx(b1, c0 + 1, f32) + ldx(b2, c0 + 1, f32));
        const size_t pairidx = (out_off >> 1) + (size_t)gw * 32 + ch2;
        if (f32) ((float2*)out)[pairidx] = make_float2(vlo, vhi);
        else {
            ushort2 u2 = make_ushort2(f2bfbits(vlo), f2bfbits(vhi));
            ((ushort2*)out)[pairidx] = u2;
        }
    }
}

// ---------------------------------------------------------------------------
extern "C" void kernel_launch(void* const* d_in, const int* in_sizes, int n_in,
                              void* d_out, int out_size, void* d_ws, size_t ws_size,
                              hipStream_t stream)
{
    const void* x_t = d_in[0];
    const void* x_d = d_in[1];
    const int* ei_tt = (const int*)d_in[2];
    const int* ei_dt = (const int*)d_in[3];
    const int* ei_dd = (const int*)d_in[4];
    const int* ei_td = (const int*)d_in[5];
    const void* W_tt     = d_in[6];
    const void* att_tt_s = d_in[7];
    const void* att_tt_d = d_in[8];
    const void* b_tt     = d_in[9];
    const void* W_dt_src = d_in[10];
    const void* W_dt_dst = d_in[11];
    const void* att_dt_s = d_in[12];
    const void* att_dt_d = d_in[13];
    const void* b_dt     = d_in[14];
    const void* W_dd     = d_in[15];
    const void* att_dd_s = d_in[16];
    const void* att_dd_d = d_in[17];
    const void* b_dd     = d_in[18];
    const void* W_td_src = d_in[19];
    const void* W_td_dst = d_in[20];
    const void* att_td_s = d_in[21];
    const void* att_td_d = d_in[22];
    const void* b_td     = d_in[23];

    const int NT = in_sizes[0] / 128;
    const int ND = in_sizes[1] / 128;
    const int Ett = in_sizes[2] / 2, Edt = in_sizes[3] / 2,
              Edd = in_sizes[4] / 2, Etd = in_sizes[5] / 2;
    const int NMAX = (NT > ND) ? NT : ND;
    int EMAX = Ett;
    if (Edt > EMAX) EMAX = Edt;
    if (Edd > EMAX) EMAX = Edd;
    if (Etd > EMAX) EMAX = Etd;
    const int TE = Ett + Edt + Edd + Etd;

    const int NBr  = (NMAX + 127) >> 7;      // buckets per relation
    const int NBtot = 4 * NBr;
    const int HM = NBtot * NBLK;             // histogram matrix size

    // ---- workspace ----
    char* wptr = (char*)d_ws;
    auto alloc = [&](size_t bytes) -> void* {
        void* p = (void*)wptr;
        wptr += (bytes + 255) & ~(size_t)255;
        return p;
    };
    bf16*  h1      = (bf16*)alloc((size_t)NMAX * 64 * 2);
    bf16*  h2      = (bf16*)alloc((size_t)NMAX * 64 * 2);
    float* als[4]; float* ald[4];
    for (int r = 0; r < 4; ++r) {
        als[r] = (float*)alloc((size_t)NMAX * 4);
        ald[r] = (float*)alloc((size_t)NMAX * 4);
    }
    int*   hist    = (int*)alloc((size_t)HM * 4);
    int*   rowptr4 = (int*)alloc((size_t)4 * (NMAX + 1) * 4);
    unsigned short* esrc4 = (unsigned short*)alloc((size_t)4 * EMAX * 2);
    unsigned* temp = (unsigned*)alloc((size_t)TE * 4);
    int*   gpart   = (int*)alloc(1024 * 4);
    float* wvec_dt = (float*)alloc(128 * 4);
    float* wvec_td = (float*)alloc(128 * 4);
    int*   flag    = (int*)alloc(256 * 4);
    bf16*  h3      = (bf16*)temp;   // temp is dead after fillb; alias for dd's H

    RelSet rs;
    rs.src0 = ei_tt; rs.dst0 = ei_tt + Ett;
    rs.src1 = ei_dt; rs.dst1 = ei_dt + Edt;
    rs.src2 = ei_dd; rs.dst2 = ei_dd + Edd;
    rs.src3 = ei_td; rs.dst3 = ei_td + Etd;
    rs.off1 = Ett; rs.off2 = Ett + Edt; rs.off3 = Ett + Edt + Edd; rs.off4 = TE;
    rs.nd0 = NT; rs.nd1 = NT; rs.nd2 = ND; rs.nd3 = ND;

    detect_kernel<<<1, 256, 0, stream>>>((const unsigned*)x_t, 4096, flag);

    // ---- CSR build ----
    const size_t ldsB = (size_t)NBtot * 4;
    pass1_kernel<<<NBLK, 1024, ldsB, stream>>>(rs, hist, NBr);
    const int gnb = (HM + 4095) / 4096;
    gscan_a_kernel<<<gnb, 1024, 0, stream>>>(hist, HM, NBtot, gpart);
    gscan_b_kernel<<<1, 1024, 0, stream>>>(gpart, gnb);
    gscan_c_kernel<<<(HM + 255) / 256, 256, 0, stream>>>(hist, gpart, HM, NBtot);
    scatter_kernel<<<NBLK, 1024, ldsB, stream>>>(rs, hist, temp, NBr);
    fillb_kernel<<<NBtot, 256, 0, stream>>>(rs, hist, temp, rowptr4, esrc4,
                                            NBr, NMAX, EMAX, TE);

    // ---- wvec for the two alpha-only projections ----
    wvec2_kernel<<<1, 256, 0, stream>>>(W_dt_dst, att_dt_d, W_td_dst, att_td_d,
                                        wvec_dt, wvec_td, flag);

    // ---- projections tt -> h1, dt -> h2, dd -> h3 (temp alias) ----
    ProjArg Ptt{ x_t, W_tt, att_tt_s, att_tt_d, wvec_dt,
                 h1, als[0], ald[0], ald[1], NT };
    ProjArg Pdt{ x_d, W_dt_src, att_dt_s, nullptr, wvec_td,
                 h2, als[1], nullptr, ald[3], ND };
    ProjArg Pdd{ x_d, W_dd, att_dd_s, att_dd_d, nullptr,
                 h3, als[2], ald[2], nullptr, ND };
    proj3_kernel<128, 128, 128><<<2304, 256, 0, stream>>>(Ptt, Pdt, Pdd,
                                                          768, 768, flag);

    // ---- target aggregate (tt rel0 + dt rel1) -> x_target_new ----
    agg2_kernel<<<(NT + 3) / 4, 256, 0, stream>>>(
        rowptr4 + 0 * (NMAX + 1), esrc4 + (size_t)0 * EMAX,
        (const unsigned*)h1, als[0], ald[0],
        rowptr4 + 1 * (NMAX + 1), esrc4 + (size_t)1 * EMAX,
        (const unsigned*)h2, als[1], ald[1],
        b_tt, b_dt, d_out, 0, NT, flag);

    // ---- td projection (reads x_target_new) -> h1 (reused) ----
    ProjArg Ptd{ d_out, W_td_src, att_td_s, nullptr, nullptr,
                 h1, als[3], nullptr, nullptr, NT };
    proj1_kernel<64><<<1024, 256, 0, stream>>>(Ptd, flag);

    // ---- drug aggregate (dd rel2 + td rel3) -> x_drug_new ----
    agg2_kernel<<<(ND + 3) / 4, 256, 0, stream>>>(
        rowptr4 + 2 * (NMAX + 1), esrc4 + (size_t)2 * EMAX,
        (const unsigned*)h3, als[2], ald[2],
        rowptr4 + 3 * (NMAX + 1), esrc4 + (size_t)3 * EMAX,
        (const unsigned*)h1, als[3], ald[3],
        b_dd, b_td, d_out, (size_t)NT * 64, ND, flag);
}

// Round 12
// 342.925 us; speedup vs baseline: 3.6452x; 1.0847x over previous
//
#include <hip/hip_runtime.h>
#include <hip/hip_bf16.h>

typedef __hip_bfloat16 bf16;

typedef __bf16 bf16v8 __attribute__((ext_vector_type(8)));
typedef short  s16v8  __attribute__((ext_vector_type(8)));
typedef float  f32v4  __attribute__((ext_vector_type(4)));

#define NBLK  256      // edge-pass blocks (power of 2)
#define NBLKL 8        // log2(NBLK)

__device__ __forceinline__ float bf2f(unsigned short u) {
    return __uint_as_float(((unsigned)u) << 16);
}
__device__ __forceinline__ float bflo(unsigned v) {
    return __uint_as_float(v << 16);
}
__device__ __forceinline__ float bfhi(unsigned v) {
    return __uint_as_float(v & 0xFFFF0000u);
}
__device__ __forceinline__ float ldx(const void* p, size_t i, bool f32) {
    return f32 ? ((const float*)p)[i] : bf2f(((const unsigned short*)p)[i]);
}
__device__ __forceinline__ unsigned short f2bfbits(float f) {
    union { bf16 h; unsigned short u; } cv;
    cv.h = __float2bfloat16(f);
    return cv.u;
}
__device__ __forceinline__ float wave_sum(float v) {
    #pragma unroll
    for (int o = 32; o > 0; o >>= 1) v += __shfl_xor(v, o);
    return v;
}
// logical (bucket-major) -> physical (block-major) index for the hist matrix
__device__ __forceinline__ int physidx(int l, int NBtot) {
    return (l & (NBLK - 1)) * NBtot + (l >> NBLKL);
}

// ---------------------------------------------------------------------------
// dtype detector (f32 vs bf16 inputs)
// ---------------------------------------------------------------------------
__global__ void detect_kernel(const unsigned* __restrict__ x, int nwords,
                              int* __restrict__ flag)
{
    __shared__ int cnt;
    if (threadIdx.x == 0) cnt = 0;
    __syncthreads();
    int c = 0;
    for (int i = threadIdx.x; i < nwords; i += blockDim.x) {
        unsigned e = (x[i] >> 23) & 0xFFu;
        if (e >= 100u && e <= 150u) c++;
    }
    atomicAdd(&cnt, c);
    __syncthreads();
    if (threadIdx.x == 0) flag[0] = (2 * cnt > nwords) ? 1 : 0;
}

// ---------------------------------------------------------------------------
// Relation set
// ---------------------------------------------------------------------------
struct RelSet {
    const int *src0, *dst0, *src1, *dst1, *src2, *dst2, *src3, *dst3;
    int off1, off2, off3, off4;
    int nd0, nd1, nd2, nd3;
};

__device__ __forceinline__ void pick(const RelSet& rs, int e, int& r,
                                     const int*& s, const int*& d, int& le)
{
    if (e < rs.off1)      { r = 0; s = rs.src0; d = rs.dst0; le = e; }
    else if (e < rs.off2) { r = 1; s = rs.src1; d = rs.dst1; le = e - rs.off1; }
    else if (e < rs.off3) { r = 2; s = rs.src2; d = rs.dst2; le = e - rs.off2; }
    else                  { r = 3; s = rs.src3; d = rs.dst3; le = e - rs.off3; }
}
__device__ __forceinline__ int ndst_of(const RelSet& rs, int r)
{
    return r == 0 ? rs.nd0 : r == 1 ? rs.nd1 : r == 2 ? rs.nd2 : rs.nd3;
}

// ---------------------------------------------------------------------------
// Pass 1: per-(block,bucket) LDS histogram -> hist[block*NBtot + bucket]
// ---------------------------------------------------------------------------
__global__ __launch_bounds__(1024) void pass1_kernel(
    RelSet rs, int* __restrict__ hist, int NBr)
{
    extern __shared__ int lh[];
    const int NBtot = 4 * NBr;
    for (int i = threadIdx.x; i < NBtot; i += 1024) lh[i] = 0;
    __syncthreads();
    for (int e = blockIdx.x * 1024 + threadIdx.x; e < rs.off4; e += NBLK * 1024) {
        int r, le; const int *s, *d;
        pick(rs, e, r, s, d, le);
        atomicAdd(&lh[r * NBr + (d[le] >> 7)], 1);
    }
    __syncthreads();
    for (int i = threadIdx.x; i < NBtot; i += 1024)
        hist[blockIdx.x * NBtot + i] = lh[i];
}

// ---------------------------------------------------------------------------
// Exclusive scan over the hist matrix in LOGICAL (bucket-major) order.
// ---------------------------------------------------------------------------
__global__ __launch_bounds__(1024) void gscan_a_kernel(
    int* __restrict__ buf, int n, int NBtot, int* __restrict__ partials)
{
    __shared__ int sh[1024];
    const int t = threadIdx.x;
    const int base = blockIdx.x * 4096 + t * 4;
    int p0 = 0, p1 = 0, p2 = 0, p3 = 0;
    int v0 = 0, v1 = 0, v2 = 0, v3 = 0;
    if (base < n)     { p0 = physidx(base,     NBtot); v0 = buf[p0]; }
    if (base + 1 < n) { p1 = physidx(base + 1, NBtot); v1 = buf[p1]; }
    if (base + 2 < n) { p2 = physidx(base + 2, NBtot); v2 = buf[p2]; }
    if (base + 3 < n) { p3 = physidx(base + 3, NBtot); v3 = buf[p3]; }
    const int tsum = v0 + v1 + v2 + v3;
    sh[t] = tsum;
    __syncthreads();
    for (int o = 1; o < 1024; o <<= 1) {
        int u = (t >= o) ? sh[t - o] : 0;
        __syncthreads();
        sh[t] += u;
        __syncthreads();
    }
    const int texcl = sh[t] - tsum;
    if (base < n)     buf[p0] = texcl;
    if (base + 1 < n) buf[p1] = texcl + v0;
    if (base + 2 < n) buf[p2] = texcl + v0 + v1;
    if (base + 3 < n) buf[p3] = texcl + v0 + v1 + v2;
    if (t == 1023) partials[blockIdx.x] = sh[t];
}

__global__ __launch_bounds__(1024) void gscan_b_kernel(int* __restrict__ partials,
                                                       int nb)
{
    __shared__ int sh[1024];
    const int t = threadIdx.x;
    int v = (t < nb) ? partials[t] : 0;
    sh[t] = v;
    __syncthreads();
    for (int o = 1; o < 1024; o <<= 1) {
        int u = (t >= o) ? sh[t - o] : 0;
        __syncthreads();
        sh[t] += u;
        __syncthreads();
    }
    if (t < nb) partials[t] = sh[t] - v;   // exclusive
}

__global__ void gscan_c_kernel(int* __restrict__ buf,
                               const int* __restrict__ partials, int n, int NBtot)
{
    int l = blockIdx.x * blockDim.x + threadIdx.x;
    if (l < n) buf[physidx(l, NBtot)] += partials[l >> 12];
}

// ---------------------------------------------------------------------------
// Scatter pass: append (src | dfine<<16) into block-private bucket ranges.
// ---------------------------------------------------------------------------
__global__ __launch_bounds__(1024) void scatter_kernel(
    RelSet rs, const int* __restrict__ O, unsigned* __restrict__ temp, int NBr)
{
    extern __shared__ int cur[];
    const int NBtot = 4 * NBr;
    for (int i = threadIdx.x; i < NBtot; i += 1024)
        cur[i] = O[blockIdx.x * NBtot + i];
    __syncthreads();
    for (int e = blockIdx.x * 1024 + threadIdx.x; e < rs.off4; e += NBLK * 1024) {
        int r, le; const int *s, *d;
        pick(rs, e, r, s, d, le);
        int dd = d[le];
        int b = r * NBr + (dd >> 7);
        int pos = atomicAdd(&cur[b], 1);
        temp[pos] = (unsigned)s[le] | ((unsigned)(dd & 127) << 16);
    }
}

// ---------------------------------------------------------------------------
// Fill: one block per bucket; rowptr + edge placement, all block-local.
// ---------------------------------------------------------------------------
__global__ __launch_bounds__(256) void fillb_kernel(
    RelSet rs, const int* __restrict__ O, const unsigned* __restrict__ temp,
    int* __restrict__ rowptr4, unsigned short* __restrict__ esrc4,
    int NBr, int NP, int EP, int TE)
{
    __shared__ int cnt[128];
    __shared__ int cur[128];
    const int b = blockIdx.x;
    const int NBtot = 4 * NBr;
    const int r = b / NBr;
    const int bloc = b - r * NBr;
    const int dbase = bloc << 7;
    const int nd = ndst_of(rs, r);
    const int bstart = O[b];
    const int bend   = (b + 1 < NBtot) ? O[b + 1] : TE;
    const int relstart = O[r * NBr];
    const int relend   = (r + 1 < 4) ? O[(r + 1) * NBr] : TE;
    const int t = threadIdx.x;

    if (t < 128) cnt[t] = 0;
    __syncthreads();
    for (int i = bstart + t; i < bend; i += 256)
        atomicAdd(&cnt[temp[i] >> 16], 1);
    __syncthreads();
    const int orig = (t < 128) ? cnt[t] : 0;
    for (int o = 1; o < 128; o <<= 1) {
        int add = 0;
        if (t < 128 && t >= o) add = cnt[t - o];
        __syncthreads();
        if (t < 128) cnt[t] += add;
        __syncthreads();
    }
    const int bucket_base = bstart - relstart;
    if (t < 128) {
        const int excl = cnt[t] - orig;
        cur[t] = bucket_base + excl;
        const int d = dbase + t;
        if (d < nd) rowptr4[r * (NP + 1) + d] = bucket_base + excl;
    }
    if (t == 0 && bloc == NBr - 1)
        rowptr4[r * (NP + 1) + nd] = relend - relstart;
    __syncthreads();
    unsigned short* es = esrc4 + (size_t)r * EP;
    for (int i = bstart + t; i < bend; i += 256) {
        unsigned u = temp[i];
        int pos = atomicAdd(&cur[u >> 16], 1);
        es[pos] = (unsigned short)(u & 0xFFFFu);
    }
}

// ---------------------------------------------------------------------------
// pack4: pre-transpose 4 weight matrices into global B-frag order (bf16 bits):
// Wp[((kt*4+ct)*64 + quad*16+n)*8 + j] = bf16(W[kt*32+quad*8+j][ct*16+n])
// ---------------------------------------------------------------------------
__device__ __forceinline__ void pack_one(const void* W, unsigned short* Wp,
                                         int i, bool f32)
{
    int k = i >> 6, c = i & 63;
    int kt = k >> 5, q = (k >> 3) & 3, j = k & 7;
    int ct = c >> 4, n = c & 15;
    Wp[(((kt * 4 + ct) * 64) + q * 16 + n) * 8 + j] = f2bfbits(ldx(W, i, f32));
}

__global__ __launch_bounds__(256) void pack4_kernel(
    const void* __restrict__ W0, const void* __restrict__ W1,
    const void* __restrict__ W2, const void* __restrict__ W3,
    unsigned short* __restrict__ P0, unsigned short* __restrict__ P1,
    unsigned short* __restrict__ P2, unsigned short* __restrict__ P3,
    const int* __restrict__ flag)
{
    const bool f32 = (flag[0] != 0);
    int i = blockIdx.x * 256 + threadIdx.x;
    if (i < 8192)       pack_one(W0, P0, i, f32);
    else if (i < 16384) pack_one(W1, P1, i - 8192, f32);
    else if (i < 24576) pack_one(W2, P2, i - 16384, f32);
    else if (i < 28672) pack_one(W3, P3, i - 24576, f32);
}

// ---------------------------------------------------------------------------
// wvec2: wv1 = W1 @ a1, wv2 = W2 @ a2 (both K=128)
// ---------------------------------------------------------------------------
__global__ void wvec2_kernel(const void* __restrict__ W1, const void* __restrict__ a1,
                             const void* __restrict__ W2, const void* __restrict__ a2,
                             float* __restrict__ wv1, float* __restrict__ wv2,
                             const int* __restrict__ flag)
{
    const bool f32 = (flag[0] != 0);
    const int t = threadIdx.x;
    const void* W = (t < 128) ? W1 : W2;
    const void* a = (t < 128) ? a1 : a2;
    const int k = t & 127;
    float s = 0.f;
    for (int c = 0; c < 64; ++c) s += ldx(W, (size_t)k * 64 + c, f32) * ldx(a, c, f32);
    ((t < 128) ? wv1 : wv2)[k] = s;
}

// ---------------------------------------------------------------------------
// MFMA projection: B-frags loaded straight from packed global W (no LDS).
// ---------------------------------------------------------------------------
struct ProjArg {
    const void* X; const unsigned short* Wp; const void* a1; const void* a2;
    const float* wvx;
    bf16* H; float* al1; float* al2; float* alx;
    int N;
};

template <int K>
__device__ __forceinline__ void proj_body(const ProjArg& P, bool f32,
                                          int bid, int nblocks)
{
    constexpr int NKT = K / 32;
    const int tid = threadIdx.x;
    const int wave = tid >> 6, lane = tid & 63;
    const int quad = lane >> 4, n = lane & 15;

    // B fragments: 16 coalesced 16B global loads (L2-hot), conflict-free
    s16v8 Bf[NKT][4];
    #pragma unroll
    for (int kt = 0; kt < NKT; ++kt)
        #pragma unroll
        for (int ct = 0; ct < 4; ++ct)
            Bf[kt][ct] = *(const s16v8*)&P.Wp[((kt * 4 + ct) * 64 + lane) * 8];

    float a1v[4], a2v[4];
    #pragma unroll
    for (int ct = 0; ct < 4; ++ct) {
        a1v[ct] = P.a1 ? ldx(P.a1, ct * 16 + n, f32) : 0.f;
        a2v[ct] = P.a2 ? ldx(P.a2, ct * 16 + n, f32) : 0.f;
    }
    float wv[NKT][8];
    if (P.wvx) {
        #pragma unroll
        for (int kt = 0; kt < NKT; ++kt)
            #pragma unroll
            for (int j = 0; j < 8; ++j)
                wv[kt][j] = P.wvx[kt * 32 + quad * 8 + j];
    }

    const int tiles = (P.N + 15) / 16;
    for (int tb = bid * 4 + wave; tb < tiles; tb += nblocks * 4) {
        const int r0 = tb * 16;
        const int arow = r0 + n;
        const int ars  = (arow < P.N) ? arow : 0;

        f32v4 acc[4];
        #pragma unroll
        for (int ct = 0; ct < 4; ++ct) acc[ct] = (f32v4){0.f, 0.f, 0.f, 0.f};
        float txd = 0.f;

        #pragma unroll
        for (int kt = 0; kt < NKT; ++kt) {
            s16v8 As;
            if (f32) {
                const float4* xp = (const float4*)P.X +
                    ((size_t)ars * K + kt * 32 + quad * 8) / 4;
                float4 x0 = xp[0], x1 = xp[1];
                As[0] = (short)f2bfbits(x0.x); As[1] = (short)f2bfbits(x0.y);
                As[2] = (short)f2bfbits(x0.z); As[3] = (short)f2bfbits(x0.w);
                As[4] = (short)f2bfbits(x1.x); As[5] = (short)f2bfbits(x1.y);
                As[6] = (short)f2bfbits(x1.z); As[7] = (short)f2bfbits(x1.w);
            } else {
                As = *(const s16v8*)((const unsigned short*)P.X +
                    (size_t)ars * K + kt * 32 + quad * 8);
            }
            if (P.wvx) {
                #pragma unroll
                for (int j = 0; j < 8; ++j)
                    txd = fmaf(bf2f((unsigned short)As[j]), wv[kt][j], txd);
            }
            bf16v8 Ab = __builtin_bit_cast(bf16v8, As);
            #pragma unroll
            for (int ct = 0; ct < 4; ++ct)
                acc[ct] = __builtin_amdgcn_mfma_f32_16x16x32_bf16(
                    Ab, __builtin_bit_cast(bf16v8, Bf[kt][ct]), acc[ct], 0, 0, 0);
        }

        if (P.alx) {
            txd += __shfl_xor(txd, 16);
            txd += __shfl_xor(txd, 32);
            if (lane < 16 && r0 + lane < P.N) P.alx[r0 + lane] = txd;
        }

        #pragma unroll
        for (int i = 0; i < 4; ++i) {
            const int r = r0 + quad * 4 + i;
            const bool rv = (r < P.N);
            if (rv && P.H) {
                #pragma unroll
                for (int ct = 0; ct < 4; ++ct)
                    P.H[(size_t)r * 64 + ct * 16 + n] = __float2bfloat16(acc[ct][i]);
            }
            if (P.al1) {
                float t = acc[0][i] * a1v[0] + acc[1][i] * a1v[1] +
                          acc[2][i] * a1v[2] + acc[3][i] * a1v[3];
                #pragma unroll
                for (int o = 1; o < 16; o <<= 1) t += __shfl_xor(t, o);
                if (rv && n == 0) P.al1[r] = t;
            }
            if (P.al2) {
                float t = acc[0][i] * a2v[0] + acc[1][i] * a2v[1] +
                          acc[2][i] * a2v[2] + acc[3][i] * a2v[3];
                #pragma unroll
                for (int o = 1; o < 16; o <<= 1) t += __shfl_xor(t, o);
                if (rv && n == 0) P.al2[r] = t;
            }
        }
    }
}

template <int KA, int KB, int KC>
__global__ __launch_bounds__(256) void proj3_kernel(ProjArg A, ProjArg B, ProjArg C,
                                                    int nA, int nB,
                                                    const int* __restrict__ flag)
{
    const bool f32 = (flag[0] != 0);
    const int bx = blockIdx.x;
    if (bx < nA)            proj_body<KA>(A, f32, bx, nA);
    else if (bx < nA + nB)  proj_body<KB>(B, f32, bx - nA, nB);
    else                    proj_body<KC>(C, f32, bx - nA - nB,
                                          gridDim.x - nA - nB);
}

template <int K>
__global__ __launch_bounds__(256) void proj1_kernel(ProjArg A,
                                                    const int* __restrict__ flag)
{
    proj_body<K>(A, flag[0] != 0, blockIdx.x, gridDim.x);
}

// ---------------------------------------------------------------------------
// Fused dual-relation softmax aggregation, 2 channels/lane.
// ---------------------------------------------------------------------------
__global__ __launch_bounds__(256) void agg2_kernel(
    const int* __restrict__ rp1, const unsigned short* __restrict__ es1,
    const unsigned* __restrict__ HS1, const float* __restrict__ als1,
    const float* __restrict__ ald1,
    const int* __restrict__ rp2, const unsigned short* __restrict__ es2,
    const unsigned* __restrict__ HS2, const float* __restrict__ als2,
    const float* __restrict__ ald2,
    const void* __restrict__ b1, const void* __restrict__ b2,
    void* __restrict__ out, size_t out_off, int n, const int* __restrict__ flag)
{
    const int gw   = (blockIdx.x * blockDim.x + threadIdx.x) >> 6;
    const int lane = threadIdx.x & 63;
    if (gw >= n) return;
    const int half = lane >> 5;      // 0: edge j, 1: edge j+1
    const int ch2  = lane & 31;      // channel pair (2*ch2, 2*ch2+1)

    int p1 = rp1[gw], e1 = rp1[gw + 1];
    int p2 = rp2[gw], e2 = rp2[gw + 1];
    const float ad1 = ald1[gw], ad2 = ald2[gw];

    float l1a = 0.f, h1a = 0.f, l1b = 0.f, h1b = 0.f, den1 = 0.f;
    float l2a = 0.f, h2a = 0.f, l2b = 0.f, h2b = 0.f, den2 = 0.f;

    while (p1 < e1 || p2 < e2) {
        int nn1 = e1 - p1; nn1 = nn1 < 0 ? 0 : (nn1 > 64 ? 64 : nn1);
        int nn2 = e2 - p2; nn2 = nn2 < 0 ? 0 : (nn2 > 64 ? 64 : nn2);
        int s1 = 0, s2 = 0; float w1 = 0.f, w2 = 0.f;
        if (lane < nn1) {
            s1 = es1[p1 + lane];
            float l = als1[s1] + ad1;
            l = (l > 0.f) ? l : 0.2f * l;
            w1 = __expf(l);
        }
        if (lane < nn2) {
            s2 = es2[p2 + lane];
            float l = als2[s2] + ad2;
            l = (l > 0.f) ? l : 0.2f * l;
            w2 = __expf(l);
        }
        den1 += w1; den2 += w2;

        const int jm = (nn1 > nn2) ? nn1 : nn2;
        for (int j = 0; j < jm; j += 4) {
            int   sA1 = __shfl(s1, j + half), sB1 = __shfl(s1, j + 2 + half);
            float wA1 = __shfl(w1, j + half), wB1 = __shfl(w1, j + 2 + half);
            int   sA2 = __shfl(s2, j + half), sB2 = __shfl(s2, j + 2 + half);
            float wA2 = __shfl(w2, j + half), wB2 = __shfl(w2, j + 2 + half);
            unsigned vA1 = HS1[(size_t)sA1 * 32 + ch2];
            unsigned vB1 = HS1[(size_t)sB1 * 32 + ch2];
            unsigned vA2 = HS2[(size_t)sA2 * 32 + ch2];
            unsigned vB2 = HS2[(size_t)sB2 * 32 + ch2];
            l1a = fmaf(wA1, bflo(vA1), l1a); h1a = fmaf(wA1, bfhi(vA1), h1a);
            l1b = fmaf(wB1, bflo(vB1), l1b); h1b = fmaf(wB1, bfhi(vB1), h1b);
            l2a = fmaf(wA2, bflo(vA2), l2a); h2a = fmaf(wA2, bfhi(vA2), h2a);
            l2b = fmaf(wB2, bflo(vB2), l2b); h2b = fmaf(wB2, bfhi(vB2), h2b);
        }
        p1 += nn1; p2 += nn2;
    }

    float lo1 = l1a + l1b, hi1 = h1a + h1b;
    float lo2 = l2a + l2b, hi2 = h2a + h2b;
    lo1 += __shfl_xor(lo1, 32); hi1 += __shfl_xor(hi1, 32);
    lo2 += __shfl_xor(lo2, 32); hi2 += __shfl_xor(hi2, 32);
    den1 = wave_sum(den1);
    den2 = wave_sum(den2);
    const float inv1 = 1.0f / (den1 + 1e-16f);
    const float inv2 = 1.0f / (den2 + 1e-16f);

    if (half == 0) {
        const bool f32 = (flag[0] != 0);
        const int c0 = 2 * ch2;
        float vlo = 0.5f * (lo1 * inv1 + lo2 * inv2 +
                            ldx(b1, c0, f32) + ldx(b2, c0, f32));
        float vhi = 0.5f * (hi1 * inv1 + hi2 * inv2 +
                            ldx(b1, c0 + 1, f32) + ldx(b2, c0 + 1, f32));
        const size_t pairidx = (out_off >> 1) + (size_t)gw * 32 + ch2;
        if (f32) ((float2*)out)[pairidx] = make_float2(vlo, vhi);
        else {
            ushort2 u2 = make_ushort2(f2bfbits(vlo), f2bfbits(vhi));
            ((ushort2*)out)[pairidx] = u2;
        }
    }
}

// ---------------------------------------------------------------------------
extern "C" void kernel_launch(void* const* d_in, const int* in_sizes, int n_in,
                              void* d_out, int out_size, void* d_ws, size_t ws_size,
                              hipStream_t stream)
{
    const void* x_t = d_in[0];
    const void* x_d = d_in[1];
    const int* ei_tt = (const int*)d_in[2];
    const int* ei_dt = (const int*)d_in[3];
    const int* ei_dd = (const int*)d_in[4];
    const int* ei_td = (const int*)d_in[5];
    const void* W_tt     = d_in[6];
    const void* att_tt_s = d_in[7];
    const void* att_tt_d = d_in[8];
    const void* b_tt     = d_in[9];
    const void* W_dt_src = d_in[10];
    const void* W_dt_dst = d_in[11];
    const void* att_dt_s = d_in[12];
    const void* att_dt_d = d_in[13];
    const void* b_dt     = d_in[14];
    const void* W_dd     = d_in[15];
    const void* att_dd_s = d_in[16];
    const void* att_dd_d = d_in[17];
    const void* b_dd     = d_in[18];
    const void* W_td_src = d_in[19];
    const void* W_td_dst = d_in[20];
    const void* att_td_s = d_in[21];
    const void* att_td_d = d_in[22];
    const void* b_td     = d_in[23];

    const int NT = in_sizes[0] / 128;
    const int ND = in_sizes[1] / 128;
    const int Ett = in_sizes[2] / 2, Edt = in_sizes[3] / 2,
              Edd = in_sizes[4] / 2, Etd = in_sizes[5] / 2;
    const int NMAX = (NT > ND) ? NT : ND;
    int EMAX = Ett;
    if (Edt > EMAX) EMAX = Edt;
    if (Edd > EMAX) EMAX = Edd;
    if (Etd > EMAX) EMAX = Etd;
    const int TE = Ett + Edt + Edd + Etd;

    const int NBr  = (NMAX + 127) >> 7;      // buckets per relation
    const int NBtot = 4 * NBr;
    const int HM = NBtot * NBLK;             // histogram matrix size

    // ---- workspace ----
    char* wptr = (char*)d_ws;
    auto alloc = [&](size_t bytes) -> void* {
        void* p = (void*)wptr;
        wptr += (bytes + 255) & ~(size_t)255;
        return p;
    };
    bf16*  h1      = (bf16*)alloc((size_t)NMAX * 64 * 2);
    bf16*  h2      = (bf16*)alloc((size_t)NMAX * 64 * 2);
    float* als[4]; float* ald[4];
    for (int r = 0; r < 4; ++r) {
        als[r] = (float*)alloc((size_t)NMAX * 4);
        ald[r] = (float*)alloc((size_t)NMAX * 4);
    }
    int*   hist    = (int*)alloc((size_t)HM * 4);
    int*   rowptr4 = (int*)alloc((size_t)4 * (NMAX + 1) * 4);
    unsigned short* esrc4 = (unsigned short*)alloc((size_t)4 * EMAX * 2);
    unsigned* temp = (unsigned*)alloc((size_t)TE * 4);
    int*   gpart   = (int*)alloc(1024 * 4);
    float* wvec_dt = (float*)alloc(128 * 4);
    float* wvec_td = (float*)alloc(128 * 4);
    unsigned short* wp_tt = (unsigned short*)alloc(8192 * 2);
    unsigned short* wp_dt = (unsigned short*)alloc(8192 * 2);
    unsigned short* wp_dd = (unsigned short*)alloc(8192 * 2);
    unsigned short* wp_td = (unsigned short*)alloc(4096 * 2);
    int*   flag    = (int*)alloc(256 * 4);
    bf16*  h3      = (bf16*)temp;   // temp dead after fillb; alias for dd's H

    RelSet rs;
    rs.src0 = ei_tt; rs.dst0 = ei_tt + Ett;
    rs.src1 = ei_dt; rs.dst1 = ei_dt + Edt;
    rs.src2 = ei_dd; rs.dst2 = ei_dd + Edd;
    rs.src3 = ei_td; rs.dst3 = ei_td + Etd;
    rs.off1 = Ett; rs.off2 = Ett + Edt; rs.off3 = Ett + Edt + Edd; rs.off4 = TE;
    rs.nd0 = NT; rs.nd1 = NT; rs.nd2 = ND; rs.nd3 = ND;

    detect_kernel<<<1, 256, 0, stream>>>((const unsigned*)x_t, 4096, flag);

    // ---- weight packing + wvecs (tiny) ----
    pack4_kernel<<<112, 256, 0, stream>>>(W_tt, W_dt_src, W_dd, W_td_src,
                                          wp_tt, wp_dt, wp_dd, wp_td, flag);
    wvec2_kernel<<<1, 256, 0, stream>>>(W_dt_dst, att_dt_d, W_td_dst, att_td_d,
                                        wvec_dt, wvec_td, flag);

    // ---- CSR build ----
    const size_t ldsB = (size_t)NBtot * 4;
    pass1_kernel<<<NBLK, 1024, ldsB, stream>>>(rs, hist, NBr);
    const int gnb = (HM + 4095) / 4096;
    gscan_a_kernel<<<gnb, 1024, 0, stream>>>(hist, HM, NBtot, gpart);
    gscan_b_kernel<<<1, 1024, 0, stream>>>(gpart, gnb);
    gscan_c_kernel<<<(HM + 255) / 256, 256, 0, stream>>>(hist, gpart, HM, NBtot);
    scatter_kernel<<<NBLK, 1024, ldsB, stream>>>(rs, hist, temp, NBr);
    fillb_kernel<<<NBtot, 256, 0, stream>>>(rs, hist, temp, rowptr4, esrc4,
                                            NBr, NMAX, EMAX, TE);

    // ---- projections tt -> h1, dt -> h2, dd -> h3 (temp alias) ----
    ProjArg Ptt{ x_t, wp_tt, att_tt_s, att_tt_d, wvec_dt,
                 h1, als[0], ald[0], ald[1], NT };
    ProjArg Pdt{ x_d, wp_dt, att_dt_s, nullptr, wvec_td,
                 h2, als[1], nullptr, ald[3], ND };
    ProjArg Pdd{ x_d, wp_dd, att_dd_s, att_dd_d, nullptr,
                 h3, als[2], ald[2], nullptr, ND };
    proj3_kernel<128, 128, 128><<<2304, 256, 0, stream>>>(Ptt, Pdt, Pdd,
                                                          768, 768, flag);

    // ---- target aggregate (tt rel0 + dt rel1) -> x_target_new ----
    agg2_kernel<<<(NT + 3) / 4, 256, 0, stream>>>(
        rowptr4 + 0 * (NMAX + 1), esrc4 + (size_t)0 * EMAX,
        (const unsigned*)h1, als[0], ald[0],
        rowptr4 + 1 * (NMAX + 1), esrc4 + (size_t)1 * EMAX,
        (const unsigned*)h2, als[1], ald[1],
        b_tt, b_dt, d_out, 0, NT, flag);

    // ---- td projection (reads x_target_new) -> h1 (reused) ----
    ProjArg Ptd{ d_out, wp_td, att_td_s, nullptr, nullptr,
                 h1, als[3], nullptr, nullptr, NT };
    proj1_kernel<64><<<1024, 256, 0, stream>>>(Ptd, flag);

    // ---- drug aggregate (dd rel2 + td rel3) -> x_drug_new ----
    agg2_kernel<<<(ND + 3) / 4, 256, 0, stream>>>(
        rowptr4 + 2 * (NMAX + 1), esrc4 + (size_t)2 * EMAX,
        (const unsigned*)h3, als[2], ald[2],
        rowptr4 + 3 * (NMAX + 1), esrc4 + (size_t)3 * EMAX,
        (const unsigned*)h1, als[3], ald[3],
        b_dd, b_td, d_out, (size_t)NT * 64, ND, flag);
}